// Round 13
// baseline (169.902 us; speedup 1.0000x reference)
//
#include <hip/hip_runtime.h>
#include <cstdint>
#include <cstddef>

// Problem constants (from reference)
constexpr int BB   = 2;
constexpr int NN   = 8192;
constexpr int MM   = 8192;
constexpr int CIN  = 32;
constexpr int COUT = 32;
constexpr int EE   = 16;
constexpr int KK   = 32;
constexpr int GRID = 32;              // binning grid (h = 1/32, ~8 pts/cell)
constexpr int NCELL = GRID * GRID;

#define QPB 4            // K1: queries per 128-thread block
#define QPB2 8           // K2: queries per 256-thread block
#define CAP 128
#define KEY_BYTES 1040   // 128 u64 + 16B skew

// Fixed-radius fast path: lambda = pi*R0^2*N ~ 58 expected candidates.
#define R0_FAST 0.0475f

// Workspace layout (bytes)
constexpr size_t OFS_COEFFT = 0;        // 16384 f = 65536 B
constexpr size_t OFS_COUNTS = 65536;    // 2*1024 i = 8192 B
constexpr size_t OFS_CURSOR = 73728;    // 2*1024 i = 8192 B
constexpr size_t OFS_STARTS = 81920;    // 2*1025 i = 8200 B (pad to 8704)
constexpr size_t OFS_PTSS   = 90624;    // 2*8192 float2 = 131072 B
constexpr size_t OFS_IDXS   = 221696;   // 2*8192 i = 65536 B  (total 287232 B)

// ---- coeff [CIN][COUT][E] -> coeffT [E][COUT][CIN] ------------------------------
__global__ __launch_bounds__(256) void transpose_coeff(const float* __restrict__ coeff,
                                                       float* __restrict__ coeffT) {
    int tid = blockIdx.x * 256 + threadIdx.x;
    if (tid >= EE * COUT * CIN) return;
    int i = tid & 31;
    int o = (tid >> 5) & 31;
    int e = tid >> 10;
    coeffT[tid] = coeff[(i * COUT + o) * EE + e];
}

// ---- binning: zero, count, scan, scatter ----------------------------------------
__global__ __launch_bounds__(256) void bin_zero(int* __restrict__ p) {
    int t = blockIdx.x * 256 + threadIdx.x;
    if (t < 2 * 2 * NCELL) p[t] = 0;
}

__device__ __forceinline__ int cell_of(float2 p) {
    int cx = min(GRID - 1, max(0, (int)(p.x * (float)GRID)));
    int cy = min(GRID - 1, max(0, (int)(p.y * (float)GRID)));
    return cy * GRID + cx;
}

__global__ __launch_bounds__(256) void bin_count(const float* __restrict__ pts,
                                                 int* __restrict__ counts) {
    int t = blockIdx.x * 256 + threadIdx.x;
    int b = t >> 13, i = t & (NN - 1);
    float2 p = ((const float2*)pts)[(size_t)b * NN + i];
    atomicAdd(&counts[b * NCELL + cell_of(p)], 1);
}

__global__ __launch_bounds__(1024) void bin_scan(const int* __restrict__ counts,
                                                 int* __restrict__ starts) {
    __shared__ int sm[NCELL];
    const int t = threadIdx.x;
    for (int b = 0; b < BB; ++b) {
        sm[t] = counts[b * NCELL + t];
        __syncthreads();
        for (int off = 1; off < NCELL; off <<= 1) {
            int v = (t >= off) ? sm[t - off] : 0;
            __syncthreads();
            sm[t] += v;
            __syncthreads();
        }
        starts[b * (NCELL + 1) + t + 1] = sm[t];
        if (t == 0) starts[b * (NCELL + 1)] = 0;
        __syncthreads();
    }
}

__global__ __launch_bounds__(256) void bin_scatter(const float* __restrict__ pts,
                                                   const int* __restrict__ starts,
                                                   int* __restrict__ cursor,
                                                   float2* __restrict__ pts_s,
                                                   int* __restrict__ idx_s) {
    int t = blockIdx.x * 256 + threadIdx.x;
    int b = t >> 13, i = t & (NN - 1);
    float2 p = ((const float2*)pts)[(size_t)b * NN + i];
    int cell = cell_of(p);
    int pos = starts[b * (NCELL + 1) + cell] + atomicAdd(&cursor[b * NCELL + cell], 1);
    pts_s[(size_t)b * NN + pos] = p;     // intra-cell order nondeterministic; final
    idx_s[(size_t)b * NN + pos] = i;     // rank by (d, orig idx) makes output exact.
}

// ==== K1: KNN selection only. One half-wave (32 lanes) per query. ================
// Writes out_uiv (exact u = q - p) and out_idx (idx as float). K2 reconstructs
// bd bit-exactly from u and bi from the float idx -> no extra workspace.
__global__ __launch_bounds__(128) void conv_knn(
    const float2* __restrict__ pts_s, const int* __restrict__ idx_s,
    const int* __restrict__ starts,
    const float* __restrict__ points_in,
    const float* __restrict__ points_out,
    float* __restrict__ out_uiv, float* __restrict__ out_idx)
{
    __shared__ alignas(16) unsigned char SMEM[QPB][KEY_BYTES];

    const int tid   = threadIdx.x;
    const int sl    = tid & 31;
    const int qslot = tid >> 5;            // 0..3
    const int half  = qslot & 1;
    const int wid   = blockIdx.x * QPB + qslot;
    const int b     = wid >> 13;
    const int m     = wid & (MM - 1);

    unsigned long long* KEYq = (unsigned long long*)&SMEM[qslot][0];

    const float2* PS = pts_s + (size_t)b * NN;
    const int*    IS = idx_s + (size_t)b * NN;
    const int*    ST = starts + b * (NCELL + 1);
    const float2* P  = ((const float2*)points_in) + (size_t)b * NN;
    const float2  q  = ((const float2*)points_out)[(size_t)b * MM + m];

    const float INF = __builtin_inff();
    const float h = 1.0f / (float)GRID;
    const unsigned lmlt32 = (1u << sl) - 1u;

    float bd;   // sorted exact distance (sub-lane sl holds entry #sl)
    int   bi;   // sorted original index
    bool  ok = false;

    // ---------------- FAST PATH: fixed analytic radius, single scan ---------------
    {
        float tau = R0_FAST;
        {
            const float bx = fminf(q.x, 1.0f - q.x);
            const float by = fminf(q.y, 1.0f - q.y);
#pragma unroll
            for (int it = 0; it < 3; ++it) {
                const float wx = 0.5f + 0.5f * fminf(bx / tau, 1.0f);
                const float wy = 0.5f + 0.5f * fminf(by / tau, 1.0f);
                tau = R0_FAST * __frsqrt_rn(wx * wy);
            }
        }
        const float tau2  = tau * tau;
        const float tau2a = tau2 * (1.0f + 2e-6f);

        const int xlo = (int)fmaxf((q.x - tau) * (float)GRID, 0.0f);
        const int xhi = (int)fminf((q.x + tau) * (float)GRID, (float)(GRID - 1));
        const int ylo = (int)fmaxf((q.y - tau) * (float)GRID, 0.0f);
        const int yhi = (int)fminf((q.y + tau) * (float)GRID, (float)(GRID - 1));
        const int nrows = yhi - ylo + 1;

        int sv = 0, ev = 0;
        if (sl < nrows) {
            sv = ST[(ylo + sl) * GRID + xlo];
            ev = ST[(ylo + sl) * GRID + xhi + 1];
        }

        int base = 0, nin = 0;
        for (int r = 0; r < nrows; ++r) {
            const int s = __shfl(sv, r, 32), e = __shfl(ev, r, 32);
            for (int j0 = s; j0 < e; j0 += 32) {
                const int j = j0 + sl;
                const bool valid = (j < e);
                float2 p = make_float2(2.0f, 2.0f);
                if (valid) p = PS[j];
                const float dx = q.x - p.x, dy = q.y - p.y;
                const float d2 = __builtin_fmaf(dy, dy, __fmul_rn(dx, dx));
                const bool adm = valid && (d2 <= tau2a);
                const unsigned bmA = (unsigned)(__ballot(adm) >> (half << 5));
                const unsigned bmS = (unsigned)(__ballot(valid && (d2 <= tau2)) >> (half << 5));
                nin += __popc(bmS);
                if (bmA) {
                    const float ex = __fsqrt_rn(__fadd_rn(__fmul_rn(dx, dx),
                                                          __fmul_rn(dy, dy)));
                    const int pos = base + __popc(bmA & lmlt32);
                    if (adm && pos < CAP)
                        KEYq[pos] =
                            ((unsigned long long)__float_as_uint(ex) << 32) | (unsigned)IS[j];
                    base += __popc(bmA);
                }
            }
        }

        ok = (nin >= 32) && (base <= CAP);
        if (ok) {
            unsigned long long k0 = (sl      < base) ? KEYq[sl]      : ~0ull;
            unsigned long long k1 = (sl + 32 < base) ? KEYq[sl + 32] : ~0ull;
            int r0 = 0, r1 = 0;
            if (!__any(base > 64)) {
                for (int t = 0; t < base; ++t) {
                    const unsigned long long kt = KEYq[t];
                    r0 += (kt < k0) ? 1 : 0;
                    r1 += (kt < k1) ? 1 : 0;
                }
            } else {
                unsigned long long k2 = (sl + 64 < base) ? KEYq[sl + 64] : ~0ull;
                unsigned long long k3 = (sl + 96 < base) ? KEYq[sl + 96] : ~0ull;
                int r2 = 0, r3 = 0;
                for (int t = 0; t < base; ++t) {
                    const unsigned long long kt = KEYq[t];
                    r0 += (kt < k0) ? 1 : 0;
                    r1 += (kt < k1) ? 1 : 0;
                    r2 += (kt < k2) ? 1 : 0;
                    r3 += (kt < k3) ? 1 : 0;
                }
                if (sl + 64 < base && r2 < 32) KEYq[r2] = k2;
                if (sl + 96 < base && r3 < 32) KEYq[r3] = k3;
            }
            if (sl      < base && r0 < 32) KEYq[r0] = k0;
            if (sl + 32 < base && r1 < 32) KEYq[r1] = k1;
            const unsigned long long kf = KEYq[sl];
            bd = __uint_as_float((unsigned)(kf >> 32));
            bi = (int)(unsigned)(kf & 0xffffffffull);

            const float tau32 = __shfl(bd, 31, 32);
            float g = INF;
            if (xlo > 0)        g = fminf(g, q.x - (float)xlo * h);
            if (xhi < GRID - 1) g = fminf(g, (float)(xhi + 1) * h - q.x);
            if (ylo > 0)        g = fminf(g, q.y - (float)ylo * h);
            if (yhi < GRID - 1) g = fminf(g, (float)(yhi + 1) * h - q.y);
            ok = (tau32 < g * (1.0f - 4e-6f));
        }
    }

    // ---------------- SLOW PATH (rare): adaptive, exact ---------------------------
    if (!ok) {
        const int cx = min(GRID - 1, max(0, (int)(q.x * (float)GRID)));
        const int cy = min(GRID - 1, max(0, (int)(q.y * (float)GRID)));
        int L = 2;
        for (;;) {
            const int xlo = max(cx - L, 0), xhi = min(cx + L, GRID - 1);
            const int ylo = max(cy - L, 0), yhi = min(cy + L, GRID - 1);
            const int nrows = yhi - ylo + 1;

            int sv = 0, ev = 0;
            if (sl < nrows) {
                sv = ST[(ylo + sl) * GRID + xlo];
                ev = ST[(ylo + sl) * GRID + xhi + 1];
            }

            float mn1 = INF, mn2 = INF;
            for (int r = 0; r < nrows; ++r) {
                const int s = __shfl(sv, r, 32), e = __shfl(ev, r, 32);
                for (int j = s + sl; j < e; j += 32) {
                    const float2 p = PS[j];
                    const float dx = q.x - p.x, dy = q.y - p.y;
                    const float d2 = __builtin_fmaf(dy, dy, __fmul_rn(dx, dx));
                    const float big = fmaxf(mn1, d2);
                    mn1 = fminf(mn1, d2);
                    mn2 = fminf(mn2, big);
                }
            }

            {
                float v = mn2;
#pragma unroll
                for (int k = 2; k <= 32; k <<= 1) {
#pragma unroll
                    for (int j = k >> 1; j > 0; j >>= 1) {
                        const float o = __shfl_xor(v, j, 32);
                        const bool up = ((sl & k) == 0), lower = ((sl & j) == 0);
                        const float mnv = fminf(v, o), mxv = fmaxf(v, o);
                        v = (lower == up) ? mnv : mxv;
                    }
                }
                mn2 = __shfl(v, 15, 32);
            }
            const float tau2b = mn2 * (1.0f + 4e-6f);

            int base = 0;
            for (int r = 0; r < nrows; ++r) {
                const int s = __shfl(sv, r, 32), e = __shfl(ev, r, 32);
                for (int j0 = s; j0 < e; j0 += 32) {
                    const int j = j0 + sl;
                    const bool valid = (j < e);
                    float2 p = make_float2(0.f, 0.f);
                    if (valid) p = PS[j];
                    const float dx = q.x - p.x, dy = q.y - p.y;
                    const float d2 = __builtin_fmaf(dy, dy, __fmul_rn(dx, dx));
                    const bool pred = valid && (d2 <= tau2b);
                    const unsigned bm = (unsigned)(__ballot(pred) >> (half << 5));
                    if (bm) {
                        const float ex = __fsqrt_rn(__fadd_rn(__fmul_rn(dx, dx),
                                                              __fmul_rn(dy, dy)));
                        const int pos = base + __popc(bm & lmlt32);
                        if (pred && pos < CAP)
                            KEYq[pos] =
                                ((unsigned long long)__float_as_uint(ex) << 32) | (unsigned)IS[j];
                        base += __popc(bm);
                    }
                }
            }

            if (base <= CAP) {
                unsigned long long k0 = (sl      < base) ? KEYq[sl]      : ~0ull;
                unsigned long long k1 = (sl + 32 < base) ? KEYq[sl + 32] : ~0ull;
                int r0 = 0, r1 = 0;
                if (!__any(base > 64)) {
                    for (int t = 0; t < base; ++t) {
                        const unsigned long long kt = KEYq[t];
                        r0 += (kt < k0) ? 1 : 0;
                        r1 += (kt < k1) ? 1 : 0;
                    }
                } else {
                    unsigned long long k2 = (sl + 64 < base) ? KEYq[sl + 64] : ~0ull;
                    unsigned long long k3 = (sl + 96 < base) ? KEYq[sl + 96] : ~0ull;
                    int r2 = 0, r3 = 0;
                    for (int t = 0; t < base; ++t) {
                        const unsigned long long kt = KEYq[t];
                        r0 += (kt < k0) ? 1 : 0;
                        r1 += (kt < k1) ? 1 : 0;
                        r2 += (kt < k2) ? 1 : 0;
                        r3 += (kt < k3) ? 1 : 0;
                    }
                    if (sl + 64 < base && r2 < 32) KEYq[r2] = k2;
                    if (sl + 96 < base && r3 < 32) KEYq[r3] = k3;
                }
                if (sl      < base && r0 < 32) KEYq[r0] = k0;
                if (sl + 32 < base && r1 < 32) KEYq[r1] = k1;
                if (base < 32 && sl >= base) KEYq[sl] = ~0ull;   // pad -> NaN -> expand
                const unsigned long long kf = KEYq[sl];
                bd = __uint_as_float((unsigned)(kf >> 32));
                bi = (int)(unsigned)(kf & 0xffffffffull);
            } else {
                float fd = INF; int fi = 0x7FFFFFFF;
                for (int r = 0; r < nrows; ++r) {
                    const int s = __shfl(sv, r, 32), e = __shfl(ev, r, 32);
                    for (int j0 = s; j0 < e; j0 += 32) {
                        const int j = j0 + sl;
                        const bool valid = (j < e);
                        float2 p = make_float2(0.f, 0.f);
                        int vi0 = 0x7FFFFFFF;
                        if (valid) { p = PS[j]; vi0 = IS[j]; }
                        const float dx = q.x - p.x, dy = q.y - p.y;
                        const float d2 = __builtin_fmaf(dy, dy, __fmul_rn(dx, dx));
                        unsigned cm = (unsigned)(__ballot(valid && (d2 <= tau2b)) >> (half << 5));
                        const float ex = __fsqrt_rn(__fadd_rn(__fmul_rn(dx, dx),
                                                              __fmul_rn(dy, dy)));
                        while (cm) {
                            const int l = __builtin_ctz(cm); cm &= cm - 1;
                            const float v  = __shfl(ex, l, 32);
                            const int   vi = __shfl(vi0, l, 32);
                            const bool cl = (fd < v) || (fd == v && fi < vi);
                            const int pos = __popc((unsigned)(__ballot(cl) >> (half << 5)));
                            const float sd = __shfl_up(fd, 1, 32);
                            const int   si = __shfl_up(fi, 1, 32);
                            fd = (sl < pos) ? fd : ((sl == pos) ? v  : sd);
                            fi = (sl < pos) ? fi : ((sl == pos) ? vi : si);
                        }
                    }
                }
                bd = fd; bi = fi;
            }

            const float tau = __shfl(bd, 31, 32);
            float g = INF;
            if (xlo > 0)        g = fminf(g, q.x - (float)xlo * h);
            if (xhi < GRID - 1) g = fminf(g, (float)(xhi + 1) * h - q.x);
            if (ylo > 0)        g = fminf(g, q.y - (float)ylo * h);
            if (yhi < GRID - 1) g = fminf(g, (float)(yhi + 1) * h - q.y);
            if (tau < g * (1.0f - 4e-6f)) break;
            L += 2;
            if (L > GRID - 1) L = GRID - 1;
        }
    }

    // ---- outputs 0 and 1: uiv_k and idx (as float) ----
    {
        const float2 pk = P[bi];
        float2 u;
        u.x = q.x - pk.x;
        u.y = q.y - pk.y;
        ((float2*)out_uiv)[(size_t)wid * KK + sl] = u;
        out_idx[(size_t)wid * KK + sl] = (float)bi;
    }
}

// ==== K2: gather + einsum + reduce. 8 queries per 256-thread block. ==============
// Reads u and idx back from the output buffer; bd reconstructed bit-exactly.
__global__ __launch_bounds__(256) void conv_apply(
    const float* __restrict__ values_in,
    const float* __restrict__ out_uiv, const float* __restrict__ out_idx,
    const float* __restrict__ coeffT, const float* __restrict__ bias,
    float* __restrict__ out_val)
{
    __shared__ alignas(16) float TL[QPB2][EE][36];   // 18.4 KB

    const int tid   = threadIdx.x;
    const int sl    = tid & 31;
    const int qslot = tid >> 5;            // 0..7
    const int wid   = blockIdx.x * QPB2 + qslot;
    const int b     = wid >> 13;

    float* TLq = &TL[qslot][0][0];

    // neighbor #sl of this query: u stored exactly in K1 -> bd bit-exact
    const float2 u = ((const float2*)out_uiv)[(size_t)wid * KK + sl];
    const float bd = __fsqrt_rn(__fadd_rn(__fmul_rn(u.x, u.x), __fmul_rn(u.y, u.y)));
    const int   bi = (int)out_idx[(size_t)wid * KK + sl];

    // ---- T[e][i] = sum_k exp(-256*(r_k - mu_e)^2) * values_in[b, idx_k, i] ----
    {
        const int e2 = sl >> 2;                 // 0..7 -> e in {2*e2, 2*e2+1}
        const int iq = sl & 3;                  // i-block of 8
        const float mu0 = (float)(2 * e2)     * (1.0f / 15.0f);
        const float mu1 = (float)(2 * e2 + 1) * (1.0f / 15.0f);
        float4 A0a = make_float4(0.f, 0.f, 0.f, 0.f);
        float4 A0b = A0a, A1a = A0a, A1b = A0a;
#pragma unroll
        for (int k = 0; k < KK; ++k) {
            const float rk  = __shfl(bd, k, 32);
            const int   bik = __shfl(bi, k, 32);
            const float d0 = rk - mu0;
            const float d1 = rk - mu1;
            const float w0 = __expf(-256.0f * d0 * d0);
            const float w1 = __expf(-256.0f * d1 * d1);
            const float4* vr = (const float4*)(values_in + ((size_t)b * NN + bik) * CIN + iq * 8);
            const float4 va = vr[0], vb = vr[1];
            A0a.x += w0 * va.x; A0a.y += w0 * va.y; A0a.z += w0 * va.z; A0a.w += w0 * va.w;
            A0b.x += w0 * vb.x; A0b.y += w0 * vb.y; A0b.z += w0 * vb.z; A0b.w += w0 * vb.w;
            A1a.x += w1 * va.x; A1a.y += w1 * va.y; A1a.z += w1 * va.z; A1a.w += w1 * va.w;
            A1b.x += w1 * vb.x; A1b.y += w1 * vb.y; A1b.z += w1 * vb.z; A1b.w += w1 * vb.w;
        }
        float4* t0 = (float4*)(TLq + (2 * e2)     * 36 + iq * 8);
        float4* t1 = (float4*)(TLq + (2 * e2 + 1) * 36 + iq * 8);
        t0[0] = A0a; t0[1] = A0b;
        t1[0] = A1a; t1[1] = A1b;
    }

    // lockstep the 8 qslots so their identical coeffT streams hit L1 together
    __syncthreads();

    // ---- out[o] = (1/K) * sum_{e,i} coeffT[e][o][i] * T[e][i] + bias[o] ----
    {
        const int o = sl;
        float s = 0.f;
#pragma unroll
        for (int e2 = 0; e2 < EE; ++e2) {
            const float4* crow = (const float4*)(coeffT + ((size_t)e2 * COUT + o) * CIN);
            const float4* trow = (const float4*)(TLq + e2 * 36);
#pragma unroll
            for (int i4 = 0; i4 < 8; ++i4) {
                const float4 c  = crow[i4];
                const float4 tv = trow[i4];
                s += c.x * tv.x + c.y * tv.y + c.z * tv.z + c.w * tv.w;
            }
        }
        out_val[(size_t)wid * COUT + o] = s * (1.0f / 32.0f) + bias[o];
    }
}

extern "C" void kernel_launch(void* const* d_in, const int* in_sizes, int n_in,
                              void* d_out, int out_size, void* d_ws, size_t ws_size,
                              hipStream_t stream) {
    const float* points_in  = (const float*)d_in[0];
    const float* values_in  = (const float*)d_in[1];
    const float* points_out = (const float*)d_in[2];
    const float* coeff      = (const float*)d_in[3];
    const float* bias       = (const float*)d_in[4];

    float* out     = (float*)d_out;
    float* out_uiv = out;                                        // B*M*K*2
    float* out_idx = out + (size_t)BB * MM * KK * 2;             // B*M*K
    float* out_val = out_idx + (size_t)BB * MM * KK;             // B*M*COUT

    char* ws = (char*)d_ws;
    float*  coeffT = (float*)(ws + OFS_COEFFT);
    int*    counts = (int*)  (ws + OFS_COUNTS);
    int*    cursor = (int*)  (ws + OFS_CURSOR);
    int*    strts  = (int*)  (ws + OFS_STARTS);
    float2* pts_s  = (float2*)(ws + OFS_PTSS);
    int*    idx_s  = (int*)  (ws + OFS_IDXS);

    hipLaunchKernelGGL(transpose_coeff, dim3(64), dim3(256), 0, stream, coeff, coeffT);
    hipLaunchKernelGGL(bin_zero, dim3(16), dim3(256), 0, stream, counts);
    hipLaunchKernelGGL(bin_count, dim3(64), dim3(256), 0, stream, points_in, counts);
    hipLaunchKernelGGL(bin_scan, dim3(1), dim3(1024), 0, stream, counts, strts);
    hipLaunchKernelGGL(bin_scatter, dim3(64), dim3(256), 0, stream,
                       points_in, strts, cursor, pts_s, idx_s);

    const int blocks1 = (BB * MM) / QPB;                         // 4096
    hipLaunchKernelGGL(conv_knn, dim3(blocks1), dim3(128), 0, stream,
                       pts_s, idx_s, strts, points_in, points_out,
                       out_uiv, out_idx);

    const int blocks2 = (BB * MM) / QPB2;                        // 2048
    hipLaunchKernelGGL(conv_apply, dim3(blocks2), dim3(256), 0, stream,
                       values_in, out_uiv, out_idx, coeffT, bias, out_val);
}

// Round 14
// 162.075 us; speedup vs baseline: 1.0483x; 1.0483x over previous
//
#include <hip/hip_runtime.h>
#include <cstdint>
#include <cstddef>

// Problem constants (from reference)
constexpr int BB   = 2;
constexpr int NN   = 8192;
constexpr int MM   = 8192;
constexpr int CIN  = 32;
constexpr int COUT = 32;
constexpr int EE   = 16;
constexpr int KK   = 32;
constexpr int GRID = 32;              // binning grid (h = 1/32, ~8 pts/cell)
constexpr int NCELL = GRID * GRID;

#define QPB 4            // K1: queries per 128-thread block
#define QPB2 8           // K2: queries per 256-thread block
#define CAP 128
#define KEY_BYTES 1040   // 128 u64 + 16B skew
#define VROW 36          // K2: padded value-row stride in floats (144B: aligned+skew)

// Fixed-radius fast path: lambda = pi*R0^2*N ~ 58 expected candidates.
#define R0_FAST 0.0475f

// Workspace layout (bytes)
constexpr size_t OFS_COEFFT = 0;        // 16384 f = 65536 B
constexpr size_t OFS_COUNTS = 65536;    // 2*1024 i = 8192 B
constexpr size_t OFS_CURSOR = 73728;    // 2*1024 i = 8192 B
constexpr size_t OFS_STARTS = 81920;    // 2*1025 i = 8200 B (pad to 8704)
constexpr size_t OFS_PTSS   = 90624;    // 2*8192 float2 = 131072 B
constexpr size_t OFS_IDXS   = 221696;   // 2*8192 i = 65536 B  (total 287232 B)

// ---- coeff [CIN][COUT][E] -> coeffT [E][COUT][CIN] ------------------------------
__global__ __launch_bounds__(256) void transpose_coeff(const float* __restrict__ coeff,
                                                       float* __restrict__ coeffT) {
    int tid = blockIdx.x * 256 + threadIdx.x;
    if (tid >= EE * COUT * CIN) return;
    int i = tid & 31;
    int o = (tid >> 5) & 31;
    int e = tid >> 10;
    coeffT[tid] = coeff[(i * COUT + o) * EE + e];
}

// ---- binning: zero, count, scan, scatter ----------------------------------------
__global__ __launch_bounds__(256) void bin_zero(int* __restrict__ p) {
    int t = blockIdx.x * 256 + threadIdx.x;
    if (t < 2 * 2 * NCELL) p[t] = 0;
}

__device__ __forceinline__ int cell_of(float2 p) {
    int cx = min(GRID - 1, max(0, (int)(p.x * (float)GRID)));
    int cy = min(GRID - 1, max(0, (int)(p.y * (float)GRID)));
    return cy * GRID + cx;
}

__global__ __launch_bounds__(256) void bin_count(const float* __restrict__ pts,
                                                 int* __restrict__ counts) {
    int t = blockIdx.x * 256 + threadIdx.x;
    int b = t >> 13, i = t & (NN - 1);
    float2 p = ((const float2*)pts)[(size_t)b * NN + i];
    atomicAdd(&counts[b * NCELL + cell_of(p)], 1);
}

__global__ __launch_bounds__(1024) void bin_scan(const int* __restrict__ counts,
                                                 int* __restrict__ starts) {
    __shared__ int sm[NCELL];
    const int t = threadIdx.x;
    for (int b = 0; b < BB; ++b) {
        sm[t] = counts[b * NCELL + t];
        __syncthreads();
        for (int off = 1; off < NCELL; off <<= 1) {
            int v = (t >= off) ? sm[t - off] : 0;
            __syncthreads();
            sm[t] += v;
            __syncthreads();
        }
        starts[b * (NCELL + 1) + t + 1] = sm[t];
        if (t == 0) starts[b * (NCELL + 1)] = 0;
        __syncthreads();
    }
}

__global__ __launch_bounds__(256) void bin_scatter(const float* __restrict__ pts,
                                                   const int* __restrict__ starts,
                                                   int* __restrict__ cursor,
                                                   float2* __restrict__ pts_s,
                                                   int* __restrict__ idx_s) {
    int t = blockIdx.x * 256 + threadIdx.x;
    int b = t >> 13, i = t & (NN - 1);
    float2 p = ((const float2*)pts)[(size_t)b * NN + i];
    int cell = cell_of(p);
    int pos = starts[b * (NCELL + 1) + cell] + atomicAdd(&cursor[b * NCELL + cell], 1);
    pts_s[(size_t)b * NN + pos] = p;     // intra-cell order nondeterministic; final
    idx_s[(size_t)b * NN + pos] = i;     // rank by (d, orig idx) makes output exact.
}

// ==== K1: KNN selection only. One half-wave (32 lanes) per query. ================
__global__ __launch_bounds__(128) void conv_knn(
    const float2* __restrict__ pts_s, const int* __restrict__ idx_s,
    const int* __restrict__ starts,
    const float* __restrict__ points_in,
    const float* __restrict__ points_out,
    float* __restrict__ out_uiv, float* __restrict__ out_idx)
{
    __shared__ alignas(16) unsigned char SMEM[QPB][KEY_BYTES];

    const int tid   = threadIdx.x;
    const int sl    = tid & 31;
    const int qslot = tid >> 5;            // 0..3
    const int half  = qslot & 1;
    const int wid   = blockIdx.x * QPB + qslot;
    const int b     = wid >> 13;
    const int m     = wid & (MM - 1);

    unsigned long long* KEYq = (unsigned long long*)&SMEM[qslot][0];

    const float2* PS = pts_s + (size_t)b * NN;
    const int*    IS = idx_s + (size_t)b * NN;
    const int*    ST = starts + b * (NCELL + 1);
    const float2* P  = ((const float2*)points_in) + (size_t)b * NN;
    const float2  q  = ((const float2*)points_out)[(size_t)b * MM + m];

    const float INF = __builtin_inff();
    const float h = 1.0f / (float)GRID;
    const unsigned lmlt32 = (1u << sl) - 1u;

    float bd;   // sorted exact distance (sub-lane sl holds entry #sl)
    int   bi;   // sorted original index
    bool  ok = false;

    // ---------------- FAST PATH: fixed analytic radius, single scan ---------------
    {
        float tau = R0_FAST;
        {
            const float bx = fminf(q.x, 1.0f - q.x);
            const float by = fminf(q.y, 1.0f - q.y);
#pragma unroll
            for (int it = 0; it < 3; ++it) {
                const float wx = 0.5f + 0.5f * fminf(bx / tau, 1.0f);
                const float wy = 0.5f + 0.5f * fminf(by / tau, 1.0f);
                tau = R0_FAST * __frsqrt_rn(wx * wy);
            }
        }
        const float tau2  = tau * tau;
        const float tau2a = tau2 * (1.0f + 2e-6f);

        const int xlo = (int)fmaxf((q.x - tau) * (float)GRID, 0.0f);
        const int xhi = (int)fminf((q.x + tau) * (float)GRID, (float)(GRID - 1));
        const int ylo = (int)fmaxf((q.y - tau) * (float)GRID, 0.0f);
        const int yhi = (int)fminf((q.y + tau) * (float)GRID, (float)(GRID - 1));
        const int nrows = yhi - ylo + 1;

        int sv = 0, ev = 0;
        if (sl < nrows) {
            sv = ST[(ylo + sl) * GRID + xlo];
            ev = ST[(ylo + sl) * GRID + xhi + 1];
        }

        int base = 0, nin = 0;
        for (int r = 0; r < nrows; ++r) {
            const int s = __shfl(sv, r, 32), e = __shfl(ev, r, 32);
            for (int j0 = s; j0 < e; j0 += 32) {
                const int j = j0 + sl;
                const bool valid = (j < e);
                float2 p = make_float2(2.0f, 2.0f);
                if (valid) p = PS[j];
                const float dx = q.x - p.x, dy = q.y - p.y;
                const float d2 = __builtin_fmaf(dy, dy, __fmul_rn(dx, dx));
                const bool adm = valid && (d2 <= tau2a);
                const unsigned bmA = (unsigned)(__ballot(adm) >> (half << 5));
                const unsigned bmS = (unsigned)(__ballot(valid && (d2 <= tau2)) >> (half << 5));
                nin += __popc(bmS);
                if (bmA) {
                    const float ex = __fsqrt_rn(__fadd_rn(__fmul_rn(dx, dx),
                                                          __fmul_rn(dy, dy)));
                    const int pos = base + __popc(bmA & lmlt32);
                    if (adm && pos < CAP)
                        KEYq[pos] =
                            ((unsigned long long)__float_as_uint(ex) << 32) | (unsigned)IS[j];
                    base += __popc(bmA);
                }
            }
        }

        ok = (nin >= 32) && (base <= CAP);
        if (ok) {
            unsigned long long k0 = (sl      < base) ? KEYq[sl]      : ~0ull;
            unsigned long long k1 = (sl + 32 < base) ? KEYq[sl + 32] : ~0ull;
            int r0 = 0, r1 = 0;
            if (!__any(base > 64)) {
                for (int t = 0; t < base; ++t) {
                    const unsigned long long kt = KEYq[t];
                    r0 += (kt < k0) ? 1 : 0;
                    r1 += (kt < k1) ? 1 : 0;
                }
            } else {
                unsigned long long k2 = (sl + 64 < base) ? KEYq[sl + 64] : ~0ull;
                unsigned long long k3 = (sl + 96 < base) ? KEYq[sl + 96] : ~0ull;
                int r2 = 0, r3 = 0;
                for (int t = 0; t < base; ++t) {
                    const unsigned long long kt = KEYq[t];
                    r0 += (kt < k0) ? 1 : 0;
                    r1 += (kt < k1) ? 1 : 0;
                    r2 += (kt < k2) ? 1 : 0;
                    r3 += (kt < k3) ? 1 : 0;
                }
                if (sl + 64 < base && r2 < 32) KEYq[r2] = k2;
                if (sl + 96 < base && r3 < 32) KEYq[r3] = k3;
            }
            if (sl      < base && r0 < 32) KEYq[r0] = k0;
            if (sl + 32 < base && r1 < 32) KEYq[r1] = k1;
            const unsigned long long kf = KEYq[sl];
            bd = __uint_as_float((unsigned)(kf >> 32));
            bi = (int)(unsigned)(kf & 0xffffffffull);

            const float tau32 = __shfl(bd, 31, 32);
            float g = INF;
            if (xlo > 0)        g = fminf(g, q.x - (float)xlo * h);
            if (xhi < GRID - 1) g = fminf(g, (float)(xhi + 1) * h - q.x);
            if (ylo > 0)        g = fminf(g, q.y - (float)ylo * h);
            if (yhi < GRID - 1) g = fminf(g, (float)(yhi + 1) * h - q.y);
            ok = (tau32 < g * (1.0f - 4e-6f));
        }
    }

    // ---------------- SLOW PATH (rare): adaptive, exact ---------------------------
    if (!ok) {
        const int cx = min(GRID - 1, max(0, (int)(q.x * (float)GRID)));
        const int cy = min(GRID - 1, max(0, (int)(q.y * (float)GRID)));
        int L = 2;
        for (;;) {
            const int xlo = max(cx - L, 0), xhi = min(cx + L, GRID - 1);
            const int ylo = max(cy - L, 0), yhi = min(cy + L, GRID - 1);
            const int nrows = yhi - ylo + 1;

            int sv = 0, ev = 0;
            if (sl < nrows) {
                sv = ST[(ylo + sl) * GRID + xlo];
                ev = ST[(ylo + sl) * GRID + xhi + 1];
            }

            float mn1 = INF, mn2 = INF;
            for (int r = 0; r < nrows; ++r) {
                const int s = __shfl(sv, r, 32), e = __shfl(ev, r, 32);
                for (int j = s + sl; j < e; j += 32) {
                    const float2 p = PS[j];
                    const float dx = q.x - p.x, dy = q.y - p.y;
                    const float d2 = __builtin_fmaf(dy, dy, __fmul_rn(dx, dx));
                    const float big = fmaxf(mn1, d2);
                    mn1 = fminf(mn1, d2);
                    mn2 = fminf(mn2, big);
                }
            }

            {
                float v = mn2;
#pragma unroll
                for (int k = 2; k <= 32; k <<= 1) {
#pragma unroll
                    for (int j = k >> 1; j > 0; j >>= 1) {
                        const float o = __shfl_xor(v, j, 32);
                        const bool up = ((sl & k) == 0), lower = ((sl & j) == 0);
                        const float mnv = fminf(v, o), mxv = fmaxf(v, o);
                        v = (lower == up) ? mnv : mxv;
                    }
                }
                mn2 = __shfl(v, 15, 32);
            }
            const float tau2b = mn2 * (1.0f + 4e-6f);

            int base = 0;
            for (int r = 0; r < nrows; ++r) {
                const int s = __shfl(sv, r, 32), e = __shfl(ev, r, 32);
                for (int j0 = s; j0 < e; j0 += 32) {
                    const int j = j0 + sl;
                    const bool valid = (j < e);
                    float2 p = make_float2(0.f, 0.f);
                    if (valid) p = PS[j];
                    const float dx = q.x - p.x, dy = q.y - p.y;
                    const float d2 = __builtin_fmaf(dy, dy, __fmul_rn(dx, dx));
                    const bool pred = valid && (d2 <= tau2b);
                    const unsigned bm = (unsigned)(__ballot(pred) >> (half << 5));
                    if (bm) {
                        const float ex = __fsqrt_rn(__fadd_rn(__fmul_rn(dx, dx),
                                                              __fmul_rn(dy, dy)));
                        const int pos = base + __popc(bm & lmlt32);
                        if (pred && pos < CAP)
                            KEYq[pos] =
                                ((unsigned long long)__float_as_uint(ex) << 32) | (unsigned)IS[j];
                        base += __popc(bm);
                    }
                }
            }

            if (base <= CAP) {
                unsigned long long k0 = (sl      < base) ? KEYq[sl]      : ~0ull;
                unsigned long long k1 = (sl + 32 < base) ? KEYq[sl + 32] : ~0ull;
                int r0 = 0, r1 = 0;
                if (!__any(base > 64)) {
                    for (int t = 0; t < base; ++t) {
                        const unsigned long long kt = KEYq[t];
                        r0 += (kt < k0) ? 1 : 0;
                        r1 += (kt < k1) ? 1 : 0;
                    }
                } else {
                    unsigned long long k2 = (sl + 64 < base) ? KEYq[sl + 64] : ~0ull;
                    unsigned long long k3 = (sl + 96 < base) ? KEYq[sl + 96] : ~0ull;
                    int r2 = 0, r3 = 0;
                    for (int t = 0; t < base; ++t) {
                        const unsigned long long kt = KEYq[t];
                        r0 += (kt < k0) ? 1 : 0;
                        r1 += (kt < k1) ? 1 : 0;
                        r2 += (kt < k2) ? 1 : 0;
                        r3 += (kt < k3) ? 1 : 0;
                    }
                    if (sl + 64 < base && r2 < 32) KEYq[r2] = k2;
                    if (sl + 96 < base && r3 < 32) KEYq[r3] = k3;
                }
                if (sl      < base && r0 < 32) KEYq[r0] = k0;
                if (sl + 32 < base && r1 < 32) KEYq[r1] = k1;
                if (base < 32 && sl >= base) KEYq[sl] = ~0ull;   // pad -> NaN -> expand
                const unsigned long long kf = KEYq[sl];
                bd = __uint_as_float((unsigned)(kf >> 32));
                bi = (int)(unsigned)(kf & 0xffffffffull);
            } else {
                float fd = INF; int fi = 0x7FFFFFFF;
                for (int r = 0; r < nrows; ++r) {
                    const int s = __shfl(sv, r, 32), e = __shfl(ev, r, 32);
                    for (int j0 = s; j0 < e; j0 += 32) {
                        const int j = j0 + sl;
                        const bool valid = (j < e);
                        float2 p = make_float2(0.f, 0.f);
                        int vi0 = 0x7FFFFFFF;
                        if (valid) { p = PS[j]; vi0 = IS[j]; }
                        const float dx = q.x - p.x, dy = q.y - p.y;
                        const float d2 = __builtin_fmaf(dy, dy, __fmul_rn(dx, dx));
                        unsigned cm = (unsigned)(__ballot(valid && (d2 <= tau2b)) >> (half << 5));
                        const float ex = __fsqrt_rn(__fadd_rn(__fmul_rn(dx, dx),
                                                              __fmul_rn(dy, dy)));
                        while (cm) {
                            const int l = __builtin_ctz(cm); cm &= cm - 1;
                            const float v  = __shfl(ex, l, 32);
                            const int   vi = __shfl(vi0, l, 32);
                            const bool cl = (fd < v) || (fd == v && fi < vi);
                            const int pos = __popc((unsigned)(__ballot(cl) >> (half << 5)));
                            const float sd = __shfl_up(fd, 1, 32);
                            const int   si = __shfl_up(fi, 1, 32);
                            fd = (sl < pos) ? fd : ((sl == pos) ? v  : sd);
                            fi = (sl < pos) ? fi : ((sl == pos) ? vi : si);
                        }
                    }
                }
                bd = fd; bi = fi;
            }

            const float tau = __shfl(bd, 31, 32);
            float g = INF;
            if (xlo > 0)        g = fminf(g, q.x - (float)xlo * h);
            if (xhi < GRID - 1) g = fminf(g, (float)(xhi + 1) * h - q.x);
            if (ylo > 0)        g = fminf(g, q.y - (float)ylo * h);
            if (yhi < GRID - 1) g = fminf(g, (float)(yhi + 1) * h - q.y);
            if (tau < g * (1.0f - 4e-6f)) break;
            L += 2;
            if (L > GRID - 1) L = GRID - 1;
        }
    }

    // ---- outputs 0 and 1: uiv_k and idx (as float) ----
    {
        const float2 pk = P[bi];
        float2 u;
        u.x = q.x - pk.x;
        u.y = q.y - pk.y;
        ((float2*)out_uiv)[(size_t)wid * KK + sl] = u;
        out_idx[(size_t)wid * KK + sl] = (float)bi;
    }
}

// ==== K2: gather + einsum + reduce, LDS-staged. 8 queries / 256-thread block. ====
// Phase A: lane sl stages ITS OWN neighbor's value row (address from own bi -> no
// cross-lane dependency; 8 independent float4 loads -> single latency exposure).
// Phase G: T-accumulation reads v from LDS (12cy, broadcast) instead of L2 (~200cy).
// Phase R: unchanged reduce; T overlays VL (same-half-wave phase ordering).
__global__ __launch_bounds__(256) void conv_apply(
    const float* __restrict__ values_in,
    const float* __restrict__ out_uiv, const float* __restrict__ out_idx,
    const float* __restrict__ coeffT, const float* __restrict__ bias,
    float* __restrict__ out_val)
{
    __shared__ alignas(16) float VL[QPB2][KK][VROW];   // 8*32*36*4 = 36864 B

    const int tid   = threadIdx.x;
    const int sl    = tid & 31;
    const int qslot = tid >> 5;            // 0..7
    const int wid   = blockIdx.x * QPB2 + qslot;
    const int b     = wid >> 13;

    float* VLq = &VL[qslot][0][0];

    // neighbor #sl of this query: u stored exactly in K1 -> bd bit-exact
    const float2 u = ((const float2*)out_uiv)[(size_t)wid * KK + sl];
    const float bd = __fsqrt_rn(__fadd_rn(__fmul_rn(u.x, u.x), __fmul_rn(u.y, u.y)));
    const int   bi = (int)out_idx[(size_t)wid * KK + sl];

    // ---- Phase A: stage my neighbor's 32-float value row into LDS ----
    {
        const float4* src = (const float4*)(values_in + ((size_t)b * NN + bi) * CIN);
        const float4 r0 = src[0], r1 = src[1], r2 = src[2], r3 = src[3];
        const float4 r4 = src[4], r5 = src[5], r6 = src[6], r7 = src[7];
        float4* dst = (float4*)(VLq + sl * VROW);
        dst[0] = r0; dst[1] = r1; dst[2] = r2; dst[3] = r3;
        dst[4] = r4; dst[5] = r5; dst[6] = r6; dst[7] = r7;
    }

    // ---- Phase G: T[e][i] = sum_k exp(-256*(r_k - mu_e)^2) * v_k[i], v from LDS --
    const int e2 = sl >> 2;                 // 0..7 -> e in {2*e2, 2*e2+1}
    const int iq = sl & 3;                  // i-block of 8
    {
        const float mu0 = (float)(2 * e2)     * (1.0f / 15.0f);
        const float mu1 = (float)(2 * e2 + 1) * (1.0f / 15.0f);
        float4 A0a = make_float4(0.f, 0.f, 0.f, 0.f);
        float4 A0b = A0a, A1a = A0a, A1b = A0a;
#pragma unroll 8
        for (int k = 0; k < KK; ++k) {
            const float rk = __shfl(bd, k, 32);
            const float d0 = rk - mu0;
            const float d1 = rk - mu1;
            const float w0 = __expf(-256.0f * d0 * d0);
            const float w1 = __expf(-256.0f * d1 * d1);
            const float4* vr = (const float4*)(VLq + k * VROW + iq * 8);
            const float4 va = vr[0], vb = vr[1];
            A0a.x += w0 * va.x; A0a.y += w0 * va.y; A0a.z += w0 * va.z; A0a.w += w0 * va.w;
            A0b.x += w0 * vb.x; A0b.y += w0 * vb.y; A0b.z += w0 * vb.z; A0b.w += w0 * vb.w;
            A1a.x += w1 * va.x; A1a.y += w1 * va.y; A1a.z += w1 * va.z; A1a.w += w1 * va.w;
            A1b.x += w1 * vb.x; A1b.y += w1 * vb.y; A1b.z += w1 * vb.z; A1b.w += w1 * vb.w;
        }
        // overlay T (16x36 floats) onto the VL region -- all G reads precede these
        // stores in program order within this same half-wave.
        float4* t0 = (float4*)(VLq + (2 * e2)     * VROW + iq * 8);
        float4* t1 = (float4*)(VLq + (2 * e2 + 1) * VROW + iq * 8);
        t0[0] = A0a; t0[1] = A0b;
        t1[0] = A1a; t1[1] = A1b;
    }

    // ---- Phase R: out[o] = (1/K) * sum_{e,i} coeffT[e][o][i] * T[e][i] + bias[o] -
    {
        const int o = sl;
        float s = 0.f;
#pragma unroll
        for (int e = 0; e < EE; ++e) {
            const float4* crow = (const float4*)(coeffT + ((size_t)e * COUT + o) * CIN);
            const float4* trow = (const float4*)(VLq + e * VROW);
#pragma unroll
            for (int i4 = 0; i4 < 8; ++i4) {
                const float4 c  = crow[i4];
                const float4 tv = trow[i4];
                s += c.x * tv.x + c.y * tv.y + c.z * tv.z + c.w * tv.w;
            }
        }
        out_val[(size_t)wid * COUT + o] = s * (1.0f / 32.0f) + bias[o];
    }
}

extern "C" void kernel_launch(void* const* d_in, const int* in_sizes, int n_in,
                              void* d_out, int out_size, void* d_ws, size_t ws_size,
                              hipStream_t stream) {
    const float* points_in  = (const float*)d_in[0];
    const float* values_in  = (const float*)d_in[1];
    const float* points_out = (const float*)d_in[2];
    const float* coeff      = (const float*)d_in[3];
    const float* bias       = (const float*)d_in[4];

    float* out     = (float*)d_out;
    float* out_uiv = out;                                        // B*M*K*2
    float* out_idx = out + (size_t)BB * MM * KK * 2;             // B*M*K
    float* out_val = out_idx + (size_t)BB * MM * KK;             // B*M*COUT

    char* ws = (char*)d_ws;
    float*  coeffT = (float*)(ws + OFS_COEFFT);
    int*    counts = (int*)  (ws + OFS_COUNTS);
    int*    cursor = (int*)  (ws + OFS_CURSOR);
    int*    strts  = (int*)  (ws + OFS_STARTS);
    float2* pts_s  = (float2*)(ws + OFS_PTSS);
    int*    idx_s  = (int*)  (ws + OFS_IDXS);

    hipLaunchKernelGGL(transpose_coeff, dim3(64), dim3(256), 0, stream, coeff, coeffT);
    hipLaunchKernelGGL(bin_zero, dim3(16), dim3(256), 0, stream, counts);
    hipLaunchKernelGGL(bin_count, dim3(64), dim3(256), 0, stream, points_in, counts);
    hipLaunchKernelGGL(bin_scan, dim3(1), dim3(1024), 0, stream, counts, strts);
    hipLaunchKernelGGL(bin_scatter, dim3(64), dim3(256), 0, stream,
                       points_in, strts, cursor, pts_s, idx_s);

    const int blocks1 = (BB * MM) / QPB;                         // 4096
    hipLaunchKernelGGL(conv_knn, dim3(blocks1), dim3(128), 0, stream,
                       pts_s, idx_s, strts, points_in, points_out,
                       out_uiv, out_idx);

    const int blocks2 = (BB * MM) / QPB2;                        // 2048
    hipLaunchKernelGGL(conv_apply, dim3(blocks2), dim3(256), 0, stream,
                       values_in, out_uiv, out_idx, coeffT, bias, out_val);
}

// Round 15
// 81.623 us; speedup vs baseline: 2.0815x; 1.9856x over previous
//
#include <hip/hip_runtime.h>
#include <cstdint>
#include <cstddef>

// Problem constants (from reference)
constexpr int BB   = 2;
constexpr int NN   = 8192;
constexpr int MM   = 8192;
constexpr int CIN  = 32;
constexpr int COUT = 32;
constexpr int EE   = 16;
constexpr int KK   = 32;
constexpr int GRID = 32;              // binning grid (h = 1/32, ~8 pts/cell)
constexpr int NCELL = GRID * GRID;

#define QPB 4            // K1: queries per 128-thread block
#define QPB2 8           // K2: queries per 256-thread block
#define CAP 128
#define KEY_BYTES 1040   // 128 u64 + 16B skew
#define VROW 36          // K2: padded value-row stride in floats (144B: aligned+skew)
#define ECH 4            // K2: e-chunk size for coeff LDS staging

// Fixed-radius fast path: lambda = pi*R0^2*N ~ 58 expected candidates.
#define R0_FAST 0.0475f

// Workspace layout (bytes)
constexpr size_t OFS_COEFFT = 0;        // coeff2[E][CIN][COUT]: 16384 f = 65536 B
constexpr size_t OFS_COUNTS = 65536;    // 2*1024 i = 8192 B
constexpr size_t OFS_CURSOR = 73728;    // 2*1024 i = 8192 B
constexpr size_t OFS_STARTS = 81920;    // 2*1025 i = 8200 B (pad to 8704)
constexpr size_t OFS_PTSS   = 90624;    // 2*8192 float2 = 131072 B
constexpr size_t OFS_IDXS   = 221696;   // 2*8192 i = 65536 B  (total 287232 B)

// ---- coeff [CIN][COUT][E] -> coeff2 [E][CIN][COUT] ------------------------------
// (o fastest so Phase-R lane reads are stride-1 across lanes)
__global__ __launch_bounds__(256) void transpose_coeff(const float* __restrict__ coeff,
                                                       float* __restrict__ coeff2) {
    int tid = blockIdx.x * 256 + threadIdx.x;
    if (tid >= EE * CIN * COUT) return;
    int o = tid & 31;
    int i = (tid >> 5) & 31;
    int e = tid >> 10;
    coeff2[tid] = coeff[(i * COUT + o) * EE + e];
}

// ---- binning: zero, count, scan, scatter ----------------------------------------
__global__ __launch_bounds__(256) void bin_zero(int* __restrict__ p) {
    int t = blockIdx.x * 256 + threadIdx.x;
    if (t < 2 * 2 * NCELL) p[t] = 0;
}

__device__ __forceinline__ int cell_of(float2 p) {
    int cx = min(GRID - 1, max(0, (int)(p.x * (float)GRID)));
    int cy = min(GRID - 1, max(0, (int)(p.y * (float)GRID)));
    return cy * GRID + cx;
}

__global__ __launch_bounds__(256) void bin_count(const float* __restrict__ pts,
                                                 int* __restrict__ counts) {
    int t = blockIdx.x * 256 + threadIdx.x;
    int b = t >> 13, i = t & (NN - 1);
    float2 p = ((const float2*)pts)[(size_t)b * NN + i];
    atomicAdd(&counts[b * NCELL + cell_of(p)], 1);
}

__global__ __launch_bounds__(1024) void bin_scan(const int* __restrict__ counts,
                                                 int* __restrict__ starts) {
    __shared__ int sm[NCELL];
    const int t = threadIdx.x;
    for (int b = 0; b < BB; ++b) {
        sm[t] = counts[b * NCELL + t];
        __syncthreads();
        for (int off = 1; off < NCELL; off <<= 1) {
            int v = (t >= off) ? sm[t - off] : 0;
            __syncthreads();
            sm[t] += v;
            __syncthreads();
        }
        starts[b * (NCELL + 1) + t + 1] = sm[t];
        if (t == 0) starts[b * (NCELL + 1)] = 0;
        __syncthreads();
    }
}

__global__ __launch_bounds__(256) void bin_scatter(const float* __restrict__ pts,
                                                   const int* __restrict__ starts,
                                                   int* __restrict__ cursor,
                                                   float2* __restrict__ pts_s,
                                                   int* __restrict__ idx_s) {
    int t = blockIdx.x * 256 + threadIdx.x;
    int b = t >> 13, i = t & (NN - 1);
    float2 p = ((const float2*)pts)[(size_t)b * NN + i];
    int cell = cell_of(p);
    int pos = starts[b * (NCELL + 1) + cell] + atomicAdd(&cursor[b * NCELL + cell], 1);
    pts_s[(size_t)b * NN + pos] = p;     // intra-cell order nondeterministic; final
    idx_s[(size_t)b * NN + pos] = i;     // rank by (d, orig idx) makes output exact.
}

// ==== K1: KNN selection only. One half-wave (32 lanes) per query. ================
__global__ __launch_bounds__(128) void conv_knn(
    const float2* __restrict__ pts_s, const int* __restrict__ idx_s,
    const int* __restrict__ starts,
    const float* __restrict__ points_in,
    const float* __restrict__ points_out,
    float* __restrict__ out_uiv, float* __restrict__ out_idx)
{
    __shared__ alignas(16) unsigned char SMEM[QPB][KEY_BYTES];

    const int tid   = threadIdx.x;
    const int sl    = tid & 31;
    const int qslot = tid >> 5;            // 0..3
    const int half  = qslot & 1;
    const int wid   = blockIdx.x * QPB + qslot;
    const int b     = wid >> 13;
    const int m     = wid & (MM - 1);

    unsigned long long* KEYq = (unsigned long long*)&SMEM[qslot][0];

    const float2* PS = pts_s + (size_t)b * NN;
    const int*    IS = idx_s + (size_t)b * NN;
    const int*    ST = starts + b * (NCELL + 1);
    const float2* P  = ((const float2*)points_in) + (size_t)b * NN;
    const float2  q  = ((const float2*)points_out)[(size_t)b * MM + m];

    const float INF = __builtin_inff();
    const float h = 1.0f / (float)GRID;
    const unsigned lmlt32 = (1u << sl) - 1u;

    float bd;   // sorted exact distance (sub-lane sl holds entry #sl)
    int   bi;   // sorted original index
    bool  ok = false;

    // ---------------- FAST PATH: fixed analytic radius, single scan ---------------
    {
        float tau = R0_FAST;
        {
            const float bx = fminf(q.x, 1.0f - q.x);
            const float by = fminf(q.y, 1.0f - q.y);
#pragma unroll
            for (int it = 0; it < 3; ++it) {
                const float wx = 0.5f + 0.5f * fminf(bx / tau, 1.0f);
                const float wy = 0.5f + 0.5f * fminf(by / tau, 1.0f);
                tau = R0_FAST * __frsqrt_rn(wx * wy);
            }
        }
        const float tau2  = tau * tau;
        const float tau2a = tau2 * (1.0f + 2e-6f);

        const int xlo = (int)fmaxf((q.x - tau) * (float)GRID, 0.0f);
        const int xhi = (int)fminf((q.x + tau) * (float)GRID, (float)(GRID - 1));
        const int ylo = (int)fmaxf((q.y - tau) * (float)GRID, 0.0f);
        const int yhi = (int)fminf((q.y + tau) * (float)GRID, (float)(GRID - 1));
        const int nrows = yhi - ylo + 1;

        int sv = 0, ev = 0;
        if (sl < nrows) {
            sv = ST[(ylo + sl) * GRID + xlo];
            ev = ST[(ylo + sl) * GRID + xhi + 1];
        }

        int base = 0, nin = 0;
        for (int r = 0; r < nrows; ++r) {
            const int s = __shfl(sv, r, 32), e = __shfl(ev, r, 32);
            for (int j0 = s; j0 < e; j0 += 32) {
                const int j = j0 + sl;
                const bool valid = (j < e);
                float2 p = make_float2(2.0f, 2.0f);
                if (valid) p = PS[j];
                const float dx = q.x - p.x, dy = q.y - p.y;
                const float d2 = __builtin_fmaf(dy, dy, __fmul_rn(dx, dx));
                const bool adm = valid && (d2 <= tau2a);
                const unsigned bmA = (unsigned)(__ballot(adm) >> (half << 5));
                const unsigned bmS = (unsigned)(__ballot(valid && (d2 <= tau2)) >> (half << 5));
                nin += __popc(bmS);
                if (bmA) {
                    const float ex = __fsqrt_rn(__fadd_rn(__fmul_rn(dx, dx),
                                                          __fmul_rn(dy, dy)));
                    const int pos = base + __popc(bmA & lmlt32);
                    if (adm && pos < CAP)
                        KEYq[pos] =
                            ((unsigned long long)__float_as_uint(ex) << 32) | (unsigned)IS[j];
                    base += __popc(bmA);
                }
            }
        }

        ok = (nin >= 32) && (base <= CAP);
        if (ok) {
            unsigned long long k0 = (sl      < base) ? KEYq[sl]      : ~0ull;
            unsigned long long k1 = (sl + 32 < base) ? KEYq[sl + 32] : ~0ull;
            int r0 = 0, r1 = 0;
            if (!__any(base > 64)) {
                for (int t = 0; t < base; ++t) {
                    const unsigned long long kt = KEYq[t];
                    r0 += (kt < k0) ? 1 : 0;
                    r1 += (kt < k1) ? 1 : 0;
                }
            } else {
                unsigned long long k2 = (sl + 64 < base) ? KEYq[sl + 64] : ~0ull;
                unsigned long long k3 = (sl + 96 < base) ? KEYq[sl + 96] : ~0ull;
                int r2 = 0, r3 = 0;
                for (int t = 0; t < base; ++t) {
                    const unsigned long long kt = KEYq[t];
                    r0 += (kt < k0) ? 1 : 0;
                    r1 += (kt < k1) ? 1 : 0;
                    r2 += (kt < k2) ? 1 : 0;
                    r3 += (kt < k3) ? 1 : 0;
                }
                if (sl + 64 < base && r2 < 32) KEYq[r2] = k2;
                if (sl + 96 < base && r3 < 32) KEYq[r3] = k3;
            }
            if (sl      < base && r0 < 32) KEYq[r0] = k0;
            if (sl + 32 < base && r1 < 32) KEYq[r1] = k1;
            const unsigned long long kf = KEYq[sl];
            bd = __uint_as_float((unsigned)(kf >> 32));
            bi = (int)(unsigned)(kf & 0xffffffffull);

            const float tau32 = __shfl(bd, 31, 32);
            float g = INF;
            if (xlo > 0)        g = fminf(g, q.x - (float)xlo * h);
            if (xhi < GRID - 1) g = fminf(g, (float)(xhi + 1) * h - q.x);
            if (ylo > 0)        g = fminf(g, q.y - (float)ylo * h);
            if (yhi < GRID - 1) g = fminf(g, (float)(yhi + 1) * h - q.y);
            ok = (tau32 < g * (1.0f - 4e-6f));
        }
    }

    // ---------------- SLOW PATH (rare): adaptive, exact ---------------------------
    if (!ok) {
        const int cx = min(GRID - 1, max(0, (int)(q.x * (float)GRID)));
        const int cy = min(GRID - 1, max(0, (int)(q.y * (float)GRID)));
        int L = 2;
        for (;;) {
            const int xlo = max(cx - L, 0), xhi = min(cx + L, GRID - 1);
            const int ylo = max(cy - L, 0), yhi = min(cy + L, GRID - 1);
            const int nrows = yhi - ylo + 1;

            int sv = 0, ev = 0;
            if (sl < nrows) {
                sv = ST[(ylo + sl) * GRID + xlo];
                ev = ST[(ylo + sl) * GRID + xhi + 1];
            }

            float mn1 = INF, mn2 = INF;
            for (int r = 0; r < nrows; ++r) {
                const int s = __shfl(sv, r, 32), e = __shfl(ev, r, 32);
                for (int j = s + sl; j < e; j += 32) {
                    const float2 p = PS[j];
                    const float dx = q.x - p.x, dy = q.y - p.y;
                    const float d2 = __builtin_fmaf(dy, dy, __fmul_rn(dx, dx));
                    const float big = fmaxf(mn1, d2);
                    mn1 = fminf(mn1, d2);
                    mn2 = fminf(mn2, big);
                }
            }

            {
                float v = mn2;
#pragma unroll
                for (int k = 2; k <= 32; k <<= 1) {
#pragma unroll
                    for (int j = k >> 1; j > 0; j >>= 1) {
                        const float o = __shfl_xor(v, j, 32);
                        const bool up = ((sl & k) == 0), lower = ((sl & j) == 0);
                        const float mnv = fminf(v, o), mxv = fmaxf(v, o);
                        v = (lower == up) ? mnv : mxv;
                    }
                }
                mn2 = __shfl(v, 15, 32);
            }
            const float tau2b = mn2 * (1.0f + 4e-6f);

            int base = 0;
            for (int r = 0; r < nrows; ++r) {
                const int s = __shfl(sv, r, 32), e = __shfl(ev, r, 32);
                for (int j0 = s; j0 < e; j0 += 32) {
                    const int j = j0 + sl;
                    const bool valid = (j < e);
                    float2 p = make_float2(0.f, 0.f);
                    if (valid) p = PS[j];
                    const float dx = q.x - p.x, dy = q.y - p.y;
                    const float d2 = __builtin_fmaf(dy, dy, __fmul_rn(dx, dx));
                    const bool pred = valid && (d2 <= tau2b);
                    const unsigned bm = (unsigned)(__ballot(pred) >> (half << 5));
                    if (bm) {
                        const float ex = __fsqrt_rn(__fadd_rn(__fmul_rn(dx, dx),
                                                              __fmul_rn(dy, dy)));
                        const int pos = base + __popc(bm & lmlt32);
                        if (pred && pos < CAP)
                            KEYq[pos] =
                                ((unsigned long long)__float_as_uint(ex) << 32) | (unsigned)IS[j];
                        base += __popc(bm);
                    }
                }
            }

            if (base <= CAP) {
                unsigned long long k0 = (sl      < base) ? KEYq[sl]      : ~0ull;
                unsigned long long k1 = (sl + 32 < base) ? KEYq[sl + 32] : ~0ull;
                int r0 = 0, r1 = 0;
                if (!__any(base > 64)) {
                    for (int t = 0; t < base; ++t) {
                        const unsigned long long kt = KEYq[t];
                        r0 += (kt < k0) ? 1 : 0;
                        r1 += (kt < k1) ? 1 : 0;
                    }
                } else {
                    unsigned long long k2 = (sl + 64 < base) ? KEYq[sl + 64] : ~0ull;
                    unsigned long long k3 = (sl + 96 < base) ? KEYq[sl + 96] : ~0ull;
                    int r2 = 0, r3 = 0;
                    for (int t = 0; t < base; ++t) {
                        const unsigned long long kt = KEYq[t];
                        r0 += (kt < k0) ? 1 : 0;
                        r1 += (kt < k1) ? 1 : 0;
                        r2 += (kt < k2) ? 1 : 0;
                        r3 += (kt < k3) ? 1 : 0;
                    }
                    if (sl + 64 < base && r2 < 32) KEYq[r2] = k2;
                    if (sl + 96 < base && r3 < 32) KEYq[r3] = k3;
                }
                if (sl      < base && r0 < 32) KEYq[r0] = k0;
                if (sl + 32 < base && r1 < 32) KEYq[r1] = k1;
                if (base < 32 && sl >= base) KEYq[sl] = ~0ull;   // pad -> NaN -> expand
                const unsigned long long kf = KEYq[sl];
                bd = __uint_as_float((unsigned)(kf >> 32));
                bi = (int)(unsigned)(kf & 0xffffffffull);
            } else {
                float fd = INF; int fi = 0x7FFFFFFF;
                for (int r = 0; r < nrows; ++r) {
                    const int s = __shfl(sv, r, 32), e = __shfl(ev, r, 32);
                    for (int j0 = s; j0 < e; j0 += 32) {
                        const int j = j0 + sl;
                        const bool valid = (j < e);
                        float2 p = make_float2(0.f, 0.f);
                        int vi0 = 0x7FFFFFFF;
                        if (valid) { p = PS[j]; vi0 = IS[j]; }
                        const float dx = q.x - p.x, dy = q.y - p.y;
                        const float d2 = __builtin_fmaf(dy, dy, __fmul_rn(dx, dx));
                        unsigned cm = (unsigned)(__ballot(valid && (d2 <= tau2b)) >> (half << 5));
                        const float ex = __fsqrt_rn(__fadd_rn(__fmul_rn(dx, dx),
                                                              __fmul_rn(dy, dy)));
                        while (cm) {
                            const int l = __builtin_ctz(cm); cm &= cm - 1;
                            const float v  = __shfl(ex, l, 32);
                            const int   vi = __shfl(vi0, l, 32);
                            const bool cl = (fd < v) || (fd == v && fi < vi);
                            const int pos = __popc((unsigned)(__ballot(cl) >> (half << 5)));
                            const float sd = __shfl_up(fd, 1, 32);
                            const int   si = __shfl_up(fi, 1, 32);
                            fd = (sl < pos) ? fd : ((sl == pos) ? v  : sd);
                            fi = (sl < pos) ? fi : ((sl == pos) ? vi : si);
                        }
                    }
                }
                bd = fd; bi = fi;
            }

            const float tau = __shfl(bd, 31, 32);
            float g = INF;
            if (xlo > 0)        g = fminf(g, q.x - (float)xlo * h);
            if (xhi < GRID - 1) g = fminf(g, (float)(xhi + 1) * h - q.x);
            if (ylo > 0)        g = fminf(g, q.y - (float)ylo * h);
            if (yhi < GRID - 1) g = fminf(g, (float)(yhi + 1) * h - q.y);
            if (tau < g * (1.0f - 4e-6f)) break;
            L += 2;
            if (L > GRID - 1) L = GRID - 1;
        }
    }

    // ---- outputs 0 and 1: uiv_k and idx (as float) ----
    {
        const float2 pk = P[bi];
        float2 u;
        u.x = q.x - pk.x;
        u.y = q.y - pk.y;
        ((float2*)out_uiv)[(size_t)wid * KK + sl] = u;
        out_idx[(size_t)wid * KK + sl] = (float)bi;
    }
}

// ==== K2: gather + einsum + reduce. 8 queries / 256-thread block. ================
// Phase A: lane sl stages its own neighbor's value row into LDS (no cross-lane dep).
// Phase G: T accumulation, v from LDS.
// Phase R: coeff2[e][i][o] staged chunk-wise into LDS once PER BLOCK (8x dedup of
// the 64KB stream that was thrashing L1); lane reads are stride-1 -> conflict-free;
// T reads are lane-uniform -> broadcast.
__global__ __launch_bounds__(256) void conv_apply(
    const float* __restrict__ values_in,
    const float* __restrict__ out_uiv, const float* __restrict__ out_idx,
    const float* __restrict__ coeff2, const float* __restrict__ bias,
    float* __restrict__ out_val)
{
    __shared__ alignas(16) float VL[QPB2][KK][VROW];     // 36864 B
    __shared__ alignas(16) float CL[ECH][CIN][COUT];     // 16384 B  (53.25 KB total)

    const int tid   = threadIdx.x;
    const int sl    = tid & 31;
    const int qslot = tid >> 5;            // 0..7
    const int wid   = blockIdx.x * QPB2 + qslot;
    const int b     = wid >> 13;

    float* VLq = &VL[qslot][0][0];

    // neighbor #sl of this query: u stored exactly in K1 -> bd bit-exact
    const float2 u = ((const float2*)out_uiv)[(size_t)wid * KK + sl];
    const float bd = __fsqrt_rn(__fadd_rn(__fmul_rn(u.x, u.x), __fmul_rn(u.y, u.y)));
    const int   bi = (int)out_idx[(size_t)wid * KK + sl];

    // ---- Phase A: stage my neighbor's 32-float value row into LDS ----
    {
        const float4* src = (const float4*)(values_in + ((size_t)b * NN + bi) * CIN);
        const float4 r0 = src[0], r1 = src[1], r2 = src[2], r3 = src[3];
        const float4 r4 = src[4], r5 = src[5], r6 = src[6], r7 = src[7];
        float4* dst = (float4*)(VLq + sl * VROW);
        dst[0] = r0; dst[1] = r1; dst[2] = r2; dst[3] = r3;
        dst[4] = r4; dst[5] = r5; dst[6] = r6; dst[7] = r7;
    }

    // ---- Phase G: T[e][i] = sum_k exp(-256*(r_k - mu_e)^2) * v_k[i], v from LDS --
    {
        const int e2 = sl >> 2;                 // 0..7 -> e in {2*e2, 2*e2+1}
        const int iq = sl & 3;                  // i-block of 8
        const float mu0 = (float)(2 * e2)     * (1.0f / 15.0f);
        const float mu1 = (float)(2 * e2 + 1) * (1.0f / 15.0f);
        float4 A0a = make_float4(0.f, 0.f, 0.f, 0.f);
        float4 A0b = A0a, A1a = A0a, A1b = A0a;
#pragma unroll 8
        for (int k = 0; k < KK; ++k) {
            const float rk = __shfl(bd, k, 32);
            const float d0 = rk - mu0;
            const float d1 = rk - mu1;
            const float w0 = __expf(-256.0f * d0 * d0);
            const float w1 = __expf(-256.0f * d1 * d1);
            const float4* vr = (const float4*)(VLq + k * VROW + iq * 8);
            const float4 va = vr[0], vb = vr[1];
            A0a.x += w0 * va.x; A0a.y += w0 * va.y; A0a.z += w0 * va.z; A0a.w += w0 * va.w;
            A0b.x += w0 * vb.x; A0b.y += w0 * vb.y; A0b.z += w0 * vb.z; A0b.w += w0 * vb.w;
            A1a.x += w1 * va.x; A1a.y += w1 * va.y; A1a.z += w1 * va.z; A1a.w += w1 * va.w;
            A1b.x += w1 * vb.x; A1b.y += w1 * vb.y; A1b.z += w1 * vb.z; A1b.w += w1 * vb.w;
        }
        // overlay T (16 x VROW floats) onto the VL region -- all G reads precede
        // these stores in program order within this same half-wave.
        float4* t0 = (float4*)(VLq + (2 * e2)     * VROW + iq * 8);
        float4* t1 = (float4*)(VLq + (2 * e2 + 1) * VROW + iq * 8);
        t0[0] = A0a; t0[1] = A0b;
        t1[0] = A1a; t1[1] = A1b;
    }

    // ---- Phase R: out[o] = (1/K)*sum_{e,i} coeff2[e][i][o]*T[e][i] + bias[o] ----
    // coeff2 staged per block in ECH-e chunks; K2 control flow is uniform so the
    // block-wide barriers are lockstep-cheap.
    {
        const int o = sl;
        float s = 0.f;
#pragma unroll
        for (int ec = 0; ec < EE / ECH; ++ec) {
            __syncthreads();                      // prior chunk fully consumed
            {
                const float4* src = (const float4*)(coeff2 + ec * (ECH * CIN * COUT));
                float4* dst = (float4*)&CL[0][0][0];
#pragma unroll
                for (int j = 0; j < (ECH * CIN * COUT) / (4 * 256); ++j) {
                    const int idx = tid + j * 256;
                    dst[idx] = src[idx];
                }
            }
            __syncthreads();
#pragma unroll
            for (int el = 0; el < ECH; ++el) {
                const int e = ec * ECH + el;
                const float* Crow = &CL[el][0][0];
                const float* Trow = VLq + e * VROW;
#pragma unroll
                for (int i4 = 0; i4 < 8; ++i4) {
                    const float4 t = *(const float4*)(Trow + i4 * 4);   // broadcast
                    s += Crow[(i4 * 4 + 0) * 32 + o] * t.x;
                    s += Crow[(i4 * 4 + 1) * 32 + o] * t.y;
                    s += Crow[(i4 * 4 + 2) * 32 + o] * t.z;
                    s += Crow[(i4 * 4 + 3) * 32 + o] * t.w;
                }
            }
        }
        out_val[(size_t)wid * COUT + o] = s * (1.0f / 32.0f) + bias[o];
    }
}

extern "C" void kernel_launch(void* const* d_in, const int* in_sizes, int n_in,
                              void* d_out, int out_size, void* d_ws, size_t ws_size,
                              hipStream_t stream) {
    const float* points_in  = (const float*)d_in[0];
    const float* values_in  = (const float*)d_in[1];
    const float* points_out = (const float*)d_in[2];
    const float* coeff      = (const float*)d_in[3];
    const float* bias       = (const float*)d_in[4];

    float* out     = (float*)d_out;
    float* out_uiv = out;                                        // B*M*K*2
    float* out_idx = out + (size_t)BB * MM * KK * 2;             // B*M*K
    float* out_val = out_idx + (size_t)BB * MM * KK;             // B*M*COUT

    char* ws = (char*)d_ws;
    float*  coeff2 = (float*)(ws + OFS_COEFFT);
    int*    counts = (int*)  (ws + OFS_COUNTS);
    int*    cursor = (int*)  (ws + OFS_CURSOR);
    int*    strts  = (int*)  (ws + OFS_STARTS);
    float2* pts_s  = (float2*)(ws + OFS_PTSS);
    int*    idx_s  = (int*)  (ws + OFS_IDXS);

    hipLaunchKernelGGL(transpose_coeff, dim3(64), dim3(256), 0, stream, coeff, coeff2);
    hipLaunchKernelGGL(bin_zero, dim3(16), dim3(256), 0, stream, counts);
    hipLaunchKernelGGL(bin_count, dim3(64), dim3(256), 0, stream, points_in, counts);
    hipLaunchKernelGGL(bin_scan, dim3(1), dim3(1024), 0, stream, counts, strts);
    hipLaunchKernelGGL(bin_scatter, dim3(64), dim3(256), 0, stream,
                       points_in, strts, cursor, pts_s, idx_s);

    const int blocks1 = (BB * MM) / QPB;                         // 4096
    hipLaunchKernelGGL(conv_knn, dim3(blocks1), dim3(128), 0, stream,
                       pts_s, idx_s, strts, points_in, points_out,
                       out_uiv, out_idx);

    const int blocks2 = (BB * MM) / QPB2;                        // 2048
    hipLaunchKernelGGL(conv_apply, dim3(blocks2), dim3(256), 0, stream,
                       values_in, out_uiv, out_idx, coeff2, bias, out_val);
}

// Round 16
// 77.243 us; speedup vs baseline: 2.1996x; 1.0567x over previous
//
#include <hip/hip_runtime.h>
#include <cstdint>
#include <cstddef>

// Problem constants (from reference)
constexpr int BB   = 2;
constexpr int NN   = 8192;
constexpr int MM   = 8192;
constexpr int CIN  = 32;
constexpr int COUT = 32;
constexpr int EE   = 16;
constexpr int KK   = 32;
constexpr int GRID = 32;              // binning grid (h = 1/32, ~8 pts/cell)
constexpr int NCELL = GRID * GRID;

#define QPB 4            // K1: queries per 128-thread block
#define QPB2 8           // K2: queries per 256-thread block
#define CAP 128
#define KEY_BYTES 1040   // 128 u64 + 16B skew
#define VROW 36          // K2: padded value-row stride in floats (144B: aligned+skew)
#define ECH 4            // K2: e-chunk size for coeff LDS staging

// Fixed-radius fast path: lambda = pi*R0^2*N ~ 58 expected candidates.
#define R0_FAST 0.0475f

// Workspace layout (bytes)
constexpr size_t OFS_COEFFT = 0;        // coeff2[E][CIN][COUT]: 16384 f = 65536 B
constexpr size_t OFS_COUNTS = 65536;    // 2*1024 i = 8192 B
constexpr size_t OFS_CURSOR = 73728;    // 2*1024 i = 8192 B
constexpr size_t OFS_STARTS = 81920;    // 2*1025 i = 8200 B (pad to 8704)
constexpr size_t OFS_PTSS   = 90624;    // 2*8192 float2 = 131072 B
constexpr size_t OFS_IDXS   = 221696;   // 2*8192 i = 65536 B  (total 287232 B)

// ---- coeff [CIN][COUT][E] -> coeff2 [E][CIN][COUT] ------------------------------
// (o fastest so Phase-R C reads are float4 over o)
__global__ __launch_bounds__(256) void transpose_coeff(const float* __restrict__ coeff,
                                                       float* __restrict__ coeff2) {
    int tid = blockIdx.x * 256 + threadIdx.x;
    if (tid >= EE * CIN * COUT) return;
    int o = tid & 31;
    int i = (tid >> 5) & 31;
    int e = tid >> 10;
    coeff2[tid] = coeff[(i * COUT + o) * EE + e];
}

// ---- binning: zero, count, scan, scatter ----------------------------------------
__global__ __launch_bounds__(256) void bin_zero(int* __restrict__ p) {
    int t = blockIdx.x * 256 + threadIdx.x;
    if (t < 2 * 2 * NCELL) p[t] = 0;
}

__device__ __forceinline__ int cell_of(float2 p) {
    int cx = min(GRID - 1, max(0, (int)(p.x * (float)GRID)));
    int cy = min(GRID - 1, max(0, (int)(p.y * (float)GRID)));
    return cy * GRID + cx;
}

__global__ __launch_bounds__(256) void bin_count(const float* __restrict__ pts,
                                                 int* __restrict__ counts) {
    int t = blockIdx.x * 256 + threadIdx.x;
    int b = t >> 13, i = t & (NN - 1);
    float2 p = ((const float2*)pts)[(size_t)b * NN + i];
    atomicAdd(&counts[b * NCELL + cell_of(p)], 1);
}

__global__ __launch_bounds__(1024) void bin_scan(const int* __restrict__ counts,
                                                 int* __restrict__ starts) {
    __shared__ int sm[NCELL];
    const int t = threadIdx.x;
    for (int b = 0; b < BB; ++b) {
        sm[t] = counts[b * NCELL + t];
        __syncthreads();
        for (int off = 1; off < NCELL; off <<= 1) {
            int v = (t >= off) ? sm[t - off] : 0;
            __syncthreads();
            sm[t] += v;
            __syncthreads();
        }
        starts[b * (NCELL + 1) + t + 1] = sm[t];
        if (t == 0) starts[b * (NCELL + 1)] = 0;
        __syncthreads();
    }
}

__global__ __launch_bounds__(256) void bin_scatter(const float* __restrict__ pts,
                                                   const int* __restrict__ starts,
                                                   int* __restrict__ cursor,
                                                   float2* __restrict__ pts_s,
                                                   int* __restrict__ idx_s) {
    int t = blockIdx.x * 256 + threadIdx.x;
    int b = t >> 13, i = t & (NN - 1);
    float2 p = ((const float2*)pts)[(size_t)b * NN + i];
    int cell = cell_of(p);
    int pos = starts[b * (NCELL + 1) + cell] + atomicAdd(&cursor[b * NCELL + cell], 1);
    pts_s[(size_t)b * NN + pos] = p;     // intra-cell order nondeterministic; final
    idx_s[(size_t)b * NN + pos] = i;     // rank by (d, orig idx) makes output exact.
}

// ==== K1: KNN selection only. One half-wave (32 lanes) per query. ================
__global__ __launch_bounds__(128) void conv_knn(
    const float2* __restrict__ pts_s, const int* __restrict__ idx_s,
    const int* __restrict__ starts,
    const float* __restrict__ points_in,
    const float* __restrict__ points_out,
    float* __restrict__ out_uiv, float* __restrict__ out_idx)
{
    __shared__ alignas(16) unsigned char SMEM[QPB][KEY_BYTES];

    const int tid   = threadIdx.x;
    const int sl    = tid & 31;
    const int qslot = tid >> 5;            // 0..3
    const int half  = qslot & 1;
    const int wid   = blockIdx.x * QPB + qslot;
    const int b     = wid >> 13;
    const int m     = wid & (MM - 1);

    unsigned long long* KEYq = (unsigned long long*)&SMEM[qslot][0];

    const float2* PS = pts_s + (size_t)b * NN;
    const int*    IS = idx_s + (size_t)b * NN;
    const int*    ST = starts + b * (NCELL + 1);
    const float2* P  = ((const float2*)points_in) + (size_t)b * NN;
    const float2  q  = ((const float2*)points_out)[(size_t)b * MM + m];

    const float INF = __builtin_inff();
    const float h = 1.0f / (float)GRID;
    const unsigned lmlt32 = (1u << sl) - 1u;

    float bd;   // sorted exact distance (sub-lane sl holds entry #sl)
    int   bi;   // sorted original index
    bool  ok = false;

    // ---------------- FAST PATH: fixed analytic radius, single scan ---------------
    {
        float tau = R0_FAST;
        {
            const float bx = fminf(q.x, 1.0f - q.x);
            const float by = fminf(q.y, 1.0f - q.y);
#pragma unroll
            for (int it = 0; it < 3; ++it) {
                const float wx = 0.5f + 0.5f * fminf(bx / tau, 1.0f);
                const float wy = 0.5f + 0.5f * fminf(by / tau, 1.0f);
                tau = R0_FAST * __frsqrt_rn(wx * wy);
            }
        }
        const float tau2  = tau * tau;
        const float tau2a = tau2 * (1.0f + 2e-6f);

        const int xlo = (int)fmaxf((q.x - tau) * (float)GRID, 0.0f);
        const int xhi = (int)fminf((q.x + tau) * (float)GRID, (float)(GRID - 1));
        const int ylo = (int)fmaxf((q.y - tau) * (float)GRID, 0.0f);
        const int yhi = (int)fminf((q.y + tau) * (float)GRID, (float)(GRID - 1));
        const int nrows = yhi - ylo + 1;

        int sv = 0, ev = 0;
        if (sl < nrows) {
            sv = ST[(ylo + sl) * GRID + xlo];
            ev = ST[(ylo + sl) * GRID + xhi + 1];
        }

        int base = 0, nin = 0;
        for (int r = 0; r < nrows; ++r) {
            const int s = __shfl(sv, r, 32), e = __shfl(ev, r, 32);
            for (int j0 = s; j0 < e; j0 += 32) {
                const int j = j0 + sl;
                const bool valid = (j < e);
                float2 p = make_float2(2.0f, 2.0f);
                if (valid) p = PS[j];
                const float dx = q.x - p.x, dy = q.y - p.y;
                const float d2 = __builtin_fmaf(dy, dy, __fmul_rn(dx, dx));
                const bool adm = valid && (d2 <= tau2a);
                const unsigned bmA = (unsigned)(__ballot(adm) >> (half << 5));
                const unsigned bmS = (unsigned)(__ballot(valid && (d2 <= tau2)) >> (half << 5));
                nin += __popc(bmS);
                if (bmA) {
                    const float ex = __fsqrt_rn(__fadd_rn(__fmul_rn(dx, dx),
                                                          __fmul_rn(dy, dy)));
                    const int pos = base + __popc(bmA & lmlt32);
                    if (adm && pos < CAP)
                        KEYq[pos] =
                            ((unsigned long long)__float_as_uint(ex) << 32) | (unsigned)IS[j];
                    base += __popc(bmA);
                }
            }
        }

        ok = (nin >= 32) && (base <= CAP);
        if (ok) {
            unsigned long long k0 = (sl      < base) ? KEYq[sl]      : ~0ull;
            unsigned long long k1 = (sl + 32 < base) ? KEYq[sl + 32] : ~0ull;
            int r0 = 0, r1 = 0;
            if (!__any(base > 64)) {
                for (int t = 0; t < base; ++t) {
                    const unsigned long long kt = KEYq[t];
                    r0 += (kt < k0) ? 1 : 0;
                    r1 += (kt < k1) ? 1 : 0;
                }
            } else {
                unsigned long long k2 = (sl + 64 < base) ? KEYq[sl + 64] : ~0ull;
                unsigned long long k3 = (sl + 96 < base) ? KEYq[sl + 96] : ~0ull;
                int r2 = 0, r3 = 0;
                for (int t = 0; t < base; ++t) {
                    const unsigned long long kt = KEYq[t];
                    r0 += (kt < k0) ? 1 : 0;
                    r1 += (kt < k1) ? 1 : 0;
                    r2 += (kt < k2) ? 1 : 0;
                    r3 += (kt < k3) ? 1 : 0;
                }
                if (sl + 64 < base && r2 < 32) KEYq[r2] = k2;
                if (sl + 96 < base && r3 < 32) KEYq[r3] = k3;
            }
            if (sl      < base && r0 < 32) KEYq[r0] = k0;
            if (sl + 32 < base && r1 < 32) KEYq[r1] = k1;
            const unsigned long long kf = KEYq[sl];
            bd = __uint_as_float((unsigned)(kf >> 32));
            bi = (int)(unsigned)(kf & 0xffffffffull);

            const float tau32 = __shfl(bd, 31, 32);
            float g = INF;
            if (xlo > 0)        g = fminf(g, q.x - (float)xlo * h);
            if (xhi < GRID - 1) g = fminf(g, (float)(xhi + 1) * h - q.x);
            if (ylo > 0)        g = fminf(g, q.y - (float)ylo * h);
            if (yhi < GRID - 1) g = fminf(g, (float)(yhi + 1) * h - q.y);
            ok = (tau32 < g * (1.0f - 4e-6f));
        }
    }

    // ---------------- SLOW PATH (rare): adaptive, exact ---------------------------
    if (!ok) {
        const int cx = min(GRID - 1, max(0, (int)(q.x * (float)GRID)));
        const int cy = min(GRID - 1, max(0, (int)(q.y * (float)GRID)));
        int L = 2;
        for (;;) {
            const int xlo = max(cx - L, 0), xhi = min(cx + L, GRID - 1);
            const int ylo = max(cy - L, 0), yhi = min(cy + L, GRID - 1);
            const int nrows = yhi - ylo + 1;

            int sv = 0, ev = 0;
            if (sl < nrows) {
                sv = ST[(ylo + sl) * GRID + xlo];
                ev = ST[(ylo + sl) * GRID + xhi + 1];
            }

            float mn1 = INF, mn2 = INF;
            for (int r = 0; r < nrows; ++r) {
                const int s = __shfl(sv, r, 32), e = __shfl(ev, r, 32);
                for (int j = s + sl; j < e; j += 32) {
                    const float2 p = PS[j];
                    const float dx = q.x - p.x, dy = q.y - p.y;
                    const float d2 = __builtin_fmaf(dy, dy, __fmul_rn(dx, dx));
                    const float big = fmaxf(mn1, d2);
                    mn1 = fminf(mn1, d2);
                    mn2 = fminf(mn2, big);
                }
            }

            {
                float v = mn2;
#pragma unroll
                for (int k = 2; k <= 32; k <<= 1) {
#pragma unroll
                    for (int j = k >> 1; j > 0; j >>= 1) {
                        const float o = __shfl_xor(v, j, 32);
                        const bool up = ((sl & k) == 0), lower = ((sl & j) == 0);
                        const float mnv = fminf(v, o), mxv = fmaxf(v, o);
                        v = (lower == up) ? mnv : mxv;
                    }
                }
                mn2 = __shfl(v, 15, 32);
            }
            const float tau2b = mn2 * (1.0f + 4e-6f);

            int base = 0;
            for (int r = 0; r < nrows; ++r) {
                const int s = __shfl(sv, r, 32), e = __shfl(ev, r, 32);
                for (int j0 = s; j0 < e; j0 += 32) {
                    const int j = j0 + sl;
                    const bool valid = (j < e);
                    float2 p = make_float2(0.f, 0.f);
                    if (valid) p = PS[j];
                    const float dx = q.x - p.x, dy = q.y - p.y;
                    const float d2 = __builtin_fmaf(dy, dy, __fmul_rn(dx, dx));
                    const bool pred = valid && (d2 <= tau2b);
                    const unsigned bm = (unsigned)(__ballot(pred) >> (half << 5));
                    if (bm) {
                        const float ex = __fsqrt_rn(__fadd_rn(__fmul_rn(dx, dx),
                                                              __fmul_rn(dy, dy)));
                        const int pos = base + __popc(bm & lmlt32);
                        if (pred && pos < CAP)
                            KEYq[pos] =
                                ((unsigned long long)__float_as_uint(ex) << 32) | (unsigned)IS[j];
                        base += __popc(bm);
                    }
                }
            }

            if (base <= CAP) {
                unsigned long long k0 = (sl      < base) ? KEYq[sl]      : ~0ull;
                unsigned long long k1 = (sl + 32 < base) ? KEYq[sl + 32] : ~0ull;
                int r0 = 0, r1 = 0;
                if (!__any(base > 64)) {
                    for (int t = 0; t < base; ++t) {
                        const unsigned long long kt = KEYq[t];
                        r0 += (kt < k0) ? 1 : 0;
                        r1 += (kt < k1) ? 1 : 0;
                    }
                } else {
                    unsigned long long k2 = (sl + 64 < base) ? KEYq[sl + 64] : ~0ull;
                    unsigned long long k3 = (sl + 96 < base) ? KEYq[sl + 96] : ~0ull;
                    int r2 = 0, r3 = 0;
                    for (int t = 0; t < base; ++t) {
                        const unsigned long long kt = KEYq[t];
                        r0 += (kt < k0) ? 1 : 0;
                        r1 += (kt < k1) ? 1 : 0;
                        r2 += (kt < k2) ? 1 : 0;
                        r3 += (kt < k3) ? 1 : 0;
                    }
                    if (sl + 64 < base && r2 < 32) KEYq[r2] = k2;
                    if (sl + 96 < base && r3 < 32) KEYq[r3] = k3;
                }
                if (sl      < base && r0 < 32) KEYq[r0] = k0;
                if (sl + 32 < base && r1 < 32) KEYq[r1] = k1;
                if (base < 32 && sl >= base) KEYq[sl] = ~0ull;   // pad -> NaN -> expand
                const unsigned long long kf = KEYq[sl];
                bd = __uint_as_float((unsigned)(kf >> 32));
                bi = (int)(unsigned)(kf & 0xffffffffull);
            } else {
                float fd = INF; int fi = 0x7FFFFFFF;
                for (int r = 0; r < nrows; ++r) {
                    const int s = __shfl(sv, r, 32), e = __shfl(ev, r, 32);
                    for (int j0 = s; j0 < e; j0 += 32) {
                        const int j = j0 + sl;
                        const bool valid = (j < e);
                        float2 p = make_float2(0.f, 0.f);
                        int vi0 = 0x7FFFFFFF;
                        if (valid) { p = PS[j]; vi0 = IS[j]; }
                        const float dx = q.x - p.x, dy = q.y - p.y;
                        const float d2 = __builtin_fmaf(dy, dy, __fmul_rn(dx, dx));
                        unsigned cm = (unsigned)(__ballot(valid && (d2 <= tau2b)) >> (half << 5));
                        const float ex = __fsqrt_rn(__fadd_rn(__fmul_rn(dx, dx),
                                                              __fmul_rn(dy, dy)));
                        while (cm) {
                            const int l = __builtin_ctz(cm); cm &= cm - 1;
                            const float v  = __shfl(ex, l, 32);
                            const int   vi = __shfl(vi0, l, 32);
                            const bool cl = (fd < v) || (fd == v && fi < vi);
                            const int pos = __popc((unsigned)(__ballot(cl) >> (half << 5)));
                            const float sd = __shfl_up(fd, 1, 32);
                            const int   si = __shfl_up(fi, 1, 32);
                            fd = (sl < pos) ? fd : ((sl == pos) ? v  : sd);
                            fi = (sl < pos) ? fi : ((sl == pos) ? vi : si);
                        }
                    }
                }
                bd = fd; bi = fi;
            }

            const float tau = __shfl(bd, 31, 32);
            float g = INF;
            if (xlo > 0)        g = fminf(g, q.x - (float)xlo * h);
            if (xhi < GRID - 1) g = fminf(g, (float)(xhi + 1) * h - q.x);
            if (ylo > 0)        g = fminf(g, q.y - (float)ylo * h);
            if (yhi < GRID - 1) g = fminf(g, (float)(yhi + 1) * h - q.y);
            if (tau < g * (1.0f - 4e-6f)) break;
            L += 2;
            if (L > GRID - 1) L = GRID - 1;
        }
    }

    // ---- outputs 0 and 1: uiv_k and idx (as float) ----
    {
        const float2 pk = P[bi];
        float2 u;
        u.x = q.x - pk.x;
        u.y = q.y - pk.y;
        ((float2*)out_uiv)[(size_t)wid * KK + sl] = u;
        out_idx[(size_t)wid * KK + sl] = (float)bi;
    }
}

// ==== K2: gather + einsum + reduce. 8 queries / 256-thread block. ================
// Phase A: lane sl stages its own neighbor's value row into LDS.
// Phase G: T accumulation, v from LDS.
// Phase R: lane = (i8, o4): C read as float4 over o (4x fewer LDS instructions than
// the lane=o scalar-read arrangement); T read as 2 float4 per e; shfl_xor reduce
// over i8; coalesced float4 output write.
__global__ __launch_bounds__(256) void conv_apply(
    const float* __restrict__ values_in,
    const float* __restrict__ out_uiv, const float* __restrict__ out_idx,
    const float* __restrict__ coeff2, const float* __restrict__ bias,
    float* __restrict__ out_val)
{
    __shared__ alignas(16) float VL[QPB2][KK][VROW];     // 36864 B
    __shared__ alignas(16) float CL[ECH][CIN][COUT];     // 16384 B  (53.25 KB total)

    const int tid   = threadIdx.x;
    const int sl    = tid & 31;
    const int qslot = tid >> 5;            // 0..7
    const int wid   = blockIdx.x * QPB2 + qslot;
    const int b     = wid >> 13;

    float* VLq = &VL[qslot][0][0];

    // neighbor #sl of this query: u stored exactly in K1 -> bd bit-exact
    const float2 u = ((const float2*)out_uiv)[(size_t)wid * KK + sl];
    const float bd = __fsqrt_rn(__fadd_rn(__fmul_rn(u.x, u.x), __fmul_rn(u.y, u.y)));
    const int   bi = (int)out_idx[(size_t)wid * KK + sl];

    // ---- Phase A: stage my neighbor's 32-float value row into LDS ----
    {
        const float4* src = (const float4*)(values_in + ((size_t)b * NN + bi) * CIN);
        const float4 r0 = src[0], r1 = src[1], r2 = src[2], r3 = src[3];
        const float4 r4 = src[4], r5 = src[5], r6 = src[6], r7 = src[7];
        float4* dst = (float4*)(VLq + sl * VROW);
        dst[0] = r0; dst[1] = r1; dst[2] = r2; dst[3] = r3;
        dst[4] = r4; dst[5] = r5; dst[6] = r6; dst[7] = r7;
    }

    // ---- Phase G: T[e][i] = sum_k exp(-256*(r_k - mu_e)^2) * v_k[i], v from LDS --
    {
        const int e2 = sl >> 2;                 // 0..7 -> e in {2*e2, 2*e2+1}
        const int iq = sl & 3;                  // i-block of 8
        const float mu0 = (float)(2 * e2)     * (1.0f / 15.0f);
        const float mu1 = (float)(2 * e2 + 1) * (1.0f / 15.0f);
        float4 A0a = make_float4(0.f, 0.f, 0.f, 0.f);
        float4 A0b = A0a, A1a = A0a, A1b = A0a;
#pragma unroll 8
        for (int k = 0; k < KK; ++k) {
            const float rk = __shfl(bd, k, 32);
            const float d0 = rk - mu0;
            const float d1 = rk - mu1;
            const float w0 = __expf(-256.0f * d0 * d0);
            const float w1 = __expf(-256.0f * d1 * d1);
            const float4* vr = (const float4*)(VLq + k * VROW + iq * 8);
            const float4 va = vr[0], vb = vr[1];
            A0a.x += w0 * va.x; A0a.y += w0 * va.y; A0a.z += w0 * va.z; A0a.w += w0 * va.w;
            A0b.x += w0 * vb.x; A0b.y += w0 * vb.y; A0b.z += w0 * vb.z; A0b.w += w0 * vb.w;
            A1a.x += w1 * va.x; A1a.y += w1 * va.y; A1a.z += w1 * va.z; A1a.w += w1 * va.w;
            A1b.x += w1 * vb.x; A1b.y += w1 * vb.y; A1b.z += w1 * vb.z; A1b.w += w1 * vb.w;
        }
        // overlay T (16 x VROW floats) onto the VL region -- all G reads precede
        // these stores in program order within this same half-wave.
        float4* t0 = (float4*)(VLq + (2 * e2)     * VROW + iq * 8);
        float4* t1 = (float4*)(VLq + (2 * e2 + 1) * VROW + iq * 8);
        t0[0] = A0a; t0[1] = A0b;
        t1[0] = A1a; t1[1] = A1b;
    }

    // ---- Phase R: out[o] = (1/K)*sum_{e,i} coeff2[e][i][o]*T[e][i] + bias[o] ----
    // lane (i8, o4): outputs o4*4..+3 over i-range i8*8..+7; cross-i8 shfl reduce.
    {
        const int i8 = sl >> 3;               // 0..3
        const int o4 = sl & 7;                // 0..7
        float4 s4 = make_float4(0.f, 0.f, 0.f, 0.f);
#pragma unroll
        for (int ec = 0; ec < EE / ECH; ++ec) {
            __syncthreads();                   // prior chunk fully consumed
            {
                const float4* src = (const float4*)(coeff2 + ec * (ECH * CIN * COUT));
                float4* dst = (float4*)&CL[0][0][0];
#pragma unroll
                for (int j = 0; j < (ECH * CIN * COUT) / (4 * 256); ++j) {
                    const int idx = tid + j * 256;
                    dst[idx] = src[idx];
                }
            }
            __syncthreads();
#pragma unroll
            for (int el = 0; el < ECH; ++el) {
                const int e = ec * ECH + el;
                const float* Trow = VLq + e * VROW + i8 * 8;
                const float4 ta = *(const float4*)(Trow);
                const float4 tb = *(const float4*)(Trow + 4);
                const float* Cbase = &CL[el][i8 * 8][0] + o4 * 4;
#pragma unroll
                for (int ir = 0; ir < 4; ++ir) {
                    const float4 c = *(const float4*)(Cbase + ir * COUT);
                    const float t = (ir == 0) ? ta.x : (ir == 1) ? ta.y
                                  : (ir == 2) ? ta.z : ta.w;
                    s4.x += t * c.x; s4.y += t * c.y;
                    s4.z += t * c.z; s4.w += t * c.w;
                }
#pragma unroll
                for (int ir = 0; ir < 4; ++ir) {
                    const float4 c = *(const float4*)(Cbase + (4 + ir) * COUT);
                    const float t = (ir == 0) ? tb.x : (ir == 1) ? tb.y
                                  : (ir == 2) ? tb.z : tb.w;
                    s4.x += t * c.x; s4.y += t * c.y;
                    s4.z += t * c.z; s4.w += t * c.w;
                }
            }
        }
        // reduce over i8 (lanes o4, o4+8, o4+16, o4+24 within the 32-wide half)
        s4.x += __shfl_xor(s4.x, 8, 32);  s4.y += __shfl_xor(s4.y, 8, 32);
        s4.z += __shfl_xor(s4.z, 8, 32);  s4.w += __shfl_xor(s4.w, 8, 32);
        s4.x += __shfl_xor(s4.x, 16, 32); s4.y += __shfl_xor(s4.y, 16, 32);
        s4.z += __shfl_xor(s4.z, 16, 32); s4.w += __shfl_xor(s4.w, 16, 32);
        if (i8 == 0) {
            const float4 bv = *(const float4*)(bias + o4 * 4);
            float4 ov;
            ov.x = s4.x * (1.0f / 32.0f) + bv.x;
            ov.y = s4.y * (1.0f / 32.0f) + bv.y;
            ov.z = s4.z * (1.0f / 32.0f) + bv.z;
            ov.w = s4.w * (1.0f / 32.0f) + bv.w;
            *(float4*)(out_val + (size_t)wid * COUT + o4 * 4) = ov;
        }
    }
}

extern "C" void kernel_launch(void* const* d_in, const int* in_sizes, int n_in,
                              void* d_out, int out_size, void* d_ws, size_t ws_size,
                              hipStream_t stream) {
    const float* points_in  = (const float*)d_in[0];
    const float* values_in  = (const float*)d_in[1];
    const float* points_out = (const float*)d_in[2];
    const float* coeff      = (const float*)d_in[3];
    const float* bias       = (const float*)d_in[4];

    float* out     = (float*)d_out;
    float* out_uiv = out;                                        // B*M*K*2
    float* out_idx = out + (size_t)BB * MM * KK * 2;             // B*M*K
    float* out_val = out_idx + (size_t)BB * MM * KK;             // B*M*COUT

    char* ws = (char*)d_ws;
    float*  coeff2 = (float*)(ws + OFS_COEFFT);
    int*    counts = (int*)  (ws + OFS_COUNTS);
    int*    cursor = (int*)  (ws + OFS_CURSOR);
    int*    strts  = (int*)  (ws + OFS_STARTS);
    float2* pts_s  = (float2*)(ws + OFS_PTSS);
    int*    idx_s  = (int*)  (ws + OFS_IDXS);

    hipLaunchKernelGGL(transpose_coeff, dim3(64), dim3(256), 0, stream, coeff, coeff2);
    hipLaunchKernelGGL(bin_zero, dim3(16), dim3(256), 0, stream, counts);
    hipLaunchKernelGGL(bin_count, dim3(64), dim3(256), 0, stream, points_in, counts);
    hipLaunchKernelGGL(bin_scan, dim3(1), dim3(1024), 0, stream, counts, strts);
    hipLaunchKernelGGL(bin_scatter, dim3(64), dim3(256), 0, stream,
                       points_in, strts, cursor, pts_s, idx_s);

    const int blocks1 = (BB * MM) / QPB;                         // 4096
    hipLaunchKernelGGL(conv_knn, dim3(blocks1), dim3(128), 0, stream,
                       pts_s, idx_s, strts, points_in, points_out,
                       out_uiv, out_idx);

    const int blocks2 = (BB * MM) / QPB2;                        // 2048
    hipLaunchKernelGGL(conv_apply, dim3(blocks2), dim3(256), 0, stream,
                       values_in, out_uiv, out_idx, coeff2, bias, out_val);
}

// Round 17
// 70.900 us; speedup vs baseline: 2.3964x; 1.0895x over previous
//
#include <hip/hip_runtime.h>
#include <cstdint>
#include <cstddef>

// Problem constants (from reference)
constexpr int BB   = 2;
constexpr int NN   = 8192;
constexpr int MM   = 8192;
constexpr int CIN  = 32;
constexpr int COUT = 32;
constexpr int EE   = 16;
constexpr int KK   = 32;
constexpr int GRID = 32;              // binning grid (h = 1/32, ~8 pts/cell)
constexpr int NCELL = GRID * GRID;

#define QPB 4            // K1: queries per 128-thread block
#define QPB2 8           // K2: queries per 256-thread block
#define CAP 128
#define KEY_BYTES 1040   // 128 u64 + 16B skew
#define VROW 36          // K2: padded value-row stride in floats (144B)
#define VQS  1156        // K2: per-query VL stride (32*36 + 4: bank-phase skew 4q)
#define ECH 4            // K2: e-chunk size for coeff LDS staging

// Fixed-radius fast path: lambda = pi*R0^2*N ~ 58 expected candidates.
#define R0_FAST 0.0475f

// Workspace layout (bytes)
constexpr size_t OFS_COEFFT = 0;        // coeff2[E][CIN][COUT]: 16384 f = 65536 B
constexpr size_t OFS_COUNTS = 65536;    // 2*1024 i = 8192 B
constexpr size_t OFS_CURSOR = 73728;    // 2*1024 i = 8192 B
constexpr size_t OFS_STARTS = 81920;    // 2*1025 i = 8200 B (pad to 8704)
constexpr size_t OFS_PTSS   = 90624;    // 2*8192 float2 = 131072 B
constexpr size_t OFS_IDXS   = 221696;   // 2*8192 i = 65536 B  (total 287232 B)

// ---- coeff [CIN][COUT][E] -> coeff2 [E][CIN][COUT] ------------------------------
__global__ __launch_bounds__(256) void transpose_coeff(const float* __restrict__ coeff,
                                                       float* __restrict__ coeff2) {
    int tid = blockIdx.x * 256 + threadIdx.x;
    if (tid >= EE * CIN * COUT) return;
    int o = tid & 31;
    int i = (tid >> 5) & 31;
    int e = tid >> 10;
    coeff2[tid] = coeff[(i * COUT + o) * EE + e];
}

// ---- binning: zero, count, scan, scatter ----------------------------------------
__global__ __launch_bounds__(256) void bin_zero(int* __restrict__ p) {
    int t = blockIdx.x * 256 + threadIdx.x;
    if (t < 2 * 2 * NCELL) p[t] = 0;
}

__device__ __forceinline__ int cell_of(float2 p) {
    int cx = min(GRID - 1, max(0, (int)(p.x * (float)GRID)));
    int cy = min(GRID - 1, max(0, (int)(p.y * (float)GRID)));
    return cy * GRID + cx;
}

__global__ __launch_bounds__(256) void bin_count(const float* __restrict__ pts,
                                                 int* __restrict__ counts) {
    int t = blockIdx.x * 256 + threadIdx.x;
    int b = t >> 13, i = t & (NN - 1);
    float2 p = ((const float2*)pts)[(size_t)b * NN + i];
    atomicAdd(&counts[b * NCELL + cell_of(p)], 1);
}

__global__ __launch_bounds__(1024) void bin_scan(const int* __restrict__ counts,
                                                 int* __restrict__ starts) {
    __shared__ int sm[NCELL];
    const int t = threadIdx.x;
    for (int b = 0; b < BB; ++b) {
        sm[t] = counts[b * NCELL + t];
        __syncthreads();
        for (int off = 1; off < NCELL; off <<= 1) {
            int v = (t >= off) ? sm[t - off] : 0;
            __syncthreads();
            sm[t] += v;
            __syncthreads();
        }
        starts[b * (NCELL + 1) + t + 1] = sm[t];
        if (t == 0) starts[b * (NCELL + 1)] = 0;
        __syncthreads();
    }
}

__global__ __launch_bounds__(256) void bin_scatter(const float* __restrict__ pts,
                                                   const int* __restrict__ starts,
                                                   int* __restrict__ cursor,
                                                   float2* __restrict__ pts_s,
                                                   int* __restrict__ idx_s) {
    int t = blockIdx.x * 256 + threadIdx.x;
    int b = t >> 13, i = t & (NN - 1);
    float2 p = ((const float2*)pts)[(size_t)b * NN + i];
    int cell = cell_of(p);
    int pos = starts[b * (NCELL + 1) + cell] + atomicAdd(&cursor[b * NCELL + cell], 1);
    pts_s[(size_t)b * NN + pos] = p;     // intra-cell order nondeterministic; final
    idx_s[(size_t)b * NN + pos] = i;     // rank by (d, orig idx) makes output exact.
}

// ==== K1: KNN selection only. One half-wave (32 lanes) per query. ================
__global__ __launch_bounds__(128) void conv_knn(
    const float2* __restrict__ pts_s, const int* __restrict__ idx_s,
    const int* __restrict__ starts,
    const float* __restrict__ points_in,
    const float* __restrict__ points_out,
    float* __restrict__ out_uiv, float* __restrict__ out_idx)
{
    __shared__ alignas(16) unsigned char SMEM[QPB][KEY_BYTES];

    const int tid   = threadIdx.x;
    const int sl    = tid & 31;
    const int qslot = tid >> 5;            // 0..3
    const int half  = qslot & 1;
    const int wid   = blockIdx.x * QPB + qslot;
    const int b     = wid >> 13;
    const int m     = wid & (MM - 1);

    unsigned long long* KEYq = (unsigned long long*)&SMEM[qslot][0];

    const float2* PS = pts_s + (size_t)b * NN;
    const int*    IS = idx_s + (size_t)b * NN;
    const int*    ST = starts + b * (NCELL + 1);
    const float2* P  = ((const float2*)points_in) + (size_t)b * NN;
    const float2  q  = ((const float2*)points_out)[(size_t)b * MM + m];

    const float INF = __builtin_inff();
    const float h = 1.0f / (float)GRID;
    const unsigned lmlt32 = (1u << sl) - 1u;

    float bd;   // sorted exact distance (sub-lane sl holds entry #sl)
    int   bi;   // sorted original index
    bool  ok = false;

    // ---------------- FAST PATH: fixed analytic radius, single scan ---------------
    {
        float tau = R0_FAST;
        {
            const float bx = fminf(q.x, 1.0f - q.x);
            const float by = fminf(q.y, 1.0f - q.y);
#pragma unroll
            for (int it = 0; it < 3; ++it) {
                const float wx = 0.5f + 0.5f * fminf(bx / tau, 1.0f);
                const float wy = 0.5f + 0.5f * fminf(by / tau, 1.0f);
                tau = R0_FAST * __frsqrt_rn(wx * wy);
            }
        }
        const float tau2  = tau * tau;
        const float tau2a = tau2 * (1.0f + 2e-6f);

        const int xlo = (int)fmaxf((q.x - tau) * (float)GRID, 0.0f);
        const int xhi = (int)fminf((q.x + tau) * (float)GRID, (float)(GRID - 1));
        const int ylo = (int)fmaxf((q.y - tau) * (float)GRID, 0.0f);
        const int yhi = (int)fminf((q.y + tau) * (float)GRID, (float)(GRID - 1));
        const int nrows = yhi - ylo + 1;

        int sv = 0, ev = 0;
        if (sl < nrows) {
            sv = ST[(ylo + sl) * GRID + xlo];
            ev = ST[(ylo + sl) * GRID + xhi + 1];
        }

        int base = 0, nin = 0;
        for (int r = 0; r < nrows; ++r) {
            const int s = __shfl(sv, r, 32), e = __shfl(ev, r, 32);
            for (int j0 = s; j0 < e; j0 += 32) {
                const int j = j0 + sl;
                const bool valid = (j < e);
                float2 p = make_float2(2.0f, 2.0f);
                if (valid) p = PS[j];
                const float dx = q.x - p.x, dy = q.y - p.y;
                const float d2 = __builtin_fmaf(dy, dy, __fmul_rn(dx, dx));
                const bool adm = valid && (d2 <= tau2a);
                const unsigned bmA = (unsigned)(__ballot(adm) >> (half << 5));
                const unsigned bmS = (unsigned)(__ballot(valid && (d2 <= tau2)) >> (half << 5));
                nin += __popc(bmS);
                if (bmA) {
                    const float ex = __fsqrt_rn(__fadd_rn(__fmul_rn(dx, dx),
                                                          __fmul_rn(dy, dy)));
                    const int pos = base + __popc(bmA & lmlt32);
                    if (adm && pos < CAP)
                        KEYq[pos] =
                            ((unsigned long long)__float_as_uint(ex) << 32) | (unsigned)IS[j];
                    base += __popc(bmA);
                }
            }
        }

        ok = (nin >= 32) && (base <= CAP);
        if (ok) {
            unsigned long long k0 = (sl      < base) ? KEYq[sl]      : ~0ull;
            unsigned long long k1 = (sl + 32 < base) ? KEYq[sl + 32] : ~0ull;
            int r0 = 0, r1 = 0;
            if (!__any(base > 64)) {
                for (int t = 0; t < base; ++t) {
                    const unsigned long long kt = KEYq[t];
                    r0 += (kt < k0) ? 1 : 0;
                    r1 += (kt < k1) ? 1 : 0;
                }
            } else {
                unsigned long long k2 = (sl + 64 < base) ? KEYq[sl + 64] : ~0ull;
                unsigned long long k3 = (sl + 96 < base) ? KEYq[sl + 96] : ~0ull;
                int r2 = 0, r3 = 0;
                for (int t = 0; t < base; ++t) {
                    const unsigned long long kt = KEYq[t];
                    r0 += (kt < k0) ? 1 : 0;
                    r1 += (kt < k1) ? 1 : 0;
                    r2 += (kt < k2) ? 1 : 0;
                    r3 += (kt < k3) ? 1 : 0;
                }
                if (sl + 64 < base && r2 < 32) KEYq[r2] = k2;
                if (sl + 96 < base && r3 < 32) KEYq[r3] = k3;
            }
            if (sl      < base && r0 < 32) KEYq[r0] = k0;
            if (sl + 32 < base && r1 < 32) KEYq[r1] = k1;
            const unsigned long long kf = KEYq[sl];
            bd = __uint_as_float((unsigned)(kf >> 32));
            bi = (int)(unsigned)(kf & 0xffffffffull);

            const float tau32 = __shfl(bd, 31, 32);
            float g = INF;
            if (xlo > 0)        g = fminf(g, q.x - (float)xlo * h);
            if (xhi < GRID - 1) g = fminf(g, (float)(xhi + 1) * h - q.x);
            if (ylo > 0)        g = fminf(g, q.y - (float)ylo * h);
            if (yhi < GRID - 1) g = fminf(g, (float)(yhi + 1) * h - q.y);
            ok = (tau32 < g * (1.0f - 4e-6f));
        }
    }

    // ---------------- SLOW PATH (rare): adaptive, exact ---------------------------
    if (!ok) {
        const int cx = min(GRID - 1, max(0, (int)(q.x * (float)GRID)));
        const int cy = min(GRID - 1, max(0, (int)(q.y * (float)GRID)));
        int L = 2;
        for (;;) {
            const int xlo = max(cx - L, 0), xhi = min(cx + L, GRID - 1);
            const int ylo = max(cy - L, 0), yhi = min(cy + L, GRID - 1);
            const int nrows = yhi - ylo + 1;

            int sv = 0, ev = 0;
            if (sl < nrows) {
                sv = ST[(ylo + sl) * GRID + xlo];
                ev = ST[(ylo + sl) * GRID + xhi + 1];
            }

            float mn1 = INF, mn2 = INF;
            for (int r = 0; r < nrows; ++r) {
                const int s = __shfl(sv, r, 32), e = __shfl(ev, r, 32);
                for (int j = s + sl; j < e; j += 32) {
                    const float2 p = PS[j];
                    const float dx = q.x - p.x, dy = q.y - p.y;
                    const float d2 = __builtin_fmaf(dy, dy, __fmul_rn(dx, dx));
                    const float big = fmaxf(mn1, d2);
                    mn1 = fminf(mn1, d2);
                    mn2 = fminf(mn2, big);
                }
            }

            {
                float v = mn2;
#pragma unroll
                for (int k = 2; k <= 32; k <<= 1) {
#pragma unroll
                    for (int j = k >> 1; j > 0; j >>= 1) {
                        const float o = __shfl_xor(v, j, 32);
                        const bool up = ((sl & k) == 0), lower = ((sl & j) == 0);
                        const float mnv = fminf(v, o), mxv = fmaxf(v, o);
                        v = (lower == up) ? mnv : mxv;
                    }
                }
                mn2 = __shfl(v, 15, 32);
            }
            const float tau2b = mn2 * (1.0f + 4e-6f);

            int base = 0;
            for (int r = 0; r < nrows; ++r) {
                const int s = __shfl(sv, r, 32), e = __shfl(ev, r, 32);
                for (int j0 = s; j0 < e; j0 += 32) {
                    const int j = j0 + sl;
                    const bool valid = (j < e);
                    float2 p = make_float2(0.f, 0.f);
                    if (valid) p = PS[j];
                    const float dx = q.x - p.x, dy = q.y - p.y;
                    const float d2 = __builtin_fmaf(dy, dy, __fmul_rn(dx, dx));
                    const bool pred = valid && (d2 <= tau2b);
                    const unsigned bm = (unsigned)(__ballot(pred) >> (half << 5));
                    if (bm) {
                        const float ex = __fsqrt_rn(__fadd_rn(__fmul_rn(dx, dx),
                                                              __fmul_rn(dy, dy)));
                        const int pos = base + __popc(bm & lmlt32);
                        if (pred && pos < CAP)
                            KEYq[pos] =
                                ((unsigned long long)__float_as_uint(ex) << 32) | (unsigned)IS[j];
                        base += __popc(bm);
                    }
                }
            }

            if (base <= CAP) {
                unsigned long long k0 = (sl      < base) ? KEYq[sl]      : ~0ull;
                unsigned long long k1 = (sl + 32 < base) ? KEYq[sl + 32] : ~0ull;
                int r0 = 0, r1 = 0;
                if (!__any(base > 64)) {
                    for (int t = 0; t < base; ++t) {
                        const unsigned long long kt = KEYq[t];
                        r0 += (kt < k0) ? 1 : 0;
                        r1 += (kt < k1) ? 1 : 0;
                    }
                } else {
                    unsigned long long k2 = (sl + 64 < base) ? KEYq[sl + 64] : ~0ull;
                    unsigned long long k3 = (sl + 96 < base) ? KEYq[sl + 96] : ~0ull;
                    int r2 = 0, r3 = 0;
                    for (int t = 0; t < base; ++t) {
                        const unsigned long long kt = KEYq[t];
                        r0 += (kt < k0) ? 1 : 0;
                        r1 += (kt < k1) ? 1 : 0;
                        r2 += (kt < k2) ? 1 : 0;
                        r3 += (kt < k3) ? 1 : 0;
                    }
                    if (sl + 64 < base && r2 < 32) KEYq[r2] = k2;
                    if (sl + 96 < base && r3 < 32) KEYq[r3] = k3;
                }
                if (sl      < base && r0 < 32) KEYq[r0] = k0;
                if (sl + 32 < base && r1 < 32) KEYq[r1] = k1;
                if (base < 32 && sl >= base) KEYq[sl] = ~0ull;   // pad -> NaN -> expand
                const unsigned long long kf = KEYq[sl];
                bd = __uint_as_float((unsigned)(kf >> 32));
                bi = (int)(unsigned)(kf & 0xffffffffull);
            } else {
                float fd = INF; int fi = 0x7FFFFFFF;
                for (int r = 0; r < nrows; ++r) {
                    const int s = __shfl(sv, r, 32), e = __shfl(ev, r, 32);
                    for (int j0 = s; j0 < e; j0 += 32) {
                        const int j = j0 + sl;
                        const bool valid = (j < e);
                        float2 p = make_float2(0.f, 0.f);
                        int vi0 = 0x7FFFFFFF;
                        if (valid) { p = PS[j]; vi0 = IS[j]; }
                        const float dx = q.x - p.x, dy = q.y - p.y;
                        const float d2 = __builtin_fmaf(dy, dy, __fmul_rn(dx, dx));
                        unsigned cm = (unsigned)(__ballot(valid && (d2 <= tau2b)) >> (half << 5));
                        const float ex = __fsqrt_rn(__fadd_rn(__fmul_rn(dx, dx),
                                                              __fmul_rn(dy, dy)));
                        while (cm) {
                            const int l = __builtin_ctz(cm); cm &= cm - 1;
                            const float v  = __shfl(ex, l, 32);
                            const int   vi = __shfl(vi0, l, 32);
                            const bool cl = (fd < v) || (fd == v && fi < vi);
                            const int pos = __popc((unsigned)(__ballot(cl) >> (half << 5)));
                            const float sd = __shfl_up(fd, 1, 32);
                            const int   si = __shfl_up(fi, 1, 32);
                            fd = (sl < pos) ? fd : ((sl == pos) ? v  : sd);
                            fi = (sl < pos) ? fi : ((sl == pos) ? vi : si);
                        }
                    }
                }
                bd = fd; bi = fi;
            }

            const float tau = __shfl(bd, 31, 32);
            float g = INF;
            if (xlo > 0)        g = fminf(g, q.x - (float)xlo * h);
            if (xhi < GRID - 1) g = fminf(g, (float)(xhi + 1) * h - q.x);
            if (ylo > 0)        g = fminf(g, q.y - (float)ylo * h);
            if (yhi < GRID - 1) g = fminf(g, (float)(yhi + 1) * h - q.y);
            if (tau < g * (1.0f - 4e-6f)) break;
            L += 2;
            if (L > GRID - 1) L = GRID - 1;
        }
    }

    // ---- outputs 0 and 1: uiv_k and idx (as float) ----
    {
        const float2 pk = P[bi];
        float2 u;
        u.x = q.x - pk.x;
        u.y = q.y - pk.y;
        ((float2*)out_uiv)[(size_t)wid * KK + sl] = u;
        out_idx[(size_t)wid * KK + sl] = (float)bi;
    }
}

// ==== K2: gather + einsum + reduce. 8 queries / 256-thread block. ================
// Phase A: lane sl stages its own neighbor's value row into LDS.
// Phase G: T accumulation, v from LDS (broadcast-optimal).
// Phase R v2 (block-cooperative): wave w owns i-slice [8w,8w+8); lane (q,o4)
// accumulates out[q][o4*4..+3]. C addresses depend only on o4 -> 8x float4 =
// 128B/instr, broadcast across q, conflict-free, and C is read ONCE per block.
// T addresses depend only on q -> conflict-free via VQS=1156 skew (phase 4q).
__global__ __launch_bounds__(256) void conv_apply(
    const float* __restrict__ values_in,
    const float* __restrict__ out_uiv, const float* __restrict__ out_idx,
    const float* __restrict__ coeff2, const float* __restrict__ bias,
    float* __restrict__ out_val)
{
    __shared__ alignas(16) float VL[QPB2][VQS];          // 36992 B
    __shared__ alignas(16) float CL[ECH][CIN][COUT];     // 16384 B (53376 total)

    const int tid   = threadIdx.x;
    const int sl    = tid & 31;
    const int qslot = tid >> 5;            // 0..7
    const int wid   = blockIdx.x * QPB2 + qslot;
    const int b     = wid >> 13;

    float* VLq = &VL[qslot][0];

    // neighbor #sl of this query: u stored exactly in K1 -> bd bit-exact
    const float2 u = ((const float2*)out_uiv)[(size_t)wid * KK + sl];
    const float bd = __fsqrt_rn(__fadd_rn(__fmul_rn(u.x, u.x), __fmul_rn(u.y, u.y)));
    const int   bi = (int)out_idx[(size_t)wid * KK + sl];

    // ---- Phase A: stage my neighbor's 32-float value row into LDS ----
    {
        const float4* src = (const float4*)(values_in + ((size_t)b * NN + bi) * CIN);
        const float4 r0 = src[0], r1 = src[1], r2 = src[2], r3 = src[3];
        const float4 r4 = src[4], r5 = src[5], r6 = src[6], r7 = src[7];
        float4* dst = (float4*)(VLq + sl * VROW);
        dst[0] = r0; dst[1] = r1; dst[2] = r2; dst[3] = r3;
        dst[4] = r4; dst[5] = r5; dst[6] = r6; dst[7] = r7;
    }

    // ---- Phase G: T[e][i] = sum_k exp(-256*(r_k - mu_e)^2) * v_k[i], v from LDS --
    {
        const int e2 = sl >> 2;                 // 0..7 -> e in {2*e2, 2*e2+1}
        const int iq = sl & 3;                  // i-block of 8
        const float mu0 = (float)(2 * e2)     * (1.0f / 15.0f);
        const float mu1 = (float)(2 * e2 + 1) * (1.0f / 15.0f);
        float4 A0a = make_float4(0.f, 0.f, 0.f, 0.f);
        float4 A0b = A0a, A1a = A0a, A1b = A0a;
#pragma unroll 8
        for (int k = 0; k < KK; ++k) {
            const float rk = __shfl(bd, k, 32);
            const float d0 = rk - mu0;
            const float d1 = rk - mu1;
            const float w0 = __expf(-256.0f * d0 * d0);
            const float w1 = __expf(-256.0f * d1 * d1);
            const float4* vr = (const float4*)(VLq + k * VROW + iq * 8);
            const float4 va = vr[0], vb = vr[1];
            A0a.x += w0 * va.x; A0a.y += w0 * va.y; A0a.z += w0 * va.z; A0a.w += w0 * va.w;
            A0b.x += w0 * vb.x; A0b.y += w0 * vb.y; A0b.z += w0 * vb.z; A0b.w += w0 * vb.w;
            A1a.x += w1 * va.x; A1a.y += w1 * va.y; A1a.z += w1 * va.z; A1a.w += w1 * va.w;
            A1b.x += w1 * vb.x; A1b.y += w1 * vb.y; A1b.z += w1 * vb.z; A1b.w += w1 * vb.w;
        }
        // overlay T (16 x VROW floats) onto the VL region -- all G reads precede
        // these stores in program order within this same half-wave.
        float4* t0 = (float4*)(VLq + (2 * e2)     * VROW + iq * 8);
        float4* t1 = (float4*)(VLq + (2 * e2 + 1) * VROW + iq * 8);
        t0[0] = A0a; t0[1] = A0b;
        t1[0] = A1a; t1[1] = A1b;
    }

    // ---- Phase R v2: block-cooperative out = C . T over all 8 queries ----
    {
        const int w  = tid >> 6;          // wave: i-slice [8w, 8w+8)
        const int rq = (tid >> 3) & 7;    // query
        const int ro = tid & 7;           // o-chunk (4 outputs)
        float4 s4 = make_float4(0.f, 0.f, 0.f, 0.f);
        const float* Tq = &VL[rq][0];
#pragma unroll
        for (int ec = 0; ec < EE / ECH; ++ec) {
            __syncthreads();               // G complete (ec=0) / prior chunk consumed
            {
                const float4* src = (const float4*)(coeff2 + ec * (ECH * CIN * COUT));
                float4* dst = (float4*)&CL[0][0][0];
#pragma unroll
                for (int j = 0; j < (ECH * CIN * COUT) / (4 * 256); ++j) {
                    const int idx = tid + j * 256;
                    dst[idx] = src[idx];
                }
            }
            __syncthreads();
#pragma unroll
            for (int el = 0; el < ECH; ++el) {
                const int e = ec * ECH + el;
                const float* Trow = Tq + e * VROW + 8 * w;
                const float* Crow = &CL[el][8 * w][0] + ro * 4;
#pragma unroll
                for (int ir = 0; ir < 8; ++ir) {
                    const float t = Trow[ir];
                    const float4 c = *(const float4*)(Crow + ir * COUT);
                    s4.x += t * c.x; s4.y += t * c.y;
                    s4.z += t * c.z; s4.w += t * c.w;
                }
            }
        }
        // cross-wave combine via PART overlay on CL
        __syncthreads();
        float4* PART = (float4*)&CL[0][0][0];    // [w][rq][ro] = tid order, 4KB
        PART[tid] = s4;
        __syncthreads();
        if (w == 0) {
            const float4 p0 = PART[tid];
            const float4 p1 = PART[tid + 64];
            const float4 p2 = PART[tid + 128];
            const float4 p3 = PART[tid + 192];
            const float4 bv = *(const float4*)(bias + ro * 4);
            float4 ov;
            ov.x = (p0.x + p1.x + p2.x + p3.x) * (1.0f / 32.0f) + bv.x;
            ov.y = (p0.y + p1.y + p2.y + p3.y) * (1.0f / 32.0f) + bv.y;
            ov.z = (p0.z + p1.z + p2.z + p3.z) * (1.0f / 32.0f) + bv.z;
            ov.w = (p0.w + p1.w + p2.w + p3.w) * (1.0f / 32.0f) + bv.w;
            const int qw = blockIdx.x * QPB2 + rq;
            *(float4*)(out_val + (size_t)qw * COUT + ro * 4) = ov;
        }
    }
}

extern "C" void kernel_launch(void* const* d_in, const int* in_sizes, int n_in,
                              void* d_out, int out_size, void* d_ws, size_t ws_size,
                              hipStream_t stream) {
    const float* points_in  = (const float*)d_in[0];
    const float* values_in  = (const float*)d_in[1];
    const float* points_out = (const float*)d_in[2];
    const float* coeff      = (const float*)d_in[3];
    const float* bias       = (const float*)d_in[4];

    float* out     = (float*)d_out;
    float* out_uiv = out;                                        // B*M*K*2
    float* out_idx = out + (size_t)BB * MM * KK * 2;             // B*M*K
    float* out_val = out_idx + (size_t)BB * MM * KK;             // B*M*COUT

    char* ws = (char*)d_ws;
    float*  coeff2 = (float*)(ws + OFS_COEFFT);
    int*    counts = (int*)  (ws + OFS_COUNTS);
    int*    cursor = (int*)  (ws + OFS_CURSOR);
    int*    strts  = (int*)  (ws + OFS_STARTS);
    float2* pts_s  = (float2*)(ws + OFS_PTSS);
    int*    idx_s  = (int*)  (ws + OFS_IDXS);

    hipLaunchKernelGGL(transpose_coeff, dim3(64), dim3(256), 0, stream, coeff, coeff2);
    hipLaunchKernelGGL(bin_zero, dim3(16), dim3(256), 0, stream, counts);
    hipLaunchKernelGGL(bin_count, dim3(64), dim3(256), 0, stream, points_in, counts);
    hipLaunchKernelGGL(bin_scan, dim3(1), dim3(1024), 0, stream, counts, strts);
    hipLaunchKernelGGL(bin_scatter, dim3(64), dim3(256), 0, stream,
                       points_in, strts, cursor, pts_s, idx_s);

    const int blocks1 = (BB * MM) / QPB;                         // 4096
    hipLaunchKernelGGL(conv_knn, dim3(blocks1), dim3(128), 0, stream,
                       pts_s, idx_s, strts, points_in, points_out,
                       out_uiv, out_idx);

    const int blocks2 = (BB * MM) / QPB2;                        // 2048
    hipLaunchKernelGGL(conv_apply, dim3(blocks2), dim3(256), 0, stream,
                       values_in, out_uiv, out_idx, coeff2, bias, out_val);
}

// Round 18
// 69.229 us; speedup vs baseline: 2.4542x; 1.0241x over previous
//
#include <hip/hip_runtime.h>
#include <cstdint>
#include <cstddef>

// Problem constants (from reference)
constexpr int BB   = 2;
constexpr int NN   = 8192;
constexpr int MM   = 8192;
constexpr int CIN  = 32;
constexpr int COUT = 32;
constexpr int EE   = 16;
constexpr int KK   = 32;
constexpr int GRID = 32;              // binning grid (h = 1/32, ~8 pts/cell)
constexpr int NCELL = GRID * GRID;

#define QPB 4            // K1: queries per 128-thread block
#define QPB2 8           // K2: queries per 256-thread block
#define CAP 128
#define KEY_BYTES 1040   // 128 u64 + 16B skew
#define VROW 36          // K2: padded value-row stride in floats (144B)
#define VQS  1156        // K2: per-query VL stride (32*36 + 4: bank-phase skew 4q)
#define ECH 4            // K2: e-chunk size for coeff LDS staging

// Fixed-radius fast path: lambda = pi*R0^2*N ~ 58 expected candidates.
#define R0_FAST 0.0475f

// Workspace layout (bytes)
constexpr size_t OFS_COEFFT = 0;        // coeff2[E][CIN][COUT]: 16384 f = 65536 B
constexpr size_t OFS_COUNTS = 65536;    // 2*1024 i = 8192 B
constexpr size_t OFS_CURSOR = 73728;    // 2*1024 i = 8192 B
constexpr size_t OFS_STARTS = 81920;    // 2*1025 i = 8200 B (pad to 8704)
constexpr size_t OFS_PTSS   = 90624;    // 2*8192 float2 = 131072 B
constexpr size_t OFS_IDXS   = 221696;   // 2*8192 i = 65536 B  (total 287232 B)

// ---- fused: zero counters/cursors + coeff [CIN][COUT][E] -> coeff2 [E][CIN][COUT]
__global__ __launch_bounds__(256) void prep_coeff_zero(const float* __restrict__ coeff,
                                                       float* __restrict__ coeff2,
                                                       int* __restrict__ cz) {
    int tid = blockIdx.x * 256 + threadIdx.x;
    if (tid < 2 * 2 * NCELL) cz[tid] = 0;             // counts + cursor
    if (tid >= EE * CIN * COUT) return;
    int o = tid & 31;
    int i = (tid >> 5) & 31;
    int e = tid >> 10;
    coeff2[tid] = coeff[(i * COUT + o) * EE + e];
}

// ---- binning: count, scan, scatter ----------------------------------------------
__device__ __forceinline__ int cell_of(float2 p) {
    int cx = min(GRID - 1, max(0, (int)(p.x * (float)GRID)));
    int cy = min(GRID - 1, max(0, (int)(p.y * (float)GRID)));
    return cy * GRID + cx;
}

__global__ __launch_bounds__(256) void bin_count(const float* __restrict__ pts,
                                                 int* __restrict__ counts) {
    int t = blockIdx.x * 256 + threadIdx.x;
    int b = t >> 13, i = t & (NN - 1);
    float2 p = ((const float2*)pts)[(size_t)b * NN + i];
    atomicAdd(&counts[b * NCELL + cell_of(p)], 1);
}

__global__ __launch_bounds__(1024) void bin_scan(const int* __restrict__ counts,
                                                 int* __restrict__ starts) {
    __shared__ int sm[NCELL];
    const int t = threadIdx.x;
    for (int b = 0; b < BB; ++b) {
        sm[t] = counts[b * NCELL + t];
        __syncthreads();
        for (int off = 1; off < NCELL; off <<= 1) {
            int v = (t >= off) ? sm[t - off] : 0;
            __syncthreads();
            sm[t] += v;
            __syncthreads();
        }
        starts[b * (NCELL + 1) + t + 1] = sm[t];
        if (t == 0) starts[b * (NCELL + 1)] = 0;
        __syncthreads();
    }
}

__global__ __launch_bounds__(256) void bin_scatter(const float* __restrict__ pts,
                                                   const int* __restrict__ starts,
                                                   int* __restrict__ cursor,
                                                   float2* __restrict__ pts_s,
                                                   int* __restrict__ idx_s) {
    int t = blockIdx.x * 256 + threadIdx.x;
    int b = t >> 13, i = t & (NN - 1);
    float2 p = ((const float2*)pts)[(size_t)b * NN + i];
    int cell = cell_of(p);
    int pos = starts[b * (NCELL + 1) + cell] + atomicAdd(&cursor[b * NCELL + cell], 1);
    pts_s[(size_t)b * NN + pos] = p;     // intra-cell order nondeterministic; final
    idx_s[(size_t)b * NN + pos] = i;     // rank by (d, orig idx) makes output exact.
}

// ==== K1: KNN selection only. One half-wave (32 lanes) per query. ================
__global__ __launch_bounds__(128) void conv_knn(
    const float2* __restrict__ pts_s, const int* __restrict__ idx_s,
    const int* __restrict__ starts,
    const float* __restrict__ points_in,
    const float* __restrict__ points_out,
    float* __restrict__ out_uiv, float* __restrict__ out_idx)
{
    __shared__ alignas(16) unsigned char SMEM[QPB][KEY_BYTES];

    const int tid   = threadIdx.x;
    const int sl    = tid & 31;
    const int qslot = tid >> 5;            // 0..3
    const int half  = qslot & 1;
    const int wid   = blockIdx.x * QPB + qslot;
    const int b     = wid >> 13;
    const int m     = wid & (MM - 1);

    unsigned long long* KEYq = (unsigned long long*)&SMEM[qslot][0];

    const float2* PS = pts_s + (size_t)b * NN;
    const int*    IS = idx_s + (size_t)b * NN;
    const int*    ST = starts + b * (NCELL + 1);
    const float2* P  = ((const float2*)points_in) + (size_t)b * NN;
    const float2  q  = ((const float2*)points_out)[(size_t)b * MM + m];

    const float INF = __builtin_inff();
    const float h = 1.0f / (float)GRID;
    const unsigned lmlt32 = (1u << sl) - 1u;

    float bd;   // sorted exact distance (sub-lane sl holds entry #sl)
    int   bi;   // sorted original index
    bool  ok = false;

    // ---------------- FAST PATH: fixed analytic radius, single scan ---------------
    {
        float tau = R0_FAST;
        {
            const float bx = fminf(q.x, 1.0f - q.x);
            const float by = fminf(q.y, 1.0f - q.y);
#pragma unroll
            for (int it = 0; it < 3; ++it) {
                const float wx = 0.5f + 0.5f * fminf(bx / tau, 1.0f);
                const float wy = 0.5f + 0.5f * fminf(by / tau, 1.0f);
                tau = R0_FAST * __frsqrt_rn(wx * wy);
            }
        }
        const float tau2  = tau * tau;
        const float tau2a = tau2 * (1.0f + 2e-6f);

        const int xlo = (int)fmaxf((q.x - tau) * (float)GRID, 0.0f);
        const int xhi = (int)fminf((q.x + tau) * (float)GRID, (float)(GRID - 1));
        const int ylo = (int)fmaxf((q.y - tau) * (float)GRID, 0.0f);
        const int yhi = (int)fminf((q.y + tau) * (float)GRID, (float)(GRID - 1));
        const int nrows = yhi - ylo + 1;

        int sv = 0, ev = 0;
        if (sl < nrows) {
            sv = ST[(ylo + sl) * GRID + xlo];
            ev = ST[(ylo + sl) * GRID + xhi + 1];
        }

        int base = 0, nin = 0;
        for (int r = 0; r < nrows; ++r) {
            const int s = __shfl(sv, r, 32), e = __shfl(ev, r, 32);
            for (int j0 = s; j0 < e; j0 += 32) {
                const int j = j0 + sl;
                const bool valid = (j < e);
                float2 p = make_float2(2.0f, 2.0f);
                if (valid) p = PS[j];
                const float dx = q.x - p.x, dy = q.y - p.y;
                const float d2 = __builtin_fmaf(dy, dy, __fmul_rn(dx, dx));
                const bool adm = valid && (d2 <= tau2a);
                const unsigned bmA = (unsigned)(__ballot(adm) >> (half << 5));
                const unsigned bmS = (unsigned)(__ballot(valid && (d2 <= tau2)) >> (half << 5));
                nin += __popc(bmS);
                if (bmA) {
                    const float ex = __fsqrt_rn(__fadd_rn(__fmul_rn(dx, dx),
                                                          __fmul_rn(dy, dy)));
                    const int pos = base + __popc(bmA & lmlt32);
                    if (adm && pos < CAP)
                        KEYq[pos] =
                            ((unsigned long long)__float_as_uint(ex) << 32) | (unsigned)IS[j];
                    base += __popc(bmA);
                }
            }
        }

        ok = (nin >= 32) && (base <= CAP);
        if (ok) {
            unsigned long long k0 = (sl      < base) ? KEYq[sl]      : ~0ull;
            unsigned long long k1 = (sl + 32 < base) ? KEYq[sl + 32] : ~0ull;
            int r0 = 0, r1 = 0;
            if (!__any(base > 64)) {
                for (int t = 0; t < base; ++t) {
                    const unsigned long long kt = KEYq[t];
                    r0 += (kt < k0) ? 1 : 0;
                    r1 += (kt < k1) ? 1 : 0;
                }
            } else {
                unsigned long long k2 = (sl + 64 < base) ? KEYq[sl + 64] : ~0ull;
                unsigned long long k3 = (sl + 96 < base) ? KEYq[sl + 96] : ~0ull;
                int r2 = 0, r3 = 0;
                for (int t = 0; t < base; ++t) {
                    const unsigned long long kt = KEYq[t];
                    r0 += (kt < k0) ? 1 : 0;
                    r1 += (kt < k1) ? 1 : 0;
                    r2 += (kt < k2) ? 1 : 0;
                    r3 += (kt < k3) ? 1 : 0;
                }
                if (sl + 64 < base && r2 < 32) KEYq[r2] = k2;
                if (sl + 96 < base && r3 < 32) KEYq[r3] = k3;
            }
            if (sl      < base && r0 < 32) KEYq[r0] = k0;
            if (sl + 32 < base && r1 < 32) KEYq[r1] = k1;
            const unsigned long long kf = KEYq[sl];
            bd = __uint_as_float((unsigned)(kf >> 32));
            bi = (int)(unsigned)(kf & 0xffffffffull);

            const float tau32 = __shfl(bd, 31, 32);
            float g = INF;
            if (xlo > 0)        g = fminf(g, q.x - (float)xlo * h);
            if (xhi < GRID - 1) g = fminf(g, (float)(xhi + 1) * h - q.x);
            if (ylo > 0)        g = fminf(g, q.y - (float)ylo * h);
            if (yhi < GRID - 1) g = fminf(g, (float)(yhi + 1) * h - q.y);
            ok = (tau32 < g * (1.0f - 4e-6f));
        }
    }

    // ---------------- SLOW PATH (rare): adaptive, exact ---------------------------
    if (!ok) {
        const int cx = min(GRID - 1, max(0, (int)(q.x * (float)GRID)));
        const int cy = min(GRID - 1, max(0, (int)(q.y * (float)GRID)));
        int L = 2;
        for (;;) {
            const int xlo = max(cx - L, 0), xhi = min(cx + L, GRID - 1);
            const int ylo = max(cy - L, 0), yhi = min(cy + L, GRID - 1);
            const int nrows = yhi - ylo + 1;

            int sv = 0, ev = 0;
            if (sl < nrows) {
                sv = ST[(ylo + sl) * GRID + xlo];
                ev = ST[(ylo + sl) * GRID + xhi + 1];
            }

            float mn1 = INF, mn2 = INF;
            for (int r = 0; r < nrows; ++r) {
                const int s = __shfl(sv, r, 32), e = __shfl(ev, r, 32);
                for (int j = s + sl; j < e; j += 32) {
                    const float2 p = PS[j];
                    const float dx = q.x - p.x, dy = q.y - p.y;
                    const float d2 = __builtin_fmaf(dy, dy, __fmul_rn(dx, dx));
                    const float big = fmaxf(mn1, d2);
                    mn1 = fminf(mn1, d2);
                    mn2 = fminf(mn2, big);
                }
            }

            {
                float v = mn2;
#pragma unroll
                for (int k = 2; k <= 32; k <<= 1) {
#pragma unroll
                    for (int j = k >> 1; j > 0; j >>= 1) {
                        const float o = __shfl_xor(v, j, 32);
                        const bool up = ((sl & k) == 0), lower = ((sl & j) == 0);
                        const float mnv = fminf(v, o), mxv = fmaxf(v, o);
                        v = (lower == up) ? mnv : mxv;
                    }
                }
                mn2 = __shfl(v, 15, 32);
            }
            const float tau2b = mn2 * (1.0f + 4e-6f);

            int base = 0;
            for (int r = 0; r < nrows; ++r) {
                const int s = __shfl(sv, r, 32), e = __shfl(ev, r, 32);
                for (int j0 = s; j0 < e; j0 += 32) {
                    const int j = j0 + sl;
                    const bool valid = (j < e);
                    float2 p = make_float2(0.f, 0.f);
                    if (valid) p = PS[j];
                    const float dx = q.x - p.x, dy = q.y - p.y;
                    const float d2 = __builtin_fmaf(dy, dy, __fmul_rn(dx, dx));
                    const bool pred = valid && (d2 <= tau2b);
                    const unsigned bm = (unsigned)(__ballot(pred) >> (half << 5));
                    if (bm) {
                        const float ex = __fsqrt_rn(__fadd_rn(__fmul_rn(dx, dx),
                                                              __fmul_rn(dy, dy)));
                        const int pos = base + __popc(bm & lmlt32);
                        if (pred && pos < CAP)
                            KEYq[pos] =
                                ((unsigned long long)__float_as_uint(ex) << 32) | (unsigned)IS[j];
                        base += __popc(bm);
                    }
                }
            }

            if (base <= CAP) {
                unsigned long long k0 = (sl      < base) ? KEYq[sl]      : ~0ull;
                unsigned long long k1 = (sl + 32 < base) ? KEYq[sl + 32] : ~0ull;
                int r0 = 0, r1 = 0;
                if (!__any(base > 64)) {
                    for (int t = 0; t < base; ++t) {
                        const unsigned long long kt = KEYq[t];
                        r0 += (kt < k0) ? 1 : 0;
                        r1 += (kt < k1) ? 1 : 0;
                    }
                } else {
                    unsigned long long k2 = (sl + 64 < base) ? KEYq[sl + 64] : ~0ull;
                    unsigned long long k3 = (sl + 96 < base) ? KEYq[sl + 96] : ~0ull;
                    int r2 = 0, r3 = 0;
                    for (int t = 0; t < base; ++t) {
                        const unsigned long long kt = KEYq[t];
                        r0 += (kt < k0) ? 1 : 0;
                        r1 += (kt < k1) ? 1 : 0;
                        r2 += (kt < k2) ? 1 : 0;
                        r3 += (kt < k3) ? 1 : 0;
                    }
                    if (sl + 64 < base && r2 < 32) KEYq[r2] = k2;
                    if (sl + 96 < base && r3 < 32) KEYq[r3] = k3;
                }
                if (sl      < base && r0 < 32) KEYq[r0] = k0;
                if (sl + 32 < base && r1 < 32) KEYq[r1] = k1;
                if (base < 32 && sl >= base) KEYq[sl] = ~0ull;   // pad -> NaN -> expand
                const unsigned long long kf = KEYq[sl];
                bd = __uint_as_float((unsigned)(kf >> 32));
                bi = (int)(unsigned)(kf & 0xffffffffull);
            } else {
                float fd = INF; int fi = 0x7FFFFFFF;
                for (int r = 0; r < nrows; ++r) {
                    const int s = __shfl(sv, r, 32), e = __shfl(ev, r, 32);
                    for (int j0 = s; j0 < e; j0 += 32) {
                        const int j = j0 + sl;
                        const bool valid = (j < e);
                        float2 p = make_float2(0.f, 0.f);
                        int vi0 = 0x7FFFFFFF;
                        if (valid) { p = PS[j]; vi0 = IS[j]; }
                        const float dx = q.x - p.x, dy = q.y - p.y;
                        const float d2 = __builtin_fmaf(dy, dy, __fmul_rn(dx, dx));
                        unsigned cm = (unsigned)(__ballot(valid && (d2 <= tau2b)) >> (half << 5));
                        const float ex = __fsqrt_rn(__fadd_rn(__fmul_rn(dx, dx),
                                                              __fmul_rn(dy, dy)));
                        while (cm) {
                            const int l = __builtin_ctz(cm); cm &= cm - 1;
                            const float v  = __shfl(ex, l, 32);
                            const int   vi = __shfl(vi0, l, 32);
                            const bool cl = (fd < v) || (fd == v && fi < vi);
                            const int pos = __popc((unsigned)(__ballot(cl) >> (half << 5)));
                            const float sd = __shfl_up(fd, 1, 32);
                            const int   si = __shfl_up(fi, 1, 32);
                            fd = (sl < pos) ? fd : ((sl == pos) ? v  : sd);
                            fi = (sl < pos) ? fi : ((sl == pos) ? vi : si);
                        }
                    }
                }
                bd = fd; bi = fi;
            }

            const float tau = __shfl(bd, 31, 32);
            float g = INF;
            if (xlo > 0)        g = fminf(g, q.x - (float)xlo * h);
            if (xhi < GRID - 1) g = fminf(g, (float)(xhi + 1) * h - q.x);
            if (ylo > 0)        g = fminf(g, q.y - (float)ylo * h);
            if (yhi < GRID - 1) g = fminf(g, (float)(yhi + 1) * h - q.y);
            if (tau < g * (1.0f - 4e-6f)) break;
            L += 2;
            if (L > GRID - 1) L = GRID - 1;
        }
    }

    // ---- outputs 0 and 1: uiv_k and idx (as float) ----
    {
        const float2 pk = P[bi];
        float2 u;
        u.x = q.x - pk.x;
        u.y = q.y - pk.y;
        ((float2*)out_uiv)[(size_t)wid * KK + sl] = u;
        out_idx[(size_t)wid * KK + sl] = (float)bi;
    }
}

// ==== K2: gather + einsum + reduce. 8 queries / 256-thread block. ================
// Phase A: lane sl stages its own neighbor's value row into LDS.
// Phase G: T accumulation, v from LDS (broadcast-optimal).
// Phase R (block-cooperative): wave w owns i-slice [8w,8w+8); lane (q,o4)
// accumulates out[q][o4*4..+3]. C read once per block, float4, conflict-free;
// T read as 2 float4 per e (16B-aligned: e*144B + 32wB).
__global__ __launch_bounds__(256) void conv_apply(
    const float* __restrict__ values_in,
    const float* __restrict__ out_uiv, const float* __restrict__ out_idx,
    const float* __restrict__ coeff2, const float* __restrict__ bias,
    float* __restrict__ out_val)
{
    __shared__ alignas(16) float VL[QPB2][VQS];          // 36992 B
    __shared__ alignas(16) float CL[ECH][CIN][COUT];     // 16384 B (53376 total)

    const int tid   = threadIdx.x;
    const int sl    = tid & 31;
    const int qslot = tid >> 5;            // 0..7
    const int wid   = blockIdx.x * QPB2 + qslot;
    const int b     = wid >> 13;

    float* VLq = &VL[qslot][0];

    // neighbor #sl of this query: u stored exactly in K1 -> bd bit-exact
    const float2 u = ((const float2*)out_uiv)[(size_t)wid * KK + sl];
    const float bd = __fsqrt_rn(__fadd_rn(__fmul_rn(u.x, u.x), __fmul_rn(u.y, u.y)));
    const int   bi = (int)out_idx[(size_t)wid * KK + sl];

    // ---- Phase A: stage my neighbor's 32-float value row into LDS ----
    {
        const float4* src = (const float4*)(values_in + ((size_t)b * NN + bi) * CIN);
        const float4 r0 = src[0], r1 = src[1], r2 = src[2], r3 = src[3];
        const float4 r4 = src[4], r5 = src[5], r6 = src[6], r7 = src[7];
        float4* dst = (float4*)(VLq + sl * VROW);
        dst[0] = r0; dst[1] = r1; dst[2] = r2; dst[3] = r3;
        dst[4] = r4; dst[5] = r5; dst[6] = r6; dst[7] = r7;
    }

    // ---- Phase G: T[e][i] = sum_k exp(-256*(r_k - mu_e)^2) * v_k[i], v from LDS --
    {
        const int e2 = sl >> 2;                 // 0..7 -> e in {2*e2, 2*e2+1}
        const int iq = sl & 3;                  // i-block of 8
        const float mu0 = (float)(2 * e2)     * (1.0f / 15.0f);
        const float mu1 = (float)(2 * e2 + 1) * (1.0f / 15.0f);
        float4 A0a = make_float4(0.f, 0.f, 0.f, 0.f);
        float4 A0b = A0a, A1a = A0a, A1b = A0a;
#pragma unroll 8
        for (int k = 0; k < KK; ++k) {
            const float rk = __shfl(bd, k, 32);
            const float d0 = rk - mu0;
            const float d1 = rk - mu1;
            const float w0 = __expf(-256.0f * d0 * d0);
            const float w1 = __expf(-256.0f * d1 * d1);
            const float4* vr = (const float4*)(VLq + k * VROW + iq * 8);
            const float4 va = vr[0], vb = vr[1];
            A0a.x += w0 * va.x; A0a.y += w0 * va.y; A0a.z += w0 * va.z; A0a.w += w0 * va.w;
            A0b.x += w0 * vb.x; A0b.y += w0 * vb.y; A0b.z += w0 * vb.z; A0b.w += w0 * vb.w;
            A1a.x += w1 * va.x; A1a.y += w1 * va.y; A1a.z += w1 * va.z; A1a.w += w1 * va.w;
            A1b.x += w1 * vb.x; A1b.y += w1 * vb.y; A1b.z += w1 * vb.z; A1b.w += w1 * vb.w;
        }
        // overlay T (16 x VROW floats) onto the VL region -- all G reads precede
        // these stores in program order within this same half-wave.
        float4* t0 = (float4*)(VLq + (2 * e2)     * VROW + iq * 8);
        float4* t1 = (float4*)(VLq + (2 * e2 + 1) * VROW + iq * 8);
        t0[0] = A0a; t0[1] = A0b;
        t1[0] = A1a; t1[1] = A1b;
    }

    // ---- Phase R: block-cooperative out = C . T over all 8 queries ----
    {
        const int w  = tid >> 6;          // wave: i-slice [8w, 8w+8)
        const int rq = (tid >> 3) & 7;    // query
        const int ro = tid & 7;           // o-chunk (4 outputs)
        float4 s4 = make_float4(0.f, 0.f, 0.f, 0.f);
        const float* Tq = &VL[rq][0];
#pragma unroll
        for (int ec = 0; ec < EE / ECH; ++ec) {
            __syncthreads();               // G complete (ec=0) / prior chunk consumed
            {
                const float4* src = (const float4*)(coeff2 + ec * (ECH * CIN * COUT));
                float4* dst = (float4*)&CL[0][0][0];
#pragma unroll
                for (int j = 0; j < (ECH * CIN * COUT) / (4 * 256); ++j) {
                    const int idx = tid + j * 256;
                    dst[idx] = src[idx];
                }
            }
            __syncthreads();
#pragma unroll
            for (int el = 0; el < ECH; ++el) {
                const int e = ec * ECH + el;
                const float* Trow = Tq + e * VROW + 8 * w;
                const float4 ta = *(const float4*)(Trow);        // 16B-aligned
                const float4 tb = *(const float4*)(Trow + 4);
                const float* Crow = &CL[el][8 * w][0] + ro * 4;
#pragma unroll
                for (int ir = 0; ir < 4; ++ir) {
                    const float t = (ir == 0) ? ta.x : (ir == 1) ? ta.y
                                  : (ir == 2) ? ta.z : ta.w;
                    const float4 c = *(const float4*)(Crow + ir * COUT);
                    s4.x += t * c.x; s4.y += t * c.y;
                    s4.z += t * c.z; s4.w += t * c.w;
                }
#pragma unroll
                for (int ir = 0; ir < 4; ++ir) {
                    const float t = (ir == 0) ? tb.x : (ir == 1) ? tb.y
                                  : (ir == 2) ? tb.z : tb.w;
                    const float4 c = *(const float4*)(Crow + (4 + ir) * COUT);
                    s4.x += t * c.x; s4.y += t * c.y;
                    s4.z += t * c.z; s4.w += t * c.w;
                }
            }
        }
        // cross-wave combine via PART overlay on CL
        __syncthreads();
        float4* PART = (float4*)&CL[0][0][0];    // [w][rq][ro] = tid order, 4KB
        PART[tid] = s4;
        __syncthreads();
        if (w == 0) {
            const float4 p0 = PART[tid];
            const float4 p1 = PART[tid + 64];
            const float4 p2 = PART[tid + 128];
            const float4 p3 = PART[tid + 192];
            const float4 bv = *(const float4*)(bias + ro * 4);
            float4 ov;
            ov.x = (p0.x + p1.x + p2.x + p3.x) * (1.0f / 32.0f) + bv.x;
            ov.y = (p0.y + p1.y + p2.y + p3.y) * (1.0f / 32.0f) + bv.y;
            ov.z = (p0.z + p1.z + p2.z + p3.z) * (1.0f / 32.0f) + bv.z;
            ov.w = (p0.w + p1.w + p2.w + p3.w) * (1.0f / 32.0f) + bv.w;
            const int qw = blockIdx.x * QPB2 + rq;
            *(float4*)(out_val + (size_t)qw * COUT + ro * 4) = ov;
        }
    }
}

extern "C" void kernel_launch(void* const* d_in, const int* in_sizes, int n_in,
                              void* d_out, int out_size, void* d_ws, size_t ws_size,
                              hipStream_t stream) {
    const float* points_in  = (const float*)d_in[0];
    const float* values_in  = (const float*)d_in[1];
    const float* points_out = (const float*)d_in[2];
    const float* coeff      = (const float*)d_in[3];
    const float* bias       = (const float*)d_in[4];

    float* out     = (float*)d_out;
    float* out_uiv = out;                                        // B*M*K*2
    float* out_idx = out + (size_t)BB * MM * KK * 2;             // B*M*K
    float* out_val = out_idx + (size_t)BB * MM * KK;             // B*M*COUT

    char* ws = (char*)d_ws;
    float*  coeff2 = (float*)(ws + OFS_COEFFT);
    int*    counts = (int*)  (ws + OFS_COUNTS);
    int*    cursor = (int*)  (ws + OFS_CURSOR);
    int*    strts  = (int*)  (ws + OFS_STARTS);
    float2* pts_s  = (float2*)(ws + OFS_PTSS);
    int*    idx_s  = (int*)  (ws + OFS_IDXS);

    hipLaunchKernelGGL(prep_coeff_zero, dim3(64), dim3(256), 0, stream,
                       coeff, coeff2, counts);   // counts+cursor contiguous: zeroes both
    hipLaunchKernelGGL(bin_count, dim3(64), dim3(256), 0, stream, points_in, counts);
    hipLaunchKernelGGL(bin_scan, dim3(1), dim3(1024), 0, stream, counts, strts);
    hipLaunchKernelGGL(bin_scatter, dim3(64), dim3(256), 0, stream,
                       points_in, strts, cursor, pts_s, idx_s);

    const int blocks1 = (BB * MM) / QPB;                         // 4096
    hipLaunchKernelGGL(conv_knn, dim3(blocks1), dim3(128), 0, stream,
                       pts_s, idx_s, strts, points_in, points_out,
                       out_uiv, out_idx);

    const int blocks2 = (BB * MM) / QPB2;                        // 2048
    hipLaunchKernelGGL(conv_apply, dim3(blocks2), dim3(256), 0, stream,
                       values_in, out_uiv, out_idx, coeff2, bias, out_val);
}

// Round 19
// 67.802 us; speedup vs baseline: 2.5059x; 1.0211x over previous
//
#include <hip/hip_runtime.h>
#include <cstdint>
#include <cstddef>

// Problem constants (from reference)
constexpr int BB   = 2;
constexpr int NN   = 8192;
constexpr int MM   = 8192;
constexpr int CIN  = 32;
constexpr int COUT = 32;
constexpr int EE   = 16;
constexpr int KK   = 32;
constexpr int GRID = 32;              // binning grid (h = 1/32, ~8 pts/cell)
constexpr int NCELL = GRID * GRID;

#define QPB 4            // K1: queries per 128-thread block
#define QPB2 8           // K2: queries per 256-thread block
#define CAP 128
#define KEY_BYTES 1040   // 128 u64 + 16B skew
#define VROW 36          // K2: padded value-row stride in floats (144B)
#define VQS  1156        // K2: per-query VL stride (32*36 + 4: bank-phase skew 4q)
#define ECH 4            // K2: e-chunk size for coeff LDS staging

// Fixed-radius fast path: lambda = pi*R0^2*N ~ 48 expected candidates.
// (P(Poisson(48) <= 31) ~ 0.9% slow-path; exactness gates unchanged.)
#define R0_FAST 0.0432f

// Workspace layout (bytes)
constexpr size_t OFS_COEFFT = 0;        // coeff2[E][CIN][COUT]: 16384 f = 65536 B
constexpr size_t OFS_COUNTS = 65536;    // 2*1024 i = 8192 B
constexpr size_t OFS_CURSOR = 73728;    // 2*1024 i = 8192 B
constexpr size_t OFS_STARTS = 81920;    // 2*1025 i = 8200 B (pad to 8704)
constexpr size_t OFS_PTSS   = 90624;    // 2*8192 float2 = 131072 B
constexpr size_t OFS_IDXS   = 221696;   // 2*8192 i = 65536 B  (total 287232 B)

// ---- fused: zero counters/cursors + coeff [CIN][COUT][E] -> coeff2 [E][CIN][COUT]
__global__ __launch_bounds__(256) void prep_coeff_zero(const float* __restrict__ coeff,
                                                       float* __restrict__ coeff2,
                                                       int* __restrict__ cz) {
    int tid = blockIdx.x * 256 + threadIdx.x;
    if (tid < 2 * 2 * NCELL) cz[tid] = 0;             // counts + cursor
    if (tid >= EE * CIN * COUT) return;
    int o = tid & 31;
    int i = (tid >> 5) & 31;
    int e = tid >> 10;
    coeff2[tid] = coeff[(i * COUT + o) * EE + e];
}

// ---- binning: count, scan, scatter ----------------------------------------------
__device__ __forceinline__ int cell_of(float2 p) {
    int cx = min(GRID - 1, max(0, (int)(p.x * (float)GRID)));
    int cy = min(GRID - 1, max(0, (int)(p.y * (float)GRID)));
    return cy * GRID + cx;
}

__global__ __launch_bounds__(256) void bin_count(const float* __restrict__ pts,
                                                 int* __restrict__ counts) {
    int t = blockIdx.x * 256 + threadIdx.x;
    int b = t >> 13, i = t & (NN - 1);
    float2 p = ((const float2*)pts)[(size_t)b * NN + i];
    atomicAdd(&counts[b * NCELL + cell_of(p)], 1);
}

// 2-barrier hierarchical scan: wave shfl-scan -> wave-sum scan -> offset add.
// One block per batch (2 blocks total, parallel).
__global__ __launch_bounds__(1024) void bin_scan(const int* __restrict__ counts,
                                                 int* __restrict__ starts) {
    __shared__ int wsum[16];
    const int b    = blockIdx.x;
    const int t    = threadIdx.x;
    const int lane = t & 63, wv = t >> 6;           // 16 waves
    int s = counts[b * NCELL + t];
#pragma unroll
    for (int off = 1; off < 64; off <<= 1) {
        const int v = __shfl_up(s, off, 64);
        if (lane >= off) s += v;
    }
    if (lane == 63) wsum[wv] = s;
    __syncthreads();
    if (wv == 0) {
        int ws = (lane < 16) ? wsum[lane] : 0;
#pragma unroll
        for (int off = 1; off < 16; off <<= 1) {
            const int v = __shfl_up(ws, off, 64);
            if (lane >= off) ws += v;
        }
        if (lane < 16) wsum[lane] = ws;
    }
    __syncthreads();
    const int woff = (wv > 0) ? wsum[wv - 1] : 0;
    starts[b * (NCELL + 1) + t + 1] = s + woff;
    if (t == 0) starts[b * (NCELL + 1)] = 0;
}

__global__ __launch_bounds__(256) void bin_scatter(const float* __restrict__ pts,
                                                   const int* __restrict__ starts,
                                                   int* __restrict__ cursor,
                                                   float2* __restrict__ pts_s,
                                                   int* __restrict__ idx_s) {
    int t = blockIdx.x * 256 + threadIdx.x;
    int b = t >> 13, i = t & (NN - 1);
    float2 p = ((const float2*)pts)[(size_t)b * NN + i];
    int cell = cell_of(p);
    int pos = starts[b * (NCELL + 1) + cell] + atomicAdd(&cursor[b * NCELL + cell], 1);
    pts_s[(size_t)b * NN + pos] = p;     // intra-cell order nondeterministic; final
    idx_s[(size_t)b * NN + pos] = i;     // rank by (d, orig idx) makes output exact.
}

// ==== K1: KNN selection only. One half-wave (32 lanes) per query. ================
__global__ __launch_bounds__(128) void conv_knn(
    const float2* __restrict__ pts_s, const int* __restrict__ idx_s,
    const int* __restrict__ starts,
    const float* __restrict__ points_in,
    const float* __restrict__ points_out,
    float* __restrict__ out_uiv, float* __restrict__ out_idx)
{
    __shared__ alignas(16) unsigned char SMEM[QPB][KEY_BYTES];

    const int tid   = threadIdx.x;
    const int sl    = tid & 31;
    const int qslot = tid >> 5;            // 0..3
    const int half  = qslot & 1;
    const int wid   = blockIdx.x * QPB + qslot;
    const int b     = wid >> 13;
    const int m     = wid & (MM - 1);

    unsigned long long* KEYq = (unsigned long long*)&SMEM[qslot][0];

    const float2* PS = pts_s + (size_t)b * NN;
    const int*    IS = idx_s + (size_t)b * NN;
    const int*    ST = starts + b * (NCELL + 1);
    const float2* P  = ((const float2*)points_in) + (size_t)b * NN;
    const float2  q  = ((const float2*)points_out)[(size_t)b * MM + m];

    const float INF = __builtin_inff();
    const float h = 1.0f / (float)GRID;
    const unsigned lmlt32 = (1u << sl) - 1u;

    float bd;   // sorted exact distance (sub-lane sl holds entry #sl)
    int   bi;   // sorted original index
    bool  ok = false;

    // ---------------- FAST PATH: fixed analytic radius, single scan ---------------
    {
        float tau = R0_FAST;
        {
            const float bx = fminf(q.x, 1.0f - q.x);
            const float by = fminf(q.y, 1.0f - q.y);
#pragma unroll
            for (int it = 0; it < 3; ++it) {
                const float wx = 0.5f + 0.5f * fminf(bx / tau, 1.0f);
                const float wy = 0.5f + 0.5f * fminf(by / tau, 1.0f);
                tau = R0_FAST * __frsqrt_rn(wx * wy);
            }
        }
        const float tau2  = tau * tau;
        const float tau2a = tau2 * (1.0f + 2e-6f);

        const int xlo = (int)fmaxf((q.x - tau) * (float)GRID, 0.0f);
        const int xhi = (int)fminf((q.x + tau) * (float)GRID, (float)(GRID - 1));
        const int ylo = (int)fmaxf((q.y - tau) * (float)GRID, 0.0f);
        const int yhi = (int)fminf((q.y + tau) * (float)GRID, (float)(GRID - 1));
        const int nrows = yhi - ylo + 1;

        int sv = 0, ev = 0;
        if (sl < nrows) {
            sv = ST[(ylo + sl) * GRID + xlo];
            ev = ST[(ylo + sl) * GRID + xhi + 1];
        }

        int base = 0, nin = 0;
        for (int r = 0; r < nrows; ++r) {
            const int s = __shfl(sv, r, 32), e = __shfl(ev, r, 32);
            for (int j0 = s; j0 < e; j0 += 32) {
                const int j = j0 + sl;
                const bool valid = (j < e);
                float2 p = make_float2(2.0f, 2.0f);
                if (valid) p = PS[j];
                const float dx = q.x - p.x, dy = q.y - p.y;
                const float d2 = __builtin_fmaf(dy, dy, __fmul_rn(dx, dx));
                const bool adm = valid && (d2 <= tau2a);
                const unsigned bmA = (unsigned)(__ballot(adm) >> (half << 5));
                const unsigned bmS = (unsigned)(__ballot(valid && (d2 <= tau2)) >> (half << 5));
                nin += __popc(bmS);
                if (bmA) {
                    const float ex = __fsqrt_rn(__fadd_rn(__fmul_rn(dx, dx),
                                                          __fmul_rn(dy, dy)));
                    const int pos = base + __popc(bmA & lmlt32);
                    if (adm && pos < CAP)
                        KEYq[pos] =
                            ((unsigned long long)__float_as_uint(ex) << 32) | (unsigned)IS[j];
                    base += __popc(bmA);
                }
            }
        }

        ok = (nin >= 32) && (base <= CAP);
        if (ok) {
            unsigned long long k0 = (sl      < base) ? KEYq[sl]      : ~0ull;
            unsigned long long k1 = (sl + 32 < base) ? KEYq[sl + 32] : ~0ull;
            int r0 = 0, r1 = 0;
            if (!__any(base > 64)) {
                for (int t = 0; t < base; ++t) {
                    const unsigned long long kt = KEYq[t];
                    r0 += (kt < k0) ? 1 : 0;
                    r1 += (kt < k1) ? 1 : 0;
                }
            } else {
                unsigned long long k2 = (sl + 64 < base) ? KEYq[sl + 64] : ~0ull;
                unsigned long long k3 = (sl + 96 < base) ? KEYq[sl + 96] : ~0ull;
                int r2 = 0, r3 = 0;
                for (int t = 0; t < base; ++t) {
                    const unsigned long long kt = KEYq[t];
                    r0 += (kt < k0) ? 1 : 0;
                    r1 += (kt < k1) ? 1 : 0;
                    r2 += (kt < k2) ? 1 : 0;
                    r3 += (kt < k3) ? 1 : 0;
                }
                if (sl + 64 < base && r2 < 32) KEYq[r2] = k2;
                if (sl + 96 < base && r3 < 32) KEYq[r3] = k3;
            }
            if (sl      < base && r0 < 32) KEYq[r0] = k0;
            if (sl + 32 < base && r1 < 32) KEYq[r1] = k1;
            const unsigned long long kf = KEYq[sl];
            bd = __uint_as_float((unsigned)(kf >> 32));
            bi = (int)(unsigned)(kf & 0xffffffffull);

            const float tau32 = __shfl(bd, 31, 32);
            float g = INF;
            if (xlo > 0)        g = fminf(g, q.x - (float)xlo * h);
            if (xhi < GRID - 1) g = fminf(g, (float)(xhi + 1) * h - q.x);
            if (ylo > 0)        g = fminf(g, q.y - (float)ylo * h);
            if (yhi < GRID - 1) g = fminf(g, (float)(yhi + 1) * h - q.y);
            ok = (tau32 < g * (1.0f - 4e-6f));
        }
    }

    // ---------------- SLOW PATH (rare): adaptive, exact ---------------------------
    if (!ok) {
        const int cx = min(GRID - 1, max(0, (int)(q.x * (float)GRID)));
        const int cy = min(GRID - 1, max(0, (int)(q.y * (float)GRID)));
        int L = 2;
        for (;;) {
            const int xlo = max(cx - L, 0), xhi = min(cx + L, GRID - 1);
            const int ylo = max(cy - L, 0), yhi = min(cy + L, GRID - 1);
            const int nrows = yhi - ylo + 1;

            int sv = 0, ev = 0;
            if (sl < nrows) {
                sv = ST[(ylo + sl) * GRID + xlo];
                ev = ST[(ylo + sl) * GRID + xhi + 1];
            }

            float mn1 = INF, mn2 = INF;
            for (int r = 0; r < nrows; ++r) {
                const int s = __shfl(sv, r, 32), e = __shfl(ev, r, 32);
                for (int j = s + sl; j < e; j += 32) {
                    const float2 p = PS[j];
                    const float dx = q.x - p.x, dy = q.y - p.y;
                    const float d2 = __builtin_fmaf(dy, dy, __fmul_rn(dx, dx));
                    const float big = fmaxf(mn1, d2);
                    mn1 = fminf(mn1, d2);
                    mn2 = fminf(mn2, big);
                }
            }

            {
                float v = mn2;
#pragma unroll
                for (int k = 2; k <= 32; k <<= 1) {
#pragma unroll
                    for (int j = k >> 1; j > 0; j >>= 1) {
                        const float o = __shfl_xor(v, j, 32);
                        const bool up = ((sl & k) == 0), lower = ((sl & j) == 0);
                        const float mnv = fminf(v, o), mxv = fmaxf(v, o);
                        v = (lower == up) ? mnv : mxv;
                    }
                }
                mn2 = __shfl(v, 15, 32);
            }
            const float tau2b = mn2 * (1.0f + 4e-6f);

            int base = 0;
            for (int r = 0; r < nrows; ++r) {
                const int s = __shfl(sv, r, 32), e = __shfl(ev, r, 32);
                for (int j0 = s; j0 < e; j0 += 32) {
                    const int j = j0 + sl;
                    const bool valid = (j < e);
                    float2 p = make_float2(0.f, 0.f);
                    if (valid) p = PS[j];
                    const float dx = q.x - p.x, dy = q.y - p.y;
                    const float d2 = __builtin_fmaf(dy, dy, __fmul_rn(dx, dx));
                    const bool pred = valid && (d2 <= tau2b);
                    const unsigned bm = (unsigned)(__ballot(pred) >> (half << 5));
                    if (bm) {
                        const float ex = __fsqrt_rn(__fadd_rn(__fmul_rn(dx, dx),
                                                              __fmul_rn(dy, dy)));
                        const int pos = base + __popc(bm & lmlt32);
                        if (pred && pos < CAP)
                            KEYq[pos] =
                                ((unsigned long long)__float_as_uint(ex) << 32) | (unsigned)IS[j];
                        base += __popc(bm);
                    }
                }
            }

            if (base <= CAP) {
                unsigned long long k0 = (sl      < base) ? KEYq[sl]      : ~0ull;
                unsigned long long k1 = (sl + 32 < base) ? KEYq[sl + 32] : ~0ull;
                int r0 = 0, r1 = 0;
                if (!__any(base > 64)) {
                    for (int t = 0; t < base; ++t) {
                        const unsigned long long kt = KEYq[t];
                        r0 += (kt < k0) ? 1 : 0;
                        r1 += (kt < k1) ? 1 : 0;
                    }
                } else {
                    unsigned long long k2 = (sl + 64 < base) ? KEYq[sl + 64] : ~0ull;
                    unsigned long long k3 = (sl + 96 < base) ? KEYq[sl + 96] : ~0ull;
                    int r2 = 0, r3 = 0;
                    for (int t = 0; t < base; ++t) {
                        const unsigned long long kt = KEYq[t];
                        r0 += (kt < k0) ? 1 : 0;
                        r1 += (kt < k1) ? 1 : 0;
                        r2 += (kt < k2) ? 1 : 0;
                        r3 += (kt < k3) ? 1 : 0;
                    }
                    if (sl + 64 < base && r2 < 32) KEYq[r2] = k2;
                    if (sl + 96 < base && r3 < 32) KEYq[r3] = k3;
                }
                if (sl      < base && r0 < 32) KEYq[r0] = k0;
                if (sl + 32 < base && r1 < 32) KEYq[r1] = k1;
                if (base < 32 && sl >= base) KEYq[sl] = ~0ull;   // pad -> NaN -> expand
                const unsigned long long kf = KEYq[sl];
                bd = __uint_as_float((unsigned)(kf >> 32));
                bi = (int)(unsigned)(kf & 0xffffffffull);
            } else {
                float fd = INF; int fi = 0x7FFFFFFF;
                for (int r = 0; r < nrows; ++r) {
                    const int s = __shfl(sv, r, 32), e = __shfl(ev, r, 32);
                    for (int j0 = s; j0 < e; j0 += 32) {
                        const int j = j0 + sl;
                        const bool valid = (j < e);
                        float2 p = make_float2(0.f, 0.f);
                        int vi0 = 0x7FFFFFFF;
                        if (valid) { p = PS[j]; vi0 = IS[j]; }
                        const float dx = q.x - p.x, dy = q.y - p.y;
                        const float d2 = __builtin_fmaf(dy, dy, __fmul_rn(dx, dx));
                        unsigned cm = (unsigned)(__ballot(valid && (d2 <= tau2b)) >> (half << 5));
                        const float ex = __fsqrt_rn(__fadd_rn(__fmul_rn(dx, dx),
                                                              __fmul_rn(dy, dy)));
                        while (cm) {
                            const int l = __builtin_ctz(cm); cm &= cm - 1;
                            const float v  = __shfl(ex, l, 32);
                            const int   vi = __shfl(vi0, l, 32);
                            const bool cl = (fd < v) || (fd == v && fi < vi);
                            const int pos = __popc((unsigned)(__ballot(cl) >> (half << 5)));
                            const float sd = __shfl_up(fd, 1, 32);
                            const int   si = __shfl_up(fi, 1, 32);
                            fd = (sl < pos) ? fd : ((sl == pos) ? v  : sd);
                            fi = (sl < pos) ? fi : ((sl == pos) ? vi : si);
                        }
                    }
                }
                bd = fd; bi = fi;
            }

            const float tau = __shfl(bd, 31, 32);
            float g = INF;
            if (xlo > 0)        g = fminf(g, q.x - (float)xlo * h);
            if (xhi < GRID - 1) g = fminf(g, (float)(xhi + 1) * h - q.x);
            if (ylo > 0)        g = fminf(g, q.y - (float)ylo * h);
            if (yhi < GRID - 1) g = fminf(g, (float)(yhi + 1) * h - q.y);
            if (tau < g * (1.0f - 4e-6f)) break;
            L += 2;
            if (L > GRID - 1) L = GRID - 1;
        }
    }

    // ---- outputs 0 and 1: uiv_k and idx (as float) ----
    {
        const float2 pk = P[bi];
        float2 u;
        u.x = q.x - pk.x;
        u.y = q.y - pk.y;
        ((float2*)out_uiv)[(size_t)wid * KK + sl] = u;
        out_idx[(size_t)wid * KK + sl] = (float)bi;
    }
}

// ==== K2: gather + einsum + reduce. 8 queries / 256-thread block. ================
__global__ __launch_bounds__(256) void conv_apply(
    const float* __restrict__ values_in,
    const float* __restrict__ out_uiv, const float* __restrict__ out_idx,
    const float* __restrict__ coeff2, const float* __restrict__ bias,
    float* __restrict__ out_val)
{
    __shared__ alignas(16) float VL[QPB2][VQS];          // 36992 B
    __shared__ alignas(16) float CL[ECH][CIN][COUT];     // 16384 B (53376 total)

    const int tid   = threadIdx.x;
    const int sl    = tid & 31;
    const int qslot = tid >> 5;            // 0..7
    const int wid   = blockIdx.x * QPB2 + qslot;
    const int b     = wid >> 13;

    float* VLq = &VL[qslot][0];

    // neighbor #sl of this query: u stored exactly in K1 -> bd bit-exact
    const float2 u = ((const float2*)out_uiv)[(size_t)wid * KK + sl];
    const float bd = __fsqrt_rn(__fadd_rn(__fmul_rn(u.x, u.x), __fmul_rn(u.y, u.y)));
    const int   bi = (int)out_idx[(size_t)wid * KK + sl];

    // ---- Phase A: stage my neighbor's 32-float value row into LDS ----
    {
        const float4* src = (const float4*)(values_in + ((size_t)b * NN + bi) * CIN);
        const float4 r0 = src[0], r1 = src[1], r2 = src[2], r3 = src[3];
        const float4 r4 = src[4], r5 = src[5], r6 = src[6], r7 = src[7];
        float4* dst = (float4*)(VLq + sl * VROW);
        dst[0] = r0; dst[1] = r1; dst[2] = r2; dst[3] = r3;
        dst[4] = r4; dst[5] = r5; dst[6] = r6; dst[7] = r7;
    }

    // ---- Phase G: T[e][i] = sum_k exp(-256*(r_k - mu_e)^2) * v_k[i], v from LDS --
    {
        const int e2 = sl >> 2;                 // 0..7 -> e in {2*e2, 2*e2+1}
        const int iq = sl & 3;                  // i-block of 8
        const float mu0 = (float)(2 * e2)     * (1.0f / 15.0f);
        const float mu1 = (float)(2 * e2 + 1) * (1.0f / 15.0f);
        float4 A0a = make_float4(0.f, 0.f, 0.f, 0.f);
        float4 A0b = A0a, A1a = A0a, A1b = A0a;
#pragma unroll 8
        for (int k = 0; k < KK; ++k) {
            const float rk = __shfl(bd, k, 32);
            const float d0 = rk - mu0;
            const float d1 = rk - mu1;
            const float w0 = __expf(-256.0f * d0 * d0);
            const float w1 = __expf(-256.0f * d1 * d1);
            const float4* vr = (const float4*)(VLq + k * VROW + iq * 8);
            const float4 va = vr[0], vb = vr[1];
            A0a.x += w0 * va.x; A0a.y += w0 * va.y; A0a.z += w0 * va.z; A0a.w += w0 * va.w;
            A0b.x += w0 * vb.x; A0b.y += w0 * vb.y; A0b.z += w0 * vb.z; A0b.w += w0 * vb.w;
            A1a.x += w1 * va.x; A1a.y += w1 * va.y; A1a.z += w1 * va.z; A1a.w += w1 * va.w;
            A1b.x += w1 * vb.x; A1b.y += w1 * vb.y; A1b.z += w1 * vb.z; A1b.w += w1 * vb.w;
        }
        // overlay T (16 x VROW floats) onto the VL region -- all G reads precede
        // these stores in program order within this same half-wave.
        float4* t0 = (float4*)(VLq + (2 * e2)     * VROW + iq * 8);
        float4* t1 = (float4*)(VLq + (2 * e2 + 1) * VROW + iq * 8);
        t0[0] = A0a; t0[1] = A0b;
        t1[0] = A1a; t1[1] = A1b;
    }

    // ---- Phase R: block-cooperative out = C . T over all 8 queries ----
    {
        const int w  = tid >> 6;          // wave: i-slice [8w, 8w+8)
        const int rq = (tid >> 3) & 7;    // query
        const int ro = tid & 7;           // o-chunk (4 outputs)
        float4 s4 = make_float4(0.f, 0.f, 0.f, 0.f);
        const float* Tq = &VL[rq][0];
#pragma unroll
        for (int ec = 0; ec < EE / ECH; ++ec) {
            __syncthreads();               // G complete (ec=0) / prior chunk consumed
            {
                const float4* src = (const float4*)(coeff2 + ec * (ECH * CIN * COUT));
                float4* dst = (float4*)&CL[0][0][0];
#pragma unroll
                for (int j = 0; j < (ECH * CIN * COUT) / (4 * 256); ++j) {
                    const int idx = tid + j * 256;
                    dst[idx] = src[idx];
                }
            }
            __syncthreads();
#pragma unroll
            for (int el = 0; el < ECH; ++el) {
                const int e = ec * ECH + el;
                const float* Trow = Tq + e * VROW + 8 * w;
                const float4 ta = *(const float4*)(Trow);        // 16B-aligned
                const float4 tb = *(const float4*)(Trow + 4);
                const float* Crow = &CL[el][8 * w][0] + ro * 4;
#pragma unroll
                for (int ir = 0; ir < 4; ++ir) {
                    const float t = (ir == 0) ? ta.x : (ir == 1) ? ta.y
                                  : (ir == 2) ? ta.z : ta.w;
                    const float4 c = *(const float4*)(Crow + ir * COUT);
                    s4.x += t * c.x; s4.y += t * c.y;
                    s4.z += t * c.z; s4.w += t * c.w;
                }
#pragma unroll
                for (int ir = 0; ir < 4; ++ir) {
                    const float t = (ir == 0) ? tb.x : (ir == 1) ? tb.y
                                  : (ir == 2) ? tb.z : tb.w;
                    const float4 c = *(const float4*)(Crow + (4 + ir) * COUT);
                    s4.x += t * c.x; s4.y += t * c.y;
                    s4.z += t * c.z; s4.w += t * c.w;
                }
            }
        }
        // cross-wave combine via PART overlay on CL
        __syncthreads();
        float4* PART = (float4*)&CL[0][0][0];    // [w][rq][ro] = tid order, 4KB
        PART[tid] = s4;
        __syncthreads();
        if (w == 0) {
            const float4 p0 = PART[tid];
            const float4 p1 = PART[tid + 64];
            const float4 p2 = PART[tid + 128];
            const float4 p3 = PART[tid + 192];
            const float4 bv = *(const float4*)(bias + ro * 4);
            float4 ov;
            ov.x = (p0.x + p1.x + p2.x + p3.x) * (1.0f / 32.0f) + bv.x;
            ov.y = (p0.y + p1.y + p2.y + p3.y) * (1.0f / 32.0f) + bv.y;
            ov.z = (p0.z + p1.z + p2.z + p3.z) * (1.0f / 32.0f) + bv.z;
            ov.w = (p0.w + p1.w + p2.w + p3.w) * (1.0f / 32.0f) + bv.w;
            const int qw = blockIdx.x * QPB2 + rq;
            *(float4*)(out_val + (size_t)qw * COUT + ro * 4) = ov;
        }
    }
}

extern "C" void kernel_launch(void* const* d_in, const int* in_sizes, int n_in,
                              void* d_out, int out_size, void* d_ws, size_t ws_size,
                              hipStream_t stream) {
    const float* points_in  = (const float*)d_in[0];
    const float* values_in  = (const float*)d_in[1];
    const float* points_out = (const float*)d_in[2];
    const float* coeff      = (const float*)d_in[3];
    const float* bias       = (const float*)d_in[4];

    float* out     = (float*)d_out;
    float* out_uiv = out;                                        // B*M*K*2
    float* out_idx = out + (size_t)BB * MM * KK * 2;             // B*M*K
    float* out_val = out_idx + (size_t)BB * MM * KK;             // B*M*COUT

    char* ws = (char*)d_ws;
    float*  coeff2 = (float*)(ws + OFS_COEFFT);
    int*    counts = (int*)  (ws + OFS_COUNTS);
    int*    cursor = (int*)  (ws + OFS_CURSOR);
    int*    strts  = (int*)  (ws + OFS_STARTS);
    float2* pts_s  = (float2*)(ws + OFS_PTSS);
    int*    idx_s  = (int*)  (ws + OFS_IDXS);

    hipLaunchKernelGGL(prep_coeff_zero, dim3(64), dim3(256), 0, stream,
                       coeff, coeff2, counts);   // counts+cursor contiguous: zeroes both
    hipLaunchKernelGGL(bin_count, dim3(64), dim3(256), 0, stream, points_in, counts);
    hipLaunchKernelGGL(bin_scan, dim3(BB), dim3(1024), 0, stream, counts, strts);
    hipLaunchKernelGGL(bin_scatter, dim3(64), dim3(256), 0, stream,
                       points_in, strts, cursor, pts_s, idx_s);

    const int blocks1 = (BB * MM) / QPB;                         // 4096
    hipLaunchKernelGGL(conv_knn, dim3(blocks1), dim3(128), 0, stream,
                       pts_s, idx_s, strts, points_in, points_out,
                       out_uiv, out_idx);

    const int blocks2 = (BB * MM) / QPB2;                        // 2048
    hipLaunchKernelGGL(conv_apply, dim3(blocks2), dim3(256), 0, stream,
                       values_in, out_uiv, out_idx, coeff2, bias, out_val);
}

// Round 20
// 67.784 us; speedup vs baseline: 2.5065x; 1.0003x over previous
//
#include <hip/hip_runtime.h>
#include <cstdint>
#include <cstddef>

// Problem constants (from reference)
constexpr int BB   = 2;
constexpr int NN   = 8192;
constexpr int MM   = 8192;
constexpr int CIN  = 32;
constexpr int COUT = 32;
constexpr int EE   = 16;
constexpr int KK   = 32;
constexpr int GRID = 32;              // binning grid (h = 1/32, ~8 pts/cell)
constexpr int NCELL = GRID * GRID;

#define QPB2 8           // queries per 256-thread block (32 lanes/query)
#define CAP 128
#define KEY_BYTES 1040   // 128 u64 + 16B skew (per query)
#define VROW 36          // padded value-row stride in floats (144B)
#define VQS  1156        // per-query VL stride (32*36 + 4: bank-phase skew 4q)
#define ECH 4            // e-chunk size for coeff LDS staging

// Fixed-radius fast path: lambda = pi*R0^2*N ~ 48 expected candidates.
#define R0_FAST 0.0432f

// Workspace layout (bytes)
constexpr size_t OFS_COEFFT = 0;        // coeff2[E][CIN][COUT]: 16384 f = 65536 B
constexpr size_t OFS_COUNTS = 65536;    // 2*1024 i = 8192 B
constexpr size_t OFS_CURSOR = 73728;    // 2*1024 i = 8192 B
constexpr size_t OFS_STARTS = 81920;    // 2*1025 i = 8200 B (pad to 8704)
constexpr size_t OFS_PTSS   = 90624;    // 2*8192 float2 = 131072 B
constexpr size_t OFS_IDXS   = 221696;   // 2*8192 i = 65536 B  (total 287232 B)

// ---- fused: zero counters/cursors + coeff [CIN][COUT][E] -> coeff2 [E][CIN][COUT]
__global__ __launch_bounds__(256) void prep_coeff_zero(const float* __restrict__ coeff,
                                                       float* __restrict__ coeff2,
                                                       int* __restrict__ cz) {
    int tid = blockIdx.x * 256 + threadIdx.x;
    if (tid < 2 * 2 * NCELL) cz[tid] = 0;             // counts + cursor
    if (tid >= EE * CIN * COUT) return;
    int o = tid & 31;
    int i = (tid >> 5) & 31;
    int e = tid >> 10;
    coeff2[tid] = coeff[(i * COUT + o) * EE + e];
}

// ---- binning: count, scan, scatter ----------------------------------------------
__device__ __forceinline__ int cell_of(float2 p) {
    int cx = min(GRID - 1, max(0, (int)(p.x * (float)GRID)));
    int cy = min(GRID - 1, max(0, (int)(p.y * (float)GRID)));
    return cy * GRID + cx;
}

__global__ __launch_bounds__(256) void bin_count(const float* __restrict__ pts,
                                                 int* __restrict__ counts) {
    int t = blockIdx.x * 256 + threadIdx.x;
    int b = t >> 13, i = t & (NN - 1);
    float2 p = ((const float2*)pts)[(size_t)b * NN + i];
    atomicAdd(&counts[b * NCELL + cell_of(p)], 1);
}

// 2-barrier hierarchical scan; one block per batch.
__global__ __launch_bounds__(1024) void bin_scan(const int* __restrict__ counts,
                                                 int* __restrict__ starts) {
    __shared__ int wsum[16];
    const int b    = blockIdx.x;
    const int t    = threadIdx.x;
    const int lane = t & 63, wv = t >> 6;           // 16 waves
    int s = counts[b * NCELL + t];
#pragma unroll
    for (int off = 1; off < 64; off <<= 1) {
        const int v = __shfl_up(s, off, 64);
        if (lane >= off) s += v;
    }
    if (lane == 63) wsum[wv] = s;
    __syncthreads();
    if (wv == 0) {
        int ws = (lane < 16) ? wsum[lane] : 0;
#pragma unroll
        for (int off = 1; off < 16; off <<= 1) {
            const int v = __shfl_up(ws, off, 64);
            if (lane >= off) ws += v;
        }
        if (lane < 16) wsum[lane] = ws;
    }
    __syncthreads();
    const int woff = (wv > 0) ? wsum[wv - 1] : 0;
    starts[b * (NCELL + 1) + t + 1] = s + woff;
    if (t == 0) starts[b * (NCELL + 1)] = 0;
}

__global__ __launch_bounds__(256) void bin_scatter(const float* __restrict__ pts,
                                                   const int* __restrict__ starts,
                                                   int* __restrict__ cursor,
                                                   float2* __restrict__ pts_s,
                                                   int* __restrict__ idx_s) {
    int t = blockIdx.x * 256 + threadIdx.x;
    int b = t >> 13, i = t & (NN - 1);
    float2 p = ((const float2*)pts)[(size_t)b * NN + i];
    int cell = cell_of(p);
    int pos = starts[b * (NCELL + 1) + cell] + atomicAdd(&cursor[b * NCELL + cell], 1);
    pts_s[(size_t)b * NN + pos] = p;     // intra-cell order nondeterministic; final
    idx_s[(size_t)b * NN + pos] = i;     // rank by (d, orig idx) makes output exact.
}

// ==== FUSED kernel: KNN select + gather + einsum + reduce. 8 queries/block. ======
// KNN: one half-wave (32 lanes) per query; KEY overlays the CL region (Phase R's
// first barrier orders all KEY use before CL staging). bd/bi stay in registers.
__global__ __launch_bounds__(256) void conv_fused(
    const float2* __restrict__ pts_s, const int* __restrict__ idx_s,
    const int* __restrict__ starts,
    const float* __restrict__ points_in, const float* __restrict__ values_in,
    const float* __restrict__ points_out,
    const float* __restrict__ coeff2, const float* __restrict__ bias,
    float* __restrict__ out_uiv, float* __restrict__ out_idx,
    float* __restrict__ out_val)
{
    __shared__ alignas(16) float VL[QPB2][VQS];          // 36992 B
    __shared__ alignas(16) unsigned char CLRAW[ECH * CIN * COUT * 4]; // 16384 B

    const int tid   = threadIdx.x;
    const int sl    = tid & 31;
    const int qslot = tid >> 5;            // 0..7
    const int half  = qslot & 1;
    const int wid   = blockIdx.x * QPB2 + qslot;
    const int b     = wid >> 13;
    const int m     = wid & (MM - 1);

    unsigned long long* KEYq = (unsigned long long*)(CLRAW + qslot * KEY_BYTES);
    float* CLf  = (float*)CLRAW;
    float* VLq  = &VL[qslot][0];

    const float2* PS = pts_s + (size_t)b * NN;
    const int*    IS = idx_s + (size_t)b * NN;
    const int*    ST = starts + b * (NCELL + 1);
    const float2* P  = ((const float2*)points_in) + (size_t)b * NN;
    const float2  q  = ((const float2*)points_out)[(size_t)b * MM + m];

    const float INF = __builtin_inff();
    const float h = 1.0f / (float)GRID;
    const unsigned lmlt32 = (1u << sl) - 1u;

    float bd;   // sorted exact distance (sub-lane sl holds entry #sl)
    int   bi;   // sorted original index
    bool  ok = false;

    // ---------------- FAST PATH: fixed analytic radius, single scan ---------------
    {
        float tau = R0_FAST;
        {
            const float bx = fminf(q.x, 1.0f - q.x);
            const float by = fminf(q.y, 1.0f - q.y);
#pragma unroll
            for (int it = 0; it < 3; ++it) {
                const float wx = 0.5f + 0.5f * fminf(bx / tau, 1.0f);
                const float wy = 0.5f + 0.5f * fminf(by / tau, 1.0f);
                tau = R0_FAST * __frsqrt_rn(wx * wy);
            }
        }
        const float tau2  = tau * tau;
        const float tau2a = tau2 * (1.0f + 2e-6f);

        const int xlo = (int)fmaxf((q.x - tau) * (float)GRID, 0.0f);
        const int xhi = (int)fminf((q.x + tau) * (float)GRID, (float)(GRID - 1));
        const int ylo = (int)fmaxf((q.y - tau) * (float)GRID, 0.0f);
        const int yhi = (int)fminf((q.y + tau) * (float)GRID, (float)(GRID - 1));
        const int nrows = yhi - ylo + 1;

        int sv = 0, ev = 0;
        if (sl < nrows) {
            sv = ST[(ylo + sl) * GRID + xlo];
            ev = ST[(ylo + sl) * GRID + xhi + 1];
        }

        int base = 0, nin = 0;
        for (int r = 0; r < nrows; ++r) {
            const int s = __shfl(sv, r, 32), e = __shfl(ev, r, 32);
            for (int j0 = s; j0 < e; j0 += 32) {
                const int j = j0 + sl;
                const bool valid = (j < e);
                float2 p = make_float2(2.0f, 2.0f);
                if (valid) p = PS[j];
                const float dx = q.x - p.x, dy = q.y - p.y;
                const float d2 = __builtin_fmaf(dy, dy, __fmul_rn(dx, dx));
                const bool adm = valid && (d2 <= tau2a);
                const unsigned bmA = (unsigned)(__ballot(adm) >> (half << 5));
                const unsigned bmS = (unsigned)(__ballot(valid && (d2 <= tau2)) >> (half << 5));
                nin += __popc(bmS);
                if (bmA) {
                    const float ex = __fsqrt_rn(__fadd_rn(__fmul_rn(dx, dx),
                                                          __fmul_rn(dy, dy)));
                    const int pos = base + __popc(bmA & lmlt32);
                    if (adm && pos < CAP)
                        KEYq[pos] =
                            ((unsigned long long)__float_as_uint(ex) << 32) | (unsigned)IS[j];
                    base += __popc(bmA);
                }
            }
        }

        ok = (nin >= 32) && (base <= CAP);
        if (ok) {
            unsigned long long k0 = (sl      < base) ? KEYq[sl]      : ~0ull;
            unsigned long long k1 = (sl + 32 < base) ? KEYq[sl + 32] : ~0ull;
            int r0 = 0, r1 = 0;
            if (!__any(base > 64)) {
                for (int t = 0; t < base; ++t) {
                    const unsigned long long kt = KEYq[t];
                    r0 += (kt < k0) ? 1 : 0;
                    r1 += (kt < k1) ? 1 : 0;
                }
            } else {
                unsigned long long k2 = (sl + 64 < base) ? KEYq[sl + 64] : ~0ull;
                unsigned long long k3 = (sl + 96 < base) ? KEYq[sl + 96] : ~0ull;
                int r2 = 0, r3 = 0;
                for (int t = 0; t < base; ++t) {
                    const unsigned long long kt = KEYq[t];
                    r0 += (kt < k0) ? 1 : 0;
                    r1 += (kt < k1) ? 1 : 0;
                    r2 += (kt < k2) ? 1 : 0;
                    r3 += (kt < k3) ? 1 : 0;
                }
                if (sl + 64 < base && r2 < 32) KEYq[r2] = k2;
                if (sl + 96 < base && r3 < 32) KEYq[r3] = k3;
            }
            if (sl      < base && r0 < 32) KEYq[r0] = k0;
            if (sl + 32 < base && r1 < 32) KEYq[r1] = k1;
            const unsigned long long kf = KEYq[sl];
            bd = __uint_as_float((unsigned)(kf >> 32));
            bi = (int)(unsigned)(kf & 0xffffffffull);

            const float tau32 = __shfl(bd, 31, 32);
            float g = INF;
            if (xlo > 0)        g = fminf(g, q.x - (float)xlo * h);
            if (xhi < GRID - 1) g = fminf(g, (float)(xhi + 1) * h - q.x);
            if (ylo > 0)        g = fminf(g, q.y - (float)ylo * h);
            if (yhi < GRID - 1) g = fminf(g, (float)(yhi + 1) * h - q.y);
            ok = (tau32 < g * (1.0f - 4e-6f));
        }
    }

    // ---------------- SLOW PATH (rare): adaptive, exact ---------------------------
    if (!ok) {
        const int cx = min(GRID - 1, max(0, (int)(q.x * (float)GRID)));
        const int cy = min(GRID - 1, max(0, (int)(q.y * (float)GRID)));
        int L = 2;
        for (;;) {
            const int xlo = max(cx - L, 0), xhi = min(cx + L, GRID - 1);
            const int ylo = max(cy - L, 0), yhi = min(cy + L, GRID - 1);
            const int nrows = yhi - ylo + 1;

            int sv = 0, ev = 0;
            if (sl < nrows) {
                sv = ST[(ylo + sl) * GRID + xlo];
                ev = ST[(ylo + sl) * GRID + xhi + 1];
            }

            float mn1 = INF, mn2 = INF;
            for (int r = 0; r < nrows; ++r) {
                const int s = __shfl(sv, r, 32), e = __shfl(ev, r, 32);
                for (int j = s + sl; j < e; j += 32) {
                    const float2 p = PS[j];
                    const float dx = q.x - p.x, dy = q.y - p.y;
                    const float d2 = __builtin_fmaf(dy, dy, __fmul_rn(dx, dx));
                    const float big = fmaxf(mn1, d2);
                    mn1 = fminf(mn1, d2);
                    mn2 = fminf(mn2, big);
                }
            }

            {
                float v = mn2;
#pragma unroll
                for (int k = 2; k <= 32; k <<= 1) {
#pragma unroll
                    for (int j = k >> 1; j > 0; j >>= 1) {
                        const float o = __shfl_xor(v, j, 32);
                        const bool up = ((sl & k) == 0), lower = ((sl & j) == 0);
                        const float mnv = fminf(v, o), mxv = fmaxf(v, o);
                        v = (lower == up) ? mnv : mxv;
                    }
                }
                mn2 = __shfl(v, 15, 32);
            }
            const float tau2b = mn2 * (1.0f + 4e-6f);

            int base = 0;
            for (int r = 0; r < nrows; ++r) {
                const int s = __shfl(sv, r, 32), e = __shfl(ev, r, 32);
                for (int j0 = s; j0 < e; j0 += 32) {
                    const int j = j0 + sl;
                    const bool valid = (j < e);
                    float2 p = make_float2(0.f, 0.f);
                    if (valid) p = PS[j];
                    const float dx = q.x - p.x, dy = q.y - p.y;
                    const float d2 = __builtin_fmaf(dy, dy, __fmul_rn(dx, dx));
                    const bool pred = valid && (d2 <= tau2b);
                    const unsigned bm = (unsigned)(__ballot(pred) >> (half << 5));
                    if (bm) {
                        const float ex = __fsqrt_rn(__fadd_rn(__fmul_rn(dx, dx),
                                                              __fmul_rn(dy, dy)));
                        const int pos = base + __popc(bm & lmlt32);
                        if (pred && pos < CAP)
                            KEYq[pos] =
                                ((unsigned long long)__float_as_uint(ex) << 32) | (unsigned)IS[j];
                        base += __popc(bm);
                    }
                }
            }

            if (base <= CAP) {
                unsigned long long k0 = (sl      < base) ? KEYq[sl]      : ~0ull;
                unsigned long long k1 = (sl + 32 < base) ? KEYq[sl + 32] : ~0ull;
                int r0 = 0, r1 = 0;
                if (!__any(base > 64)) {
                    for (int t = 0; t < base; ++t) {
                        const unsigned long long kt = KEYq[t];
                        r0 += (kt < k0) ? 1 : 0;
                        r1 += (kt < k1) ? 1 : 0;
                    }
                } else {
                    unsigned long long k2 = (sl + 64 < base) ? KEYq[sl + 64] : ~0ull;
                    unsigned long long k3 = (sl + 96 < base) ? KEYq[sl + 96] : ~0ull;
                    int r2 = 0, r3 = 0;
                    for (int t = 0; t < base; ++t) {
                        const unsigned long long kt = KEYq[t];
                        r0 += (kt < k0) ? 1 : 0;
                        r1 += (kt < k1) ? 1 : 0;
                        r2 += (kt < k2) ? 1 : 0;
                        r3 += (kt < k3) ? 1 : 0;
                    }
                    if (sl + 64 < base && r2 < 32) KEYq[r2] = k2;
                    if (sl + 96 < base && r3 < 32) KEYq[r3] = k3;
                }
                if (sl      < base && r0 < 32) KEYq[r0] = k0;
                if (sl + 32 < base && r1 < 32) KEYq[r1] = k1;
                if (base < 32 && sl >= base) KEYq[sl] = ~0ull;   // pad -> NaN -> expand
                const unsigned long long kf = KEYq[sl];
                bd = __uint_as_float((unsigned)(kf >> 32));
                bi = (int)(unsigned)(kf & 0xffffffffull);
            } else {
                float fd = INF; int fi = 0x7FFFFFFF;
                for (int r = 0; r < nrows; ++r) {
                    const int s = __shfl(sv, r, 32), e = __shfl(ev, r, 32);
                    for (int j0 = s; j0 < e; j0 += 32) {
                        const int j = j0 + sl;
                        const bool valid = (j < e);
                        float2 p = make_float2(0.f, 0.f);
                        int vi0 = 0x7FFFFFFF;
                        if (valid) { p = PS[j]; vi0 = IS[j]; }
                        const float dx = q.x - p.x, dy = q.y - p.y;
                        const float d2 = __builtin_fmaf(dy, dy, __fmul_rn(dx, dx));
                        unsigned cm = (unsigned)(__ballot(valid && (d2 <= tau2b)) >> (half << 5));
                        const float ex = __fsqrt_rn(__fadd_rn(__fmul_rn(dx, dx),
                                                              __fmul_rn(dy, dy)));
                        while (cm) {
                            const int l = __builtin_ctz(cm); cm &= cm - 1;
                            const float v  = __shfl(ex, l, 32);
                            const int   vi = __shfl(vi0, l, 32);
                            const bool cl = (fd < v) || (fd == v && fi < vi);
                            const int pos = __popc((unsigned)(__ballot(cl) >> (half << 5)));
                            const float sd = __shfl_up(fd, 1, 32);
                            const int   si = __shfl_up(fi, 1, 32);
                            fd = (sl < pos) ? fd : ((sl == pos) ? v  : sd);
                            fi = (sl < pos) ? fi : ((sl == pos) ? vi : si);
                        }
                    }
                }
                bd = fd; bi = fi;
            }

            const float tau = __shfl(bd, 31, 32);
            float g = INF;
            if (xlo > 0)        g = fminf(g, q.x - (float)xlo * h);
            if (xhi < GRID - 1) g = fminf(g, (float)(xhi + 1) * h - q.x);
            if (ylo > 0)        g = fminf(g, q.y - (float)ylo * h);
            if (yhi < GRID - 1) g = fminf(g, (float)(yhi + 1) * h - q.y);
            if (tau < g * (1.0f - 4e-6f)) break;
            L += 2;
            if (L > GRID - 1) L = GRID - 1;
        }
    }

    // ---- outputs 0 and 1: uiv_k and idx (as float) ----
    {
        const float2 pk = P[bi];
        float2 u;
        u.x = q.x - pk.x;
        u.y = q.y - pk.y;
        ((float2*)out_uiv)[(size_t)wid * KK + sl] = u;
        out_idx[(size_t)wid * KK + sl] = (float)bi;
    }

    // ---- Phase A: stage my neighbor's 32-float value row into LDS ----
    {
        const float4* src = (const float4*)(values_in + ((size_t)b * NN + bi) * CIN);
        const float4 r0 = src[0], r1 = src[1], r2 = src[2], r3 = src[3];
        const float4 r4 = src[4], r5 = src[5], r6 = src[6], r7 = src[7];
        float4* dst = (float4*)(VLq + sl * VROW);
        dst[0] = r0; dst[1] = r1; dst[2] = r2; dst[3] = r3;
        dst[4] = r4; dst[5] = r5; dst[6] = r6; dst[7] = r7;
    }

    // ---- Phase G: T[e][i] = sum_k exp(-256*(r_k - mu_e)^2) * v_k[i], v from LDS --
    {
        const int e2 = sl >> 2;                 // 0..7 -> e in {2*e2, 2*e2+1}
        const int iq = sl & 3;                  // i-block of 8
        const float mu0 = (float)(2 * e2)     * (1.0f / 15.0f);
        const float mu1 = (float)(2 * e2 + 1) * (1.0f / 15.0f);
        float4 A0a = make_float4(0.f, 0.f, 0.f, 0.f);
        float4 A0b = A0a, A1a = A0a, A1b = A0a;
#pragma unroll 8
        for (int k = 0; k < KK; ++k) {
            const float rk = __shfl(bd, k, 32);
            const float d0 = rk - mu0;
            const float d1 = rk - mu1;
            const float w0 = __expf(-256.0f * d0 * d0);
            const float w1 = __expf(-256.0f * d1 * d1);
            const float4* vr = (const float4*)(VLq + k * VROW + iq * 8);
            const float4 va = vr[0], vb = vr[1];
            A0a.x += w0 * va.x; A0a.y += w0 * va.y; A0a.z += w0 * va.z; A0a.w += w0 * va.w;
            A0b.x += w0 * vb.x; A0b.y += w0 * vb.y; A0b.z += w0 * vb.z; A0b.w += w0 * vb.w;
            A1a.x += w1 * va.x; A1a.y += w1 * va.y; A1a.z += w1 * va.z; A1a.w += w1 * va.w;
            A1b.x += w1 * vb.x; A1b.y += w1 * vb.y; A1b.z += w1 * vb.z; A1b.w += w1 * vb.w;
        }
        // overlay T (16 x VROW floats) onto the VL region -- all G reads precede
        // these stores in program order within this same half-wave.
        float4* t0 = (float4*)(VLq + (2 * e2)     * VROW + iq * 8);
        float4* t1 = (float4*)(VLq + (2 * e2 + 1) * VROW + iq * 8);
        t0[0] = A0a; t0[1] = A0b;
        t1[0] = A1a; t1[1] = A1b;
    }

    // ---- Phase R: block-cooperative out = C . T over all 8 queries ----
    // First barrier also orders all KEY usage before CL staging overwrites it.
    {
        const int w  = tid >> 6;          // wave: i-slice [8w, 8w+8)
        const int rq = (tid >> 3) & 7;    // query
        const int ro = tid & 7;           // o-chunk (4 outputs)
        float4 s4 = make_float4(0.f, 0.f, 0.f, 0.f);
        const float* Tq = &VL[rq][0];
#pragma unroll
        for (int ec = 0; ec < EE / ECH; ++ec) {
            __syncthreads();               // KNN/G complete (ec=0) / chunk consumed
            {
                const float4* src = (const float4*)(coeff2 + ec * (ECH * CIN * COUT));
                float4* dst = (float4*)CLRAW;
#pragma unroll
                for (int j = 0; j < (ECH * CIN * COUT) / (4 * 256); ++j) {
                    const int idx = tid + j * 256;
                    dst[idx] = src[idx];
                }
            }
            __syncthreads();
#pragma unroll
            for (int el = 0; el < ECH; ++el) {
                const int e = ec * ECH + el;
                const float* Trow = Tq + e * VROW + 8 * w;
                const float4 ta = *(const float4*)(Trow);        // 16B-aligned
                const float4 tb = *(const float4*)(Trow + 4);
                const float* Crow = CLf + el * (CIN * COUT) + (8 * w) * COUT + ro * 4;
#pragma unroll
                for (int ir = 0; ir < 4; ++ir) {
                    const float t = (ir == 0) ? ta.x : (ir == 1) ? ta.y
                                  : (ir == 2) ? ta.z : ta.w;
                    const float4 c = *(const float4*)(Crow + ir * COUT);
                    s4.x += t * c.x; s4.y += t * c.y;
                    s4.z += t * c.z; s4.w += t * c.w;
                }
#pragma unroll
                for (int ir = 0; ir < 4; ++ir) {
                    const float t = (ir == 0) ? tb.x : (ir == 1) ? tb.y
                                  : (ir == 2) ? tb.z : tb.w;
                    const float4 c = *(const float4*)(Crow + (4 + ir) * COUT);
                    s4.x += t * c.x; s4.y += t * c.y;
                    s4.z += t * c.z; s4.w += t * c.w;
                }
            }
        }
        // cross-wave combine via PART overlay on CL
        __syncthreads();
        float4* PART = (float4*)CLRAW;           // [w][rq][ro] = tid order, 4KB
        PART[tid] = s4;
        __syncthreads();
        if (w == 0) {
            const float4 p0 = PART[tid];
            const float4 p1 = PART[tid + 64];
            const float4 p2 = PART[tid + 128];
            const float4 p3 = PART[tid + 192];
            const float4 bv = *(const float4*)(bias + ro * 4);
            float4 ov;
            ov.x = (p0.x + p1.x + p2.x + p3.x) * (1.0f / 32.0f) + bv.x;
            ov.y = (p0.y + p1.y + p2.y + p3.y) * (1.0f / 32.0f) + bv.y;
            ov.z = (p0.z + p1.z + p2.z + p3.z) * (1.0f / 32.0f) + bv.z;
            ov.w = (p0.w + p1.w + p2.w + p3.w) * (1.0f / 32.0f) + bv.w;
            const int qw = blockIdx.x * QPB2 + rq;
            *(float4*)(out_val + (size_t)qw * COUT + ro * 4) = ov;
        }
    }
}

extern "C" void kernel_launch(void* const* d_in, const int* in_sizes, int n_in,
                              void* d_out, int out_size, void* d_ws, size_t ws_size,
                              hipStream_t stream) {
    const float* points_in  = (const float*)d_in[0];
    const float* values_in  = (const float*)d_in[1];
    const float* points_out = (const float*)d_in[2];
    const float* coeff      = (const float*)d_in[3];
    const float* bias       = (const float*)d_in[4];

    float* out     = (float*)d_out;
    float* out_uiv = out;                                        // B*M*K*2
    float* out_idx = out + (size_t)BB * MM * KK * 2;             // B*M*K
    float* out_val = out_idx + (size_t)BB * MM * KK;             // B*M*COUT

    char* ws = (char*)d_ws;
    float*  coeff2 = (float*)(ws + OFS_COEFFT);
    int*    counts = (int*)  (ws + OFS_COUNTS);
    int*    cursor = (int*)  (ws + OFS_CURSOR);
    int*    strts  = (int*)  (ws + OFS_STARTS);
    float2* pts_s  = (float2*)(ws + OFS_PTSS);
    int*    idx_s  = (int*)  (ws + OFS_IDXS);

    hipLaunchKernelGGL(prep_coeff_zero, dim3(64), dim3(256), 0, stream,
                       coeff, coeff2, counts);   // counts+cursor contiguous
    hipLaunchKernelGGL(bin_count, dim3(64), dim3(256), 0, stream, points_in, counts);
    hipLaunchKernelGGL(bin_scan, dim3(BB), dim3(1024), 0, stream, counts, strts);
    hipLaunchKernelGGL(bin_scatter, dim3(64), dim3(256), 0, stream,
                       points_in, strts, cursor, pts_s, idx_s);

    const int blocks = (BB * MM) / QPB2;                         // 2048
    hipLaunchKernelGGL(conv_fused, dim3(blocks), dim3(256), 0, stream,
                       pts_s, idx_s, strts, points_in, values_in, points_out,
                       coeff2, bias, out_uiv, out_idx, out_val);
}

// Round 21
// 60.342 us; speedup vs baseline: 2.8157x; 1.1233x over previous
//
#include <hip/hip_runtime.h>
#include <cstdint>
#include <cstddef>

// Problem constants (from reference)
constexpr int BB   = 2;
constexpr int NN   = 8192;
constexpr int MM   = 8192;
constexpr int CIN  = 32;
constexpr int COUT = 32;
constexpr int EE   = 16;
constexpr int KK   = 32;
constexpr int GRID = 32;              // binning grid (h = 1/32, ~8 pts/cell)
constexpr int NCELL = GRID * GRID;

#define QPB2 8           // queries per 256-thread block (32 lanes/query)
#define CAP 128
#define VROW 36          // padded value-row stride in floats (144B)
#define VQS  1156        // per-query pool stripe (32*36 + 4: bank-phase skew 4q)
#define ECH 4            // e-chunk size for coeff LDS staging
#define CLBASE 580       // float offset of CL chunk within a stripe (dead V region)

// Fixed-radius fast path: lambda = pi*R0^2*N ~ 48 expected candidates.
#define R0_FAST 0.0432f

// Workspace layout (bytes)
constexpr size_t OFS_COEFFT = 0;        // coeff2[E][CIN][COUT]: 16384 f = 65536 B
constexpr size_t OFS_COUNTS = 65536;    // 2*1024 i = 8192 B
constexpr size_t OFS_CURSOR = 73728;    // 2*1024 i = 8192 B
constexpr size_t OFS_STARTS = 81920;    // 2*1025 i = 8200 B (pad to 8704)
constexpr size_t OFS_PTSS   = 90624;    // 2*8192 float2 = 131072 B
constexpr size_t OFS_IDXS   = 221696;   // 2*8192 i = 65536 B  (total 287232 B)

// ---- fused: zero counters/cursors + coeff [CIN][COUT][E] -> coeff2 [E][CIN][COUT]
__global__ __launch_bounds__(256) void prep_coeff_zero(const float* __restrict__ coeff,
                                                       float* __restrict__ coeff2,
                                                       int* __restrict__ cz) {
    int tid = blockIdx.x * 256 + threadIdx.x;
    if (tid < 2 * 2 * NCELL) cz[tid] = 0;             // counts + cursor
    if (tid >= EE * CIN * COUT) return;
    int o = tid & 31;
    int i = (tid >> 5) & 31;
    int e = tid >> 10;
    coeff2[tid] = coeff[(i * COUT + o) * EE + e];
}

// ---- binning: count, scan, scatter ----------------------------------------------
__device__ __forceinline__ int cell_of(float2 p) {
    int cx = min(GRID - 1, max(0, (int)(p.x * (float)GRID)));
    int cy = min(GRID - 1, max(0, (int)(p.y * (float)GRID)));
    return cy * GRID + cx;
}

__global__ __launch_bounds__(256) void bin_count(const float* __restrict__ pts,
                                                 int* __restrict__ counts) {
    int t = blockIdx.x * 256 + threadIdx.x;
    int b = t >> 13, i = t & (NN - 1);
    float2 p = ((const float2*)pts)[(size_t)b * NN + i];
    atomicAdd(&counts[b * NCELL + cell_of(p)], 1);
}

// 2-barrier hierarchical scan; one block per batch.
__global__ __launch_bounds__(1024) void bin_scan(const int* __restrict__ counts,
                                                 int* __restrict__ starts) {
    __shared__ int wsum[16];
    const int b    = blockIdx.x;
    const int t    = threadIdx.x;
    const int lane = t & 63, wv = t >> 6;           // 16 waves
    int s = counts[b * NCELL + t];
#pragma unroll
    for (int off = 1; off < 64; off <<= 1) {
        const int v = __shfl_up(s, off, 64);
        if (lane >= off) s += v;
    }
    if (lane == 63) wsum[wv] = s;
    __syncthreads();
    if (wv == 0) {
        int ws = (lane < 16) ? wsum[lane] : 0;
#pragma unroll
        for (int off = 1; off < 16; off <<= 1) {
            const int v = __shfl_up(ws, off, 64);
            if (lane >= off) ws += v;
        }
        if (lane < 16) wsum[lane] = ws;
    }
    __syncthreads();
    const int woff = (wv > 0) ? wsum[wv - 1] : 0;
    starts[b * (NCELL + 1) + t + 1] = s + woff;
    if (t == 0) starts[b * (NCELL + 1)] = 0;
}

__global__ __launch_bounds__(256) void bin_scatter(const float* __restrict__ pts,
                                                   const int* __restrict__ starts,
                                                   int* __restrict__ cursor,
                                                   float2* __restrict__ pts_s,
                                                   int* __restrict__ idx_s) {
    int t = blockIdx.x * 256 + threadIdx.x;
    int b = t >> 13, i = t & (NN - 1);
    float2 p = ((const float2*)pts)[(size_t)b * NN + i];
    int cell = cell_of(p);
    int pos = starts[b * (NCELL + 1) + cell] + atomicAdd(&cursor[b * NCELL + cell], 1);
    pts_s[(size_t)b * NN + pos] = p;     // intra-cell order nondeterministic; final
    idx_s[(size_t)b * NN + pos] = i;     // rank by (d, orig idx) makes output exact.
}

// ==== FUSED kernel: KNN select + gather + einsum + reduce. 8 queries/block. ======
// Single 37KB LDS pool (8 stripes of VQS floats) with liveness overlays:
//   KNN:     KEY (1040B) lives at stripe base           [dead after select]
//   Phase A: 32 V-rows fill the stripe   [rows dead after G]
//   Phase G: T (2304B) overlays stripe base
//   Phase R: CL chunks overlay the DEAD upper stripes [CLBASE*4, CLBASE*4+2048)
//   combine: PART (4KB) overlays pool start
// 37KB/block -> 4 blocks/CU (was 53.7KB -> 3): the occupancy lever of this round.
__global__ __launch_bounds__(256) void conv_fused(
    const float2* __restrict__ pts_s, const int* __restrict__ idx_s,
    const int* __restrict__ starts,
    const float* __restrict__ points_in, const float* __restrict__ values_in,
    const float* __restrict__ points_out,
    const float* __restrict__ coeff2, const float* __restrict__ bias,
    float* __restrict__ out_uiv, float* __restrict__ out_idx,
    float* __restrict__ out_val)
{
    __shared__ alignas(16) float POOL[QPB2 * VQS];      // 36992 B

    const int tid   = threadIdx.x;
    const int sl    = tid & 31;
    const int qslot = tid >> 5;            // 0..7
    const int half  = qslot & 1;
    const int wid   = blockIdx.x * QPB2 + qslot;
    const int b     = wid >> 13;
    const int m     = wid & (MM - 1);

    unsigned long long* KEYq = (unsigned long long*)&POOL[qslot * VQS];
    float* VLq = &POOL[qslot * VQS];

    const float2* PS = pts_s + (size_t)b * NN;
    const int*    IS = idx_s + (size_t)b * NN;
    const int*    ST = starts + b * (NCELL + 1);
    const float2* P  = ((const float2*)points_in) + (size_t)b * NN;
    const float2  q  = ((const float2*)points_out)[(size_t)b * MM + m];

    const float INF = __builtin_inff();
    const float h = 1.0f / (float)GRID;
    const unsigned lmlt32 = (1u << sl) - 1u;

    float bd;   // sorted exact distance (sub-lane sl holds entry #sl)
    int   bi;   // sorted original index
    bool  ok = false;

    // ---------------- FAST PATH: fixed analytic radius, single scan ---------------
    {
        float tau = R0_FAST;
        {
            const float bx = fminf(q.x, 1.0f - q.x);
            const float by = fminf(q.y, 1.0f - q.y);
#pragma unroll
            for (int it = 0; it < 3; ++it) {
                const float wx = 0.5f + 0.5f * fminf(bx / tau, 1.0f);
                const float wy = 0.5f + 0.5f * fminf(by / tau, 1.0f);
                tau = R0_FAST * __frsqrt_rn(wx * wy);
            }
        }
        const float tau2  = tau * tau;
        const float tau2a = tau2 * (1.0f + 2e-6f);

        const int xlo = (int)fmaxf((q.x - tau) * (float)GRID, 0.0f);
        const int xhi = (int)fminf((q.x + tau) * (float)GRID, (float)(GRID - 1));
        const int ylo = (int)fmaxf((q.y - tau) * (float)GRID, 0.0f);
        const int yhi = (int)fminf((q.y + tau) * (float)GRID, (float)(GRID - 1));
        const int nrows = yhi - ylo + 1;

        int sv = 0, ev = 0;
        if (sl < nrows) {
            sv = ST[(ylo + sl) * GRID + xlo];
            ev = ST[(ylo + sl) * GRID + xhi + 1];
        }

        int base = 0, nin = 0;
        for (int r = 0; r < nrows; ++r) {
            const int s = __shfl(sv, r, 32), e = __shfl(ev, r, 32);
            for (int j0 = s; j0 < e; j0 += 32) {
                const int j = j0 + sl;
                const bool valid = (j < e);
                float2 p = make_float2(2.0f, 2.0f);
                if (valid) p = PS[j];
                const float dx = q.x - p.x, dy = q.y - p.y;
                const float d2 = __builtin_fmaf(dy, dy, __fmul_rn(dx, dx));
                const bool adm = valid && (d2 <= tau2a);
                const unsigned bmA = (unsigned)(__ballot(adm) >> (half << 5));
                const unsigned bmS = (unsigned)(__ballot(valid && (d2 <= tau2)) >> (half << 5));
                nin += __popc(bmS);
                if (bmA) {
                    const float ex = __fsqrt_rn(__fadd_rn(__fmul_rn(dx, dx),
                                                          __fmul_rn(dy, dy)));
                    const int pos = base + __popc(bmA & lmlt32);
                    if (adm && pos < CAP)
                        KEYq[pos] =
                            ((unsigned long long)__float_as_uint(ex) << 32) | (unsigned)IS[j];
                    base += __popc(bmA);
                }
            }
        }

        ok = (nin >= 32) && (base <= CAP);
        if (ok) {
            unsigned long long k0 = (sl      < base) ? KEYq[sl]      : ~0ull;
            unsigned long long k1 = (sl + 32 < base) ? KEYq[sl + 32] : ~0ull;
            int r0 = 0, r1 = 0;
            if (!__any(base > 64)) {
                for (int t = 0; t < base; ++t) {
                    const unsigned long long kt = KEYq[t];
                    r0 += (kt < k0) ? 1 : 0;
                    r1 += (kt < k1) ? 1 : 0;
                }
            } else {
                unsigned long long k2 = (sl + 64 < base) ? KEYq[sl + 64] : ~0ull;
                unsigned long long k3 = (sl + 96 < base) ? KEYq[sl + 96] : ~0ull;
                int r2 = 0, r3 = 0;
                for (int t = 0; t < base; ++t) {
                    const unsigned long long kt = KEYq[t];
                    r0 += (kt < k0) ? 1 : 0;
                    r1 += (kt < k1) ? 1 : 0;
                    r2 += (kt < k2) ? 1 : 0;
                    r3 += (kt < k3) ? 1 : 0;
                }
                if (sl + 64 < base && r2 < 32) KEYq[r2] = k2;
                if (sl + 96 < base && r3 < 32) KEYq[r3] = k3;
            }
            if (sl      < base && r0 < 32) KEYq[r0] = k0;
            if (sl + 32 < base && r1 < 32) KEYq[r1] = k1;
            const unsigned long long kf = KEYq[sl];
            bd = __uint_as_float((unsigned)(kf >> 32));
            bi = (int)(unsigned)(kf & 0xffffffffull);

            const float tau32 = __shfl(bd, 31, 32);
            float g = INF;
            if (xlo > 0)        g = fminf(g, q.x - (float)xlo * h);
            if (xhi < GRID - 1) g = fminf(g, (float)(xhi + 1) * h - q.x);
            if (ylo > 0)        g = fminf(g, q.y - (float)ylo * h);
            if (yhi < GRID - 1) g = fminf(g, (float)(yhi + 1) * h - q.y);
            ok = (tau32 < g * (1.0f - 4e-6f));
        }
    }

    // ---------------- SLOW PATH (rare): adaptive, exact ---------------------------
    if (!ok) {
        const int cx = min(GRID - 1, max(0, (int)(q.x * (float)GRID)));
        const int cy = min(GRID - 1, max(0, (int)(q.y * (float)GRID)));
        int L = 2;
        for (;;) {
            const int xlo = max(cx - L, 0), xhi = min(cx + L, GRID - 1);
            const int ylo = max(cy - L, 0), yhi = min(cy + L, GRID - 1);
            const int nrows = yhi - ylo + 1;

            int sv = 0, ev = 0;
            if (sl < nrows) {
                sv = ST[(ylo + sl) * GRID + xlo];
                ev = ST[(ylo + sl) * GRID + xhi + 1];
            }

            float mn1 = INF, mn2 = INF;
            for (int r = 0; r < nrows; ++r) {
                const int s = __shfl(sv, r, 32), e = __shfl(ev, r, 32);
                for (int j = s + sl; j < e; j += 32) {
                    const float2 p = PS[j];
                    const float dx = q.x - p.x, dy = q.y - p.y;
                    const float d2 = __builtin_fmaf(dy, dy, __fmul_rn(dx, dx));
                    const float big = fmaxf(mn1, d2);
                    mn1 = fminf(mn1, d2);
                    mn2 = fminf(mn2, big);
                }
            }

            {
                float v = mn2;
#pragma unroll
                for (int k = 2; k <= 32; k <<= 1) {
#pragma unroll
                    for (int j = k >> 1; j > 0; j >>= 1) {
                        const float o = __shfl_xor(v, j, 32);
                        const bool up = ((sl & k) == 0), lower = ((sl & j) == 0);
                        const float mnv = fminf(v, o), mxv = fmaxf(v, o);
                        v = (lower == up) ? mnv : mxv;
                    }
                }
                mn2 = __shfl(v, 15, 32);
            }
            const float tau2b = mn2 * (1.0f + 4e-6f);

            int base = 0;
            for (int r = 0; r < nrows; ++r) {
                const int s = __shfl(sv, r, 32), e = __shfl(ev, r, 32);
                for (int j0 = s; j0 < e; j0 += 32) {
                    const int j = j0 + sl;
                    const bool valid = (j < e);
                    float2 p = make_float2(0.f, 0.f);
                    if (valid) p = PS[j];
                    const float dx = q.x - p.x, dy = q.y - p.y;
                    const float d2 = __builtin_fmaf(dy, dy, __fmul_rn(dx, dx));
                    const bool pred = valid && (d2 <= tau2b);
                    const unsigned bm = (unsigned)(__ballot(pred) >> (half << 5));
                    if (bm) {
                        const float ex = __fsqrt_rn(__fadd_rn(__fmul_rn(dx, dx),
                                                              __fmul_rn(dy, dy)));
                        const int pos = base + __popc(bm & lmlt32);
                        if (pred && pos < CAP)
                            KEYq[pos] =
                                ((unsigned long long)__float_as_uint(ex) << 32) | (unsigned)IS[j];
                        base += __popc(bm);
                    }
                }
            }

            if (base <= CAP) {
                unsigned long long k0 = (sl      < base) ? KEYq[sl]      : ~0ull;
                unsigned long long k1 = (sl + 32 < base) ? KEYq[sl + 32] : ~0ull;
                int r0 = 0, r1 = 0;
                if (!__any(base > 64)) {
                    for (int t = 0; t < base; ++t) {
                        const unsigned long long kt = KEYq[t];
                        r0 += (kt < k0) ? 1 : 0;
                        r1 += (kt < k1) ? 1 : 0;
                    }
                } else {
                    unsigned long long k2 = (sl + 64 < base) ? KEYq[sl + 64] : ~0ull;
                    unsigned long long k3 = (sl + 96 < base) ? KEYq[sl + 96] : ~0ull;
                    int r2 = 0, r3 = 0;
                    for (int t = 0; t < base; ++t) {
                        const unsigned long long kt = KEYq[t];
                        r0 += (kt < k0) ? 1 : 0;
                        r1 += (kt < k1) ? 1 : 0;
                        r2 += (kt < k2) ? 1 : 0;
                        r3 += (kt < k3) ? 1 : 0;
                    }
                    if (sl + 64 < base && r2 < 32) KEYq[r2] = k2;
                    if (sl + 96 < base && r3 < 32) KEYq[r3] = k3;
                }
                if (sl      < base && r0 < 32) KEYq[r0] = k0;
                if (sl + 32 < base && r1 < 32) KEYq[r1] = k1;
                if (base < 32 && sl >= base) KEYq[sl] = ~0ull;   // pad -> NaN -> expand
                const unsigned long long kf = KEYq[sl];
                bd = __uint_as_float((unsigned)(kf >> 32));
                bi = (int)(unsigned)(kf & 0xffffffffull);
            } else {
                float fd = INF; int fi = 0x7FFFFFFF;
                for (int r = 0; r < nrows; ++r) {
                    const int s = __shfl(sv, r, 32), e = __shfl(ev, r, 32);
                    for (int j0 = s; j0 < e; j0 += 32) {
                        const int j = j0 + sl;
                        const bool valid = (j < e);
                        float2 p = make_float2(0.f, 0.f);
                        int vi0 = 0x7FFFFFFF;
                        if (valid) { p = PS[j]; vi0 = IS[j]; }
                        const float dx = q.x - p.x, dy = q.y - p.y;
                        const float d2 = __builtin_fmaf(dy, dy, __fmul_rn(dx, dx));
                        unsigned cm = (unsigned)(__ballot(valid && (d2 <= tau2b)) >> (half << 5));
                        const float ex = __fsqrt_rn(__fadd_rn(__fmul_rn(dx, dx),
                                                              __fmul_rn(dy, dy)));
                        while (cm) {
                            const int l = __builtin_ctz(cm); cm &= cm - 1;
                            const float v  = __shfl(ex, l, 32);
                            const int   vi = __shfl(vi0, l, 32);
                            const bool cl = (fd < v) || (fd == v && fi < vi);
                            const int pos = __popc((unsigned)(__ballot(cl) >> (half << 5)));
                            const float sd = __shfl_up(fd, 1, 32);
                            const int   si = __shfl_up(fi, 1, 32);
                            fd = (sl < pos) ? fd : ((sl == pos) ? v  : sd);
                            fi = (sl < pos) ? fi : ((sl == pos) ? vi : si);
                        }
                    }
                }
                bd = fd; bi = fi;
            }

            const float tau = __shfl(bd, 31, 32);
            float g = INF;
            if (xlo > 0)        g = fminf(g, q.x - (float)xlo * h);
            if (xhi < GRID - 1) g = fminf(g, (float)(xhi + 1) * h - q.x);
            if (ylo > 0)        g = fminf(g, q.y - (float)ylo * h);
            if (yhi < GRID - 1) g = fminf(g, (float)(yhi + 1) * h - q.y);
            if (tau < g * (1.0f - 4e-6f)) break;
            L += 2;
            if (L > GRID - 1) L = GRID - 1;
        }
    }

    // ---- outputs 0 and 1: uiv_k and idx (as float) ----
    {
        const float2 pk = P[bi];
        float2 u;
        u.x = q.x - pk.x;
        u.y = q.y - pk.y;
        ((float2*)out_uiv)[(size_t)wid * KK + sl] = u;
        out_idx[(size_t)wid * KK + sl] = (float)bi;
    }

    // ---- Phase A: stage my neighbor's 32-float value row into LDS ----
    // (overwrites KEY region -- KEY dead, same half-wave program order)
    {
        const float4* src = (const float4*)(values_in + ((size_t)b * NN + bi) * CIN);
        const float4 r0 = src[0], r1 = src[1], r2 = src[2], r3 = src[3];
        const float4 r4 = src[4], r5 = src[5], r6 = src[6], r7 = src[7];
        float4* dst = (float4*)(VLq + sl * VROW);
        dst[0] = r0; dst[1] = r1; dst[2] = r2; dst[3] = r3;
        dst[4] = r4; dst[5] = r5; dst[6] = r6; dst[7] = r7;
    }

    // ---- Phase G: T[e][i] = sum_k exp(-256*(r_k - mu_e)^2) * v_k[i], v from LDS --
    {
        const int e2 = sl >> 2;                 // 0..7 -> e in {2*e2, 2*e2+1}
        const int iq = sl & 3;                  // i-block of 8
        const float mu0 = (float)(2 * e2)     * (1.0f / 15.0f);
        const float mu1 = (float)(2 * e2 + 1) * (1.0f / 15.0f);
        float4 A0a = make_float4(0.f, 0.f, 0.f, 0.f);
        float4 A0b = A0a, A1a = A0a, A1b = A0a;
#pragma unroll 8
        for (int k = 0; k < KK; ++k) {
            const float rk = __shfl(bd, k, 32);
            const float d0 = rk - mu0;
            const float d1 = rk - mu1;
            const float w0 = __expf(-256.0f * d0 * d0);
            const float w1 = __expf(-256.0f * d1 * d1);
            const float4* vr = (const float4*)(VLq + k * VROW + iq * 8);
            const float4 va = vr[0], vb = vr[1];
            A0a.x += w0 * va.x; A0a.y += w0 * va.y; A0a.z += w0 * va.z; A0a.w += w0 * va.w;
            A0b.x += w0 * vb.x; A0b.y += w0 * vb.y; A0b.z += w0 * vb.z; A0b.w += w0 * vb.w;
            A1a.x += w1 * va.x; A1a.y += w1 * va.y; A1a.z += w1 * va.z; A1a.w += w1 * va.w;
            A1b.x += w1 * vb.x; A1b.y += w1 * vb.y; A1b.z += w1 * vb.z; A1b.w += w1 * vb.w;
        }
        // overlay T (16 x VROW floats) onto the stripe base -- all G reads precede
        // these stores in program order within this same half-wave.
        float4* t0 = (float4*)(VLq + (2 * e2)     * VROW + iq * 8);
        float4* t1 = (float4*)(VLq + (2 * e2 + 1) * VROW + iq * 8);
        t0[0] = A0a; t0[1] = A0b;
        t1[0] = A1a; t1[1] = A1b;
    }

    // ---- Phase R: block-cooperative out = C . T over all 8 queries ----
    // CL chunk (el,w-pair) lives in the dead upper part of stripe el*2+(w>>1):
    //   float offset = stripe*VQS + CLBASE + (w&1)*256 + ir*32 + ro*4
    // T in [0,2304)B and CL in [2320,4368)B of each stripe are disjoint.
    {
        const int w  = tid >> 6;          // wave: i-slice [8w, 8w+8)
        const int rq = (tid >> 3) & 7;    // query
        const int ro = tid & 7;           // o-chunk (4 outputs)
        float4 s4 = make_float4(0.f, 0.f, 0.f, 0.f);
        const float* Tq = &POOL[rq * VQS];
#pragma unroll
        for (int ec = 0; ec < EE / ECH; ++ec) {
            __syncthreads();               // KNN/G complete (ec=0) / chunk consumed
            {
                // stage 4096 floats = 1024 float4: chunk = idx>>7, off4 = idx&127
                const float4* src = (const float4*)(coeff2 + ec * (ECH * CIN * COUT));
#pragma unroll
                for (int j = 0; j < 4; ++j) {
                    const int idx = tid + j * 256;
                    const int ch  = idx >> 7;
                    const int o4  = idx & 127;
                    ((float4*)(&POOL[ch * VQS + CLBASE]))[o4] = src[idx];
                }
            }
            __syncthreads();
#pragma unroll
            for (int el = 0; el < ECH; ++el) {
                const int e = ec * ECH + el;
                const float* Trow = Tq + e * VROW + 8 * w;
                const float4 ta = *(const float4*)(Trow);        // 16B-aligned
                const float4 tb = *(const float4*)(Trow + 4);
                const float* Crow = &POOL[(el * 2 + (w >> 1)) * VQS + CLBASE
                                          + (w & 1) * 256 + ro * 4];
#pragma unroll
                for (int ir = 0; ir < 4; ++ir) {
                    const float t = (ir == 0) ? ta.x : (ir == 1) ? ta.y
                                  : (ir == 2) ? ta.z : ta.w;
                    const float4 c = *(const float4*)(Crow + ir * COUT);
                    s4.x += t * c.x; s4.y += t * c.y;
                    s4.z += t * c.z; s4.w += t * c.w;
                }
#pragma unroll
                for (int ir = 0; ir < 4; ++ir) {
                    const float t = (ir == 0) ? tb.x : (ir == 1) ? tb.y
                                  : (ir == 2) ? tb.z : tb.w;
                    const float4 c = *(const float4*)(Crow + (4 + ir) * COUT);
                    s4.x += t * c.x; s4.y += t * c.y;
                    s4.z += t * c.z; s4.w += t * c.w;
                }
            }
        }
        // cross-wave combine via PART overlay on the pool start (all T/CL dead)
        __syncthreads();
        float4* PART = (float4*)POOL;            // [w][rq][ro] = tid order, 4KB
        PART[tid] = s4;
        __syncthreads();
        if (w == 0) {
            const float4 p0 = PART[tid];
            const float4 p1 = PART[tid + 64];
            const float4 p2 = PART[tid + 128];
            const float4 p3 = PART[tid + 192];
            const float4 bv = *(const float4*)(bias + ro * 4);
            float4 ov;
            ov.x = (p0.x + p1.x + p2.x + p3.x) * (1.0f / 32.0f) + bv.x;
            ov.y = (p0.y + p1.y + p2.y + p3.y) * (1.0f / 32.0f) + bv.y;
            ov.z = (p0.z + p1.z + p2.z + p3.z) * (1.0f / 32.0f) + bv.z;
            ov.w = (p0.w + p1.w + p2.w + p3.w) * (1.0f / 32.0f) + bv.w;
            const int qw = blockIdx.x * QPB2 + rq;
            *(float4*)(out_val + (size_t)qw * COUT + ro * 4) = ov;
        }
    }
}

extern "C" void kernel_launch(void* const* d_in, const int* in_sizes, int n_in,
                              void* d_out, int out_size, void* d_ws, size_t ws_size,
                              hipStream_t stream) {
    const float* points_in  = (const float*)d_in[0];
    const float* values_in  = (const float*)d_in[1];
    const float* points_out = (const float*)d_in[2];
    const float* coeff      = (const float*)d_in[3];
    const float* bias       = (const float*)d_in[4];

    float* out     = (float*)d_out;
    float* out_uiv = out;                                        // B*M*K*2
    float* out_idx = out + (size_t)BB * MM * KK * 2;             // B*M*K
    float* out_val = out_idx + (size_t)BB * MM * KK;             // B*M*COUT

    char* ws = (char*)d_ws;
    float*  coeff2 = (float*)(ws + OFS_COEFFT);
    int*    counts = (int*)  (ws + OFS_COUNTS);
    int*    cursor = (int*)  (ws + OFS_CURSOR);
    int*    strts  = (int*)  (ws + OFS_STARTS);
    float2* pts_s  = (float2*)(ws + OFS_PTSS);
    int*    idx_s  = (int*)  (ws + OFS_IDXS);

    hipLaunchKernelGGL(prep_coeff_zero, dim3(64), dim3(256), 0, stream,
                       coeff, coeff2, counts);   // counts+cursor contiguous
    hipLaunchKernelGGL(bin_count, dim3(64), dim3(256), 0, stream, points_in, counts);
    hipLaunchKernelGGL(bin_scan, dim3(BB), dim3(1024), 0, stream, counts, strts);
    hipLaunchKernelGGL(bin_scatter, dim3(64), dim3(256), 0, stream,
                       points_in, strts, cursor, pts_s, idx_s);

    const int blocks = (BB * MM) / QPB2;                         // 2048
    hipLaunchKernelGGL(conv_fused, dim3(blocks), dim3(256), 0, stream,
                       pts_s, idx_s, strts, points_in, values_in, points_out,
                       coeff2, bias, out_uiv, out_idx, out_val);
}